// Round 3
// baseline (3236.443 us; speedup 1.0000x reference)
//
#include <hip/hip_runtime.h>
#include <cstdio>
#include <cstdint>

// R17: break k_round_wave's serial latency chain. R16 counters: VALUBusy 12%,
// occupancy 11% (VGPR=140 -> 3 waves/SIMD), FETCH 385MB = 1 line/edge gather;
// each wave serially walked ~16 edges, each a 2-deep dependent load chain ->
// latency-bound. R17 splits the round: k_base (precompute dst-half of msg L1),
// k_msg (slot-parallel, 4 slots/wave via half-split + ILP2, lean regs,
// launch_bounds(256,4) -> 4 waves/SIMD, 1.6M independent waves, writes relu'd
// M1 rows coalesced), k_aggsum (coalesced streaming segmented sum of M1),
// k_updw (wave-per-node-pair shfl-chain update MLP). M1 costs 410MB wr +
// 410MB rd ~ 130us streaming - cheap vs latency. slots now int4 (src,e,dst,0).
// Fallbacks: R16 fused path if ws < ~513MB, R14 atomic path if ws < ~78MB.

__attribute__((constructor)) static void atomgnn_r17_load_beacon() {
    fprintf(stderr, "ATOMGNN_R17_SOURCE_LOADED\n");
    fflush(stderr);
}

#define NN_REF 100000
#define NE_REF 3200000

// zero a float/int buffer (4B words), grid-stride
__global__ void __launch_bounds__(256)
k_zero(float* __restrict__ p, int n)
{
    int i = blockIdx.x * 256 + threadIdx.x;
    int stride = gridDim.x * 256;
    for (; i < n; i += stride) p[i] = 0.0f;
}

// encoder: h = relu(nf @ w1 + b1) @ w2 + b2   (16 -> 32 -> 32)
__global__ void __launch_bounds__(256)
k_encode(const float* __restrict__ nf,
         const float* __restrict__ w1g, const float* __restrict__ b1g,
         const float* __restrict__ w2g, const float* __restrict__ b2g,
         float* __restrict__ h, int n_nodes)
{
    __shared__ float sw1[16 * 32];
    __shared__ float sw2[32 * 32];
    __shared__ float sb1[32];
    __shared__ float sb2[32];
    for (int i = threadIdx.x; i < 16 * 32; i += 256) sw1[i] = w1g[i];
    for (int i = threadIdx.x; i < 32 * 32; i += 256) sw2[i] = w2g[i];
    if (threadIdx.x < 32) {
        sb1[threadIdx.x] = b1g[threadIdx.x];
        sb2[threadIdx.x] = b2g[threadIdx.x];
    }
    __syncthreads();
    int n = blockIdx.x * 256 + threadIdx.x;
    if (n >= n_nodes) return;

    const float4* p = (const float4*)(nf + (size_t)n * 16);
    float x[16];
    #pragma unroll
    for (int c = 0; c < 4; c++) {
        float4 v = p[c];
        x[4 * c] = v.x; x[4 * c + 1] = v.y; x[4 * c + 2] = v.z; x[4 * c + 3] = v.w;
    }

    float acc[32];
    #pragma unroll
    for (int j = 0; j < 32; j++) acc[j] = sb1[j];
    #pragma unroll 4
    for (int k = 0; k < 16; k++) {
        float xk = x[k];
        const float* wr = &sw1[k * 32];
        #pragma unroll
        for (int j = 0; j < 32; j++) acc[j] = fmaf(xk, wr[j], acc[j]);
    }
    #pragma unroll
    for (int j = 0; j < 32; j++) acc[j] = fmaxf(acc[j], 0.0f);

    float o[32];
    #pragma unroll
    for (int j = 0; j < 32; j++) o[j] = sb2[j];
    #pragma unroll 4
    for (int k = 0; k < 32; k++) {
        float hk = acc[k];
        const float* wr = &sw2[k * 32];
        #pragma unroll
        for (int j = 0; j < 32; j++) o[j] = fmaf(hk, wr[j], o[j]);
    }
    float4* hp = (float4*)(h + (size_t)n * 32);
    #pragma unroll
    for (int c = 0; c < 8; c++)
        hp[c] = make_float4(o[4 * c], o[4 * c + 1], o[4 * c + 2], o[4 * c + 3]);
}

// -------- CSR build: histogram -> exclusive scan -> fill --------

__global__ void __launch_bounds__(256)
k_hist(const int2* __restrict__ edges, int* __restrict__ cnt, int n_edges)
{
    int e = blockIdx.x * 256 + threadIdx.x;
    if (e >= n_edges) return;
    atomicAdd(&cnt[edges[e].y], 1);
}

__global__ void __launch_bounds__(256)
k_scan_block(const int* __restrict__ cnt, int* __restrict__ rs,
             int* __restrict__ bsum, int n)
{
    __shared__ int sd[256];
    int t = threadIdx.x;
    int i = blockIdx.x * 256 + t;
    int v = (i < n) ? cnt[i] : 0;
    sd[t] = v;
    __syncthreads();
    int val = v;
    for (int off = 1; off < 256; off <<= 1) {
        int add = (t >= off) ? sd[t - off] : 0;
        __syncthreads();
        val += add;
        sd[t] = val;
        __syncthreads();
    }
    if (i < n) rs[i] = val - v;           // exclusive within block
    if (t == 255) bsum[blockIdx.x] = val; // block total
}

__global__ void __launch_bounds__(1024)
k_scan_bsum(int* __restrict__ bsum, int nb, int* __restrict__ rs,
            int n_nodes, int n_edges)
{
    __shared__ int sd[1024];
    int t = threadIdx.x;
    int v = (t < nb) ? bsum[t] : 0;
    sd[t] = v;
    __syncthreads();
    int val = v;
    for (int off = 1; off < 1024; off <<= 1) {
        int add = (t >= off) ? sd[t - off] : 0;
        __syncthreads();
        val += add;
        sd[t] = val;
        __syncthreads();
    }
    if (t < nb) bsum[t] = val - v;  // exclusive prefix of block totals
    if (t == 0) rs[n_nodes] = n_edges;
}

__global__ void __launch_bounds__(256)
k_scan_add(int* __restrict__ rs, int* __restrict__ cursor,
           const int* __restrict__ bsum, int n)
{
    int i = blockIdx.x * 256 + threadIdx.x;
    if (i < n) {
        int v = rs[i] + bsum[blockIdx.x];
        rs[i] = v;
        cursor[i] = v;
    }
}

// scatter edges into dst-sorted slots: slot = (src, edge_idx, dst, 0)
__global__ void __launch_bounds__(256)
k_fill(const int2* __restrict__ edges, int* __restrict__ cursor,
       int4* __restrict__ slots, int n_edges)
{
    int e = blockIdx.x * 256 + threadIdx.x;
    if (e >= n_edges) return;
    int2 ed = edges[e];
    int pos = atomicAdd(&cursor[ed.y], 1);
    slots[pos] = make_int4(ed.x, e, ed.y, 0);
}

// -------- R17 round kernels --------

// base[n][c] = mb1[c] + sum_k h[n][k] * W1b[k][c]   (dst half of msg L1)
// wave handles 2 nodes (one per half); shfl width 32 is half-local.
__global__ void __launch_bounds__(256)
k_base(const float* __restrict__ h, const float* __restrict__ mw1,
       const float* __restrict__ mb1, float* __restrict__ baseb, int n_nodes)
{
    __shared__ float sW[32 * 32];
    __shared__ float sb[32];
    for (int i = threadIdx.x; i < 32 * 32; i += 256) sW[i] = mw1[32 * 32 + i];
    if (threadIdx.x < 32) sb[threadIdx.x] = mb1[threadIdx.x];
    __syncthreads();
    const int lane = threadIdx.x & 63;
    const int c    = lane & 31;
    const int half = lane >> 5;
    int wi = (int)((blockIdx.x * 256 + threadIdx.x) >> 6);
    int nw = gridDim.x * 4;
    for (; 2 * wi < n_nodes; wi += nw) {
        int nr = 2 * wi + half;
        int n  = min(nr, n_nodes - 1);
        float hn = h[(size_t)n * 32 + c];
        float b = sb[c];
        #pragma unroll
        for (int k = 0; k < 32; k++)
            b = fmaf(__shfl(hn, k, 32), sW[k * 32 + c], b);
        if (nr < n_nodes) baseb[(size_t)n * 32 + c] = b;
    }
}

// M1[s][c] = relu(base[dst][c] + sum_k h[src][k]*W1a[k][c] + sum_k ef[k]*W1c[k][c])
// slot-parallel: wave-iter handles 4 slots (2 per half, ILP 2). No LDS.
__global__ void __launch_bounds__(256, 4)
k_msg(const float* __restrict__ h_in, const float* __restrict__ baseb,
      const int4* __restrict__ slots, const float4* __restrict__ ef,
      const float* __restrict__ mw1, float* __restrict__ M1, int n_slots)
{
    const int lane = threadIdx.x & 63;
    const int c    = lane & 31;
    const int half = lane >> 5;

    float w1a[32], w1c[4];
    #pragma unroll
    for (int k = 0; k < 32; k++) w1a[k] = mw1[k * 32 + c];
    #pragma unroll
    for (int k = 0; k < 4; k++)  w1c[k] = mw1[(64 + k) * 32 + c];

    int wave   = (int)((blockIdx.x * 256 + threadIdx.x) >> 6);
    int nwaves = gridDim.x * 4;

    for (int i = wave; 4 * i < n_slots; i += nwaves) {
        int sA = 4 * i + 2 * half;
        int sB = sA + 1;
        int cA = min(sA, n_slots - 1);
        int cB = min(sB, n_slots - 1);
        int4 slA = slots[cA];
        int4 slB = slots[cB];

        const float4* hA = (const float4*)(h_in + (size_t)slA.x * 32);
        const float4* hB = (const float4*)(h_in + (size_t)slB.x * 32);
        float bA = baseb[(size_t)slA.z * 32 + c];
        float bB = baseb[(size_t)slB.z * 32 + c];
        float4 eA = ef[slA.y];
        float4 eB = ef[slB.y];

        float xa[32], xb[32];
        #pragma unroll
        for (int q = 0; q < 8; q++) {
            float4 v = hA[q];
            xa[4 * q] = v.x; xa[4 * q + 1] = v.y;
            xa[4 * q + 2] = v.z; xa[4 * q + 3] = v.w;
        }
        #pragma unroll
        for (int q = 0; q < 8; q++) {
            float4 v = hB[q];
            xb[4 * q] = v.x; xb[4 * q + 1] = v.y;
            xb[4 * q + 2] = v.z; xb[4 * q + 3] = v.w;
        }

        float aA = bA, aB = bB;
        #pragma unroll
        for (int k = 0; k < 32; k++) {
            aA = fmaf(xa[k], w1a[k], aA);
            aB = fmaf(xb[k], w1a[k], aB);
        }
        aA = fmaf(eA.x, w1c[0], aA); aA = fmaf(eA.y, w1c[1], aA);
        aA = fmaf(eA.z, w1c[2], aA); aA = fmaf(eA.w, w1c[3], aA);
        aB = fmaf(eB.x, w1c[0], aB); aB = fmaf(eB.y, w1c[1], aB);
        aB = fmaf(eB.z, w1c[2], aB); aB = fmaf(eB.w, w1c[3], aB);

        if (sA < n_slots) M1[(size_t)sA * 32 + c] = fmaxf(aA, 0.0f);
        if (sB < n_slots) M1[(size_t)sB * 32 + c] = fmaxf(aB, 0.0f);
    }
}

// rsum[n][c] = sum over node n's slots of M1[s][c]; coalesced streaming.
__global__ void __launch_bounds__(256)
k_aggsum(const float* __restrict__ M1, const int* __restrict__ row_start,
         float* __restrict__ rsumb, int n_nodes)
{
    const int lane = threadIdx.x & 63;
    const int c    = lane & 31;
    const int half = lane >> 5;
    int wi = (int)((blockIdx.x * 256 + threadIdx.x) >> 6);
    int nw = gridDim.x * 4;
    for (int n = wi; n < n_nodes; n += nw) {
        int s0 = row_start[n], s1 = row_start[n + 1];
        float r = 0.0f;
        for (int s = s0 + half; s < s1; s += 2)
            r += M1[(size_t)s * 32 + c];
        r += __shfl_xor(r, 32, 64);
        if (lane < 32) rsumb[(size_t)n * 32 + c] = r;
    }
}

// h_out[n] = h[n] + relu([h[n], deg*mb2 + rsum@W2] @ U1 + ub1) @ U2 + ub2
// wave handles 2 nodes (one per half).
__global__ void __launch_bounds__(256)
k_updw(const float* __restrict__ h_in, float* __restrict__ h_out,
       const float* __restrict__ rsumb, const int* __restrict__ row_start,
       const float* __restrict__ mw2, const float* __restrict__ mb2,
       const float* __restrict__ uw1, const float* __restrict__ ub1,
       const float* __restrict__ uw2, const float* __restrict__ ub2,
       int n_nodes)
{
    __shared__ float sW2[32 * 32];
    __shared__ float sU1[64 * 32];
    __shared__ float sU2[32 * 32];
    __shared__ float sB[3 * 32];      // mb2 | ub1 | ub2
    for (int i = threadIdx.x; i < 32 * 32; i += 256) sW2[i] = mw2[i];
    for (int i = threadIdx.x; i < 64 * 32; i += 256) sU1[i] = uw1[i];
    for (int i = threadIdx.x; i < 32 * 32; i += 256) sU2[i] = uw2[i];
    if (threadIdx.x < 32) {
        sB[threadIdx.x]      = mb2[threadIdx.x];
        sB[32 + threadIdx.x] = ub1[threadIdx.x];
        sB[64 + threadIdx.x] = ub2[threadIdx.x];
    }
    __syncthreads();
    const int lane = threadIdx.x & 63;
    const int c    = lane & 31;
    const int half = lane >> 5;
    int wi = (int)((blockIdx.x * 256 + threadIdx.x) >> 6);
    int nw = gridDim.x * 4;
    for (; 2 * wi < n_nodes; wi += nw) {
        int nr = 2 * wi + half;
        int n  = min(nr, n_nodes - 1);
        float hn = h_in[(size_t)n * 32 + c];
        float rs = rsumb[(size_t)n * 32 + c];
        float deg = (float)(row_start[n + 1] - row_start[n]);

        float agg = deg * sB[c];
        #pragma unroll
        for (int k = 0; k < 32; k++)
            agg = fmaf(__shfl(rs, k, 32), sW2[k * 32 + c], agg);

        float a2 = sB[32 + c];
        #pragma unroll
        for (int k = 0; k < 32; k++)
            a2 = fmaf(__shfl(hn, k, 32), sU1[k * 32 + c], a2);
        #pragma unroll
        for (int k = 0; k < 32; k++)
            a2 = fmaf(__shfl(agg, k, 32), sU1[(32 + k) * 32 + c], a2);
        float t = fmaxf(a2, 0.0f);
        float o = sB[64 + c];
        #pragma unroll
        for (int k = 0; k < 32; k++)
            o = fmaf(__shfl(t, k, 32), sU2[k * 32 + c], o);

        if (nr < n_nodes) h_out[(size_t)n * 32 + c] = hn + o;
    }
}

// -------- R16 fallback: fused wave-per-node round (int4 slots) --------
__global__ void __launch_bounds__(256)
k_round_wave(const float* __restrict__ h_in, float* __restrict__ h_out,
        const int* __restrict__ row_start, const int4* __restrict__ slots,
        const float4* __restrict__ ef,
        const float* __restrict__ mw1, const float* __restrict__ mb1,
        const float* __restrict__ mw2, const float* __restrict__ mb2,
        const float* __restrict__ uw1, const float* __restrict__ ub1,
        const float* __restrict__ uw2, const float* __restrict__ ub2,
        int n_nodes)
{
    __shared__ float sW1b[32 * 32];
    __shared__ float sW2[32 * 32];
    __shared__ float sU1[64 * 32];
    __shared__ float sU2[32 * 32];
    __shared__ float sB[4 * 32];
    for (int i = threadIdx.x; i < 32 * 32; i += 256) sW1b[i] = mw1[32 * 32 + i];
    for (int i = threadIdx.x; i < 32 * 32; i += 256) sW2[i]  = mw2[i];
    for (int i = threadIdx.x; i < 64 * 32; i += 256) sU1[i]  = uw1[i];
    for (int i = threadIdx.x; i < 32 * 32; i += 256) sU2[i]  = uw2[i];
    if (threadIdx.x < 32) {
        sB[threadIdx.x]      = mb1[threadIdx.x];
        sB[32 + threadIdx.x] = mb2[threadIdx.x];
        sB[64 + threadIdx.x] = ub1[threadIdx.x];
        sB[96 + threadIdx.x] = ub2[threadIdx.x];
    }
    __syncthreads();

    const int lane = threadIdx.x & 63;
    const int c    = lane & 31;
    const int half = lane >> 5;

    float w1a[32], w1c[4];
    #pragma unroll
    for (int k = 0; k < 32; k++) w1a[k] = mw1[k * 32 + c];
    #pragma unroll
    for (int k = 0; k < 4; k++)  w1c[k] = mw1[(64 + k) * 32 + c];

    int wave   = (int)((blockIdx.x * 256 + threadIdx.x) >> 6);
    int nwaves = gridDim.x * 4;

    for (int n = wave; n < n_nodes; n += nwaves) {
        float hn = h_in[(size_t)n * 32 + c];

        float base = sB[c];
        #pragma unroll
        for (int k = 0; k < 32; k++)
            base = fmaf(__shfl(hn, k, 32), sW1b[k * 32 + c], base);

        int s0 = row_start[n];
        int s1 = row_start[n + 1];
        float rsum = 0.0f;

        for (int s = s0 + half; s < s1; s += 2) {
            int4 sl = slots[s];
            const float4* hs = (const float4*)(h_in + (size_t)sl.x * 32);
            float xs[32];
            #pragma unroll
            for (int q = 0; q < 8; q++) {
                float4 v = hs[q];
                xs[4 * q]     = v.x; xs[4 * q + 1] = v.y;
                xs[4 * q + 2] = v.z; xs[4 * q + 3] = v.w;
            }
            float4 ev = ef[sl.y];

            float acc = base;
            #pragma unroll
            for (int k = 0; k < 32; k++) acc = fmaf(xs[k], w1a[k], acc);
            acc = fmaf(ev.x, w1c[0], acc);
            acc = fmaf(ev.y, w1c[1], acc);
            acc = fmaf(ev.z, w1c[2], acc);
            acc = fmaf(ev.w, w1c[3], acc);
            rsum += fmaxf(acc, 0.0f);
        }
        rsum += __shfl_xor(rsum, 32, 64);

        float deg = (float)(s1 - s0);
        float agg = deg * sB[32 + c];
        #pragma unroll
        for (int k = 0; k < 32; k++)
            agg = fmaf(__shfl(rsum, k, 32), sW2[k * 32 + c], agg);

        float a2 = sB[64 + c];
        #pragma unroll
        for (int k = 0; k < 32; k++)
            a2 = fmaf(__shfl(hn, k, 32), sU1[k * 32 + c], a2);
        #pragma unroll
        for (int k = 0; k < 32; k++)
            a2 = fmaf(__shfl(agg, k, 32), sU1[(32 + k) * 32 + c], a2);
        float t = fmaxf(a2, 0.0f);
        float o = sB[96 + c];
        #pragma unroll
        for (int k = 0; k < 32; k++)
            o = fmaf(__shfl(t, k, 32), sU2[k * 32 + c], o);

        if (lane < 32) h_out[(size_t)n * 32 + c] = hn + o;
    }
}

// -------- R14 fallback kernels (atomic path) --------

__global__ void __launch_bounds__(256)
k_message(const float* __restrict__ h, const int2* __restrict__ edges,
          const float4* __restrict__ ef,
          const float* __restrict__ w1g, const float* __restrict__ b1g,
          const float* __restrict__ w2g, const float* __restrict__ b2g,
          float* __restrict__ agg, int n_edges)
{
    __shared__ float sw1[68 * 32];
    __shared__ float sw2[32 * 32];
    __shared__ float sb1[32];
    __shared__ float sb2[32];
    for (int i = threadIdx.x; i < 68 * 32; i += 256) sw1[i] = w1g[i];
    for (int i = threadIdx.x; i < 32 * 32; i += 256) sw2[i] = w2g[i];
    if (threadIdx.x < 32) {
        sb1[threadIdx.x] = b1g[threadIdx.x];
        sb2[threadIdx.x] = b2g[threadIdx.x];
    }
    __syncthreads();
    int e = blockIdx.x * 256 + threadIdx.x;
    if (e >= n_edges) return;

    int2 ed = edges[e];
    const float4* hs = (const float4*)(h + (size_t)ed.x * 32);
    const float4* hd = (const float4*)(h + (size_t)ed.y * 32);

    float acc[32];
    #pragma unroll
    for (int j = 0; j < 32; j++) acc[j] = sb1[j];
    #pragma unroll 2
    for (int cc = 0; cc < 8; cc++) {
        float4 xv = hs[cc];
        float xsv[4] = {xv.x, xv.y, xv.z, xv.w};
        #pragma unroll
        for (int kk = 0; kk < 4; kk++) {
            float xk = xsv[kk];
            const float* wr = &sw1[(cc * 4 + kk) * 32];
            #pragma unroll
            for (int j = 0; j < 32; j++) acc[j] = fmaf(xk, wr[j], acc[j]);
        }
    }
    #pragma unroll 2
    for (int cc = 0; cc < 8; cc++) {
        float4 xv = hd[cc];
        float xsv[4] = {xv.x, xv.y, xv.z, xv.w};
        #pragma unroll
        for (int kk = 0; kk < 4; kk++) {
            float xk = xsv[kk];
            const float* wr = &sw1[(32 + cc * 4 + kk) * 32];
            #pragma unroll
            for (int j = 0; j < 32; j++) acc[j] = fmaf(xk, wr[j], acc[j]);
        }
    }
    {
        float4 evv = ef[e];
        float ex[4] = {evv.x, evv.y, evv.z, evv.w};
        #pragma unroll
        for (int kk = 0; kk < 4; kk++) {
            float xk = ex[kk];
            const float* wr = &sw1[(64 + kk) * 32];
            #pragma unroll
            for (int j = 0; j < 32; j++) acc[j] = fmaf(xk, wr[j], acc[j]);
        }
    }
    #pragma unroll
    for (int j = 0; j < 32; j++) acc[j] = fmaxf(acc[j], 0.0f);

    float o[32];
    #pragma unroll
    for (int j = 0; j < 32; j++) o[j] = sb2[j];
    #pragma unroll 4
    for (int k = 0; k < 32; k++) {
        float hk = acc[k];
        const float* wr = &sw2[k * 32];
        #pragma unroll
        for (int j = 0; j < 32; j++) o[j] = fmaf(hk, wr[j], o[j]);
    }
    float* ap = agg + (size_t)ed.y * 32;
    #pragma unroll
    for (int j = 0; j < 32; j++) atomicAdd(ap + j, o[j]);
}

__global__ void __launch_bounds__(256)
k_update(float* h, const float* __restrict__ agg,
         const float* __restrict__ w1g, const float* __restrict__ b1g,
         const float* __restrict__ w2g, const float* __restrict__ b2g,
         int n_nodes)
{
    __shared__ float sw1[64 * 32];
    __shared__ float sw2[32 * 32];
    __shared__ float sb1[32];
    __shared__ float sb2[32];
    for (int i = threadIdx.x; i < 64 * 32; i += 256) sw1[i] = w1g[i];
    for (int i = threadIdx.x; i < 32 * 32; i += 256) sw2[i] = w2g[i];
    if (threadIdx.x < 32) {
        sb1[threadIdx.x] = b1g[threadIdx.x];
        sb2[threadIdx.x] = b2g[threadIdx.x];
    }
    __syncthreads();
    int n = blockIdx.x * 256 + threadIdx.x;
    if (n >= n_nodes) return;

    const float4* hp = (const float4*)(h + (size_t)n * 32);
    const float4* ap = (const float4*)(agg + (size_t)n * 32);

    float hv[32];
    float acc[32];
    #pragma unroll
    for (int j = 0; j < 32; j++) acc[j] = sb1[j];
    #pragma unroll 2
    for (int cc = 0; cc < 8; cc++) {
        float4 xv = hp[cc];
        hv[4 * cc] = xv.x; hv[4 * cc + 1] = xv.y; hv[4 * cc + 2] = xv.z; hv[4 * cc + 3] = xv.w;
        float xsv[4] = {xv.x, xv.y, xv.z, xv.w};
        #pragma unroll
        for (int kk = 0; kk < 4; kk++) {
            float xk = xsv[kk];
            const float* wr = &sw1[(cc * 4 + kk) * 32];
            #pragma unroll
            for (int j = 0; j < 32; j++) acc[j] = fmaf(xk, wr[j], acc[j]);
        }
    }
    #pragma unroll 2
    for (int cc = 0; cc < 8; cc++) {
        float4 xv = ap[cc];
        float xsv[4] = {xv.x, xv.y, xv.z, xv.w};
        #pragma unroll
        for (int kk = 0; kk < 4; kk++) {
            float xk = xsv[kk];
            const float* wr = &sw1[(32 + cc * 4 + kk) * 32];
            #pragma unroll
            for (int j = 0; j < 32; j++) acc[j] = fmaf(xk, wr[j], acc[j]);
        }
    }
    #pragma unroll
    for (int j = 0; j < 32; j++) acc[j] = fmaxf(acc[j], 0.0f);

    float o[32];
    #pragma unroll
    for (int j = 0; j < 32; j++) o[j] = sb2[j];
    #pragma unroll 4
    for (int k = 0; k < 32; k++) {
        float hk = acc[k];
        const float* wr = &sw2[k * 32];
        #pragma unroll
        for (int j = 0; j < 32; j++) o[j] = fmaf(hk, wr[j], o[j]);
    }
    float4* op = (float4*)(h + (size_t)n * 32);
    #pragma unroll
    for (int cc = 0; cc < 8; cc++)
        op[cc] = make_float4(hv[4 * cc] + o[4 * cc], hv[4 * cc + 1] + o[4 * cc + 1],
                             hv[4 * cc + 2] + o[4 * cc + 2], hv[4 * cc + 3] + o[4 * cc + 3]);
}

// head: out = (relu(h @ w1 + b1) @ w2 + b2)[:, 0]   (fp32 out)
__global__ void AtomGNN_56169582297457_kernel(const float* h, const float* w1g, const float* b1g, const float* w2g, const float* b2g, float* out, int n_nodes) {
    __shared__ float sw1[32 * 32];
    __shared__ float sb1[32];
    __shared__ float sw2[32];
    __shared__ float sb2;
    for (int i = threadIdx.x; i < 32 * 32; i += 256) sw1[i] = w1g[i];
    if (threadIdx.x < 32) {
        sb1[threadIdx.x] = b1g[threadIdx.x];
        sw2[threadIdx.x] = w2g[threadIdx.x];
    }
    if (threadIdx.x == 0) sb2 = b2g[0];
    __syncthreads();
    int n = blockIdx.x * 256 + threadIdx.x;
    if (n >= n_nodes) return;

    const float4* hp = (const float4*)(h + (size_t)n * 32);
    float x[32];
    #pragma unroll
    for (int cc = 0; cc < 8; cc++) {
        float4 xv = hp[cc];
        x[4 * cc] = xv.x; x[4 * cc + 1] = xv.y; x[4 * cc + 2] = xv.z; x[4 * cc + 3] = xv.w;
    }
    float acc[32];
    #pragma unroll
    for (int j = 0; j < 32; j++) acc[j] = sb1[j];
    #pragma unroll 4
    for (int k = 0; k < 32; k++) {
        float xk = x[k];
        const float* wr = &sw1[k * 32];
        #pragma unroll
        for (int j = 0; j < 32; j++) acc[j] = fmaf(xk, wr[j], acc[j]);
    }
    float val = sb2;
    #pragma unroll
    for (int k = 0; k < 32; k++) val = fmaf(fmaxf(acc[k], 0.0f), sw2[k], val);
    out[n] = val;
}

extern "C" void kernel_launch(void* const* d_in, const int* in_sizes, int n_in,
                              void* d_out, int out_size, void* d_ws, size_t ws_size,
                              hipStream_t stream) {
    const float* nf      = (const float*)d_in[0];
    const int2*  edges   = (const int2*)d_in[1];
    const float4* ef     = (const float4*)d_in[2];
    const float* enc_w1  = (const float*)d_in[3];
    const float* enc_b1  = (const float*)d_in[4];
    const float* enc_w2  = (const float*)d_in[5];
    const float* enc_b2  = (const float*)d_in[6];
    const float* msg_w1  = (const float*)d_in[7];
    const float* msg_b1  = (const float*)d_in[8];
    const float* msg_w2  = (const float*)d_in[9];
    const float* msg_b2  = (const float*)d_in[10];
    const float* upd_w1  = (const float*)d_in[11];
    const float* upd_b1  = (const float*)d_in[12];
    const float* upd_w2  = (const float*)d_in[13];
    const float* upd_b2  = (const float*)d_in[14];
    const float* head_w1 = (const float*)d_in[15];
    const float* head_b1 = (const float*)d_in[16];
    const float* head_w2 = (const float*)d_in[17];
    const float* head_b2 = (const float*)d_in[18];

    int n_nodes = (out_size > 0) ? out_size : NN_REF;
    int n_edges = (in_sizes && n_in > 2 && in_sizes[2] > 0) ? in_sizes[2] / 4 : NE_REF;

    int nb_nodes = (n_nodes + 255) / 256;
    int nb_edges = (n_edges + 255) / 256;

    // Workspace layout (prefix shared with R16 fallback):
    //   h0 | h1 | row_start[n+1] | cursor[n] | bsum[nb] | pad | slots[E] int4
    //   | baseb | rsumb | M1[E*32]
    float* h0 = (float*)d_ws;
    float* h1 = h0 + (size_t)n_nodes * 32;
    int* row_start = (int*)(h1 + (size_t)n_nodes * 32);
    int* cursor = row_start + (n_nodes + 1);
    int* bsum = cursor + n_nodes;
    uintptr_t slots_addr = ((uintptr_t)(bsum + nb_nodes) + 15) & ~(uintptr_t)15;
    int4* slots = (int4*)slots_addr;
    float* baseb = (float*)(slots + (size_t)n_edges);
    float* rsumb = baseb + (size_t)n_nodes * 32;
    float* M1    = rsumb + (size_t)n_nodes * 32;

    size_t required_csr  = (slots_addr - (uintptr_t)d_ws) + (size_t)n_edges * 16;
    size_t required_full = required_csr + (size_t)n_nodes * 32 * 4 * 2
                         + (size_t)n_edges * 32 * 4;

    bool ws_any   = (ws_size == 0);
    bool full_ok  = (nb_nodes <= 1024) && (ws_any || ws_size >= required_full);
    bool csr_ok   = (nb_nodes <= 1024) && (ws_any || ws_size >= required_csr);

    if (full_ok || csr_ok) {
        k_encode<<<nb_nodes, 256, 0, stream>>>(nf, enc_w1, enc_b1, enc_w2, enc_b2, h0, n_nodes);

        // build dst-CSR once (edges identical across rounds)
        k_zero<<<256, 256, 0, stream>>>((float*)cursor, n_nodes);
        k_hist<<<nb_edges, 256, 0, stream>>>(edges, cursor, n_edges);
        k_scan_block<<<nb_nodes, 256, 0, stream>>>(cursor, row_start, bsum, n_nodes);
        k_scan_bsum<<<1, 1024, 0, stream>>>(bsum, nb_nodes, row_start, n_nodes, n_edges);
        k_scan_add<<<nb_nodes, 256, 0, stream>>>(row_start, cursor, bsum, n_nodes);
        k_fill<<<nb_edges, 256, 0, stream>>>(edges, cursor, slots, n_edges);

        for (int r = 0; r < 2; r++) {
            const float* hin = (r == 0) ? h0 : h1;
            float* hout      = (r == 0) ? h1 : h0;
            const float* mw1 = msg_w1 + (size_t)r * 68 * 32;
            const float* mb1 = msg_b1 + (size_t)r * 32;
            const float* mw2 = msg_w2 + (size_t)r * 32 * 32;
            const float* mb2 = msg_b2 + (size_t)r * 32;
            const float* uw1 = upd_w1 + (size_t)r * 64 * 32;
            const float* ub1 = upd_b1 + (size_t)r * 32;
            const float* uw2 = upd_w2 + (size_t)r * 32 * 32;
            const float* ub2 = upd_b2 + (size_t)r * 32;

            if (full_ok) {
                k_base<<<1024, 256, 0, stream>>>(hin, mw1, mb1, baseb, n_nodes);
                k_msg<<<2048, 256, 0, stream>>>(hin, baseb, slots, ef, mw1, M1, n_edges);
                k_aggsum<<<2048, 256, 0, stream>>>(M1, row_start, rsumb, n_nodes);
                k_updw<<<1024, 256, 0, stream>>>(hin, hout, rsumb, row_start,
                                                 mw2, mb2, uw1, ub1, uw2, ub2, n_nodes);
            } else {
                k_round_wave<<<2048, 256, 0, stream>>>(
                    hin, hout, row_start, slots, ef,
                    mw1, mb1, mw2, mb2, uw1, ub1, uw2, ub2, n_nodes);
            }
        }

        AtomGNN_56169582297457_kernel<<<nb_nodes, 256, 0, stream>>>(
            h0, head_w1, head_b1, head_w2, head_b2, (float*)d_out, n_nodes);
    } else {
        // R14 fallback: atomic scatter path
        float* h   = (float*)d_ws;
        float* agg = h + (size_t)n_nodes * 32;

        k_encode<<<nb_nodes, 256, 0, stream>>>(nf, enc_w1, enc_b1, enc_w2, enc_b2, h, n_nodes);
        for (int r = 0; r < 2; r++) {
            k_zero<<<1024, 256, 0, stream>>>(agg, n_nodes * 32);
            k_message<<<nb_edges, 256, 0, stream>>>(
                h, edges, ef,
                msg_w1 + (size_t)r * 68 * 32, msg_b1 + (size_t)r * 32,
                msg_w2 + (size_t)r * 32 * 32, msg_b2 + (size_t)r * 32,
                agg, n_edges);
            k_update<<<nb_nodes, 256, 0, stream>>>(
                h, agg,
                upd_w1 + (size_t)r * 64 * 32, upd_b1 + (size_t)r * 32,
                upd_w2 + (size_t)r * 32 * 32, upd_b2 + (size_t)r * 32,
                n_nodes);
        }
        AtomGNN_56169582297457_kernel<<<nb_nodes, 256, 0, stream>>>(
            h, head_w1, head_b1, head_w2, head_b2, (float*)d_out, n_nodes);
    }
}

// Round 4
// 3037.824 us; speedup vs baseline: 1.0654x; 1.0654x over previous
//
#include <hip/hip_runtime.h>
#include <cstdio>
#include <cstdint>

// R18: in-place ILP for the fused round kernel. R17's 4-kernel split never ran
// (M1 needed 513MB > ws); counters showed the R16 fallback again: latency-bound
// (VALUBusy 12%, occ 11%, VGPR 140, ~2 dependent gather chains/wave). R18 keeps
// the proven 78MB CSR layout and rewrites the fused kernel: lane-column gather
// (lane c loads h[src*32+c], 1 VGPR/edge instead of 32) + __shfl(x,k,32)
// broadcast in the FMA chain -> 4 edges in flight per half-wave (12 independent
// loads/iter, 4 interleaved shfl/FMA chains), launch_bounds(256,4) caps VGPR
// at 128 for 4 waves/SIMD = 16 chains/SIMD vs R16's ~3. shfl cost ~21us/round
// issue floor (LDS pipe, overlaps VALU across waves). R14 atomic path kept as
// deep fallback.

__attribute__((constructor)) static void atomgnn_r18_load_beacon() {
    fprintf(stderr, "ATOMGNN_R18_SOURCE_LOADED\n");
    fflush(stderr);
}

#define NN_REF 100000
#define NE_REF 3200000

// zero a float/int buffer (4B words), grid-stride
__global__ void __launch_bounds__(256)
k_zero(float* __restrict__ p, int n)
{
    int i = blockIdx.x * 256 + threadIdx.x;
    int stride = gridDim.x * 256;
    for (; i < n; i += stride) p[i] = 0.0f;
}

// encoder: h = relu(nf @ w1 + b1) @ w2 + b2   (16 -> 32 -> 32)
__global__ void __launch_bounds__(256)
k_encode(const float* __restrict__ nf,
         const float* __restrict__ w1g, const float* __restrict__ b1g,
         const float* __restrict__ w2g, const float* __restrict__ b2g,
         float* __restrict__ h, int n_nodes)
{
    __shared__ float sw1[16 * 32];
    __shared__ float sw2[32 * 32];
    __shared__ float sb1[32];
    __shared__ float sb2[32];
    for (int i = threadIdx.x; i < 16 * 32; i += 256) sw1[i] = w1g[i];
    for (int i = threadIdx.x; i < 32 * 32; i += 256) sw2[i] = w2g[i];
    if (threadIdx.x < 32) {
        sb1[threadIdx.x] = b1g[threadIdx.x];
        sb2[threadIdx.x] = b2g[threadIdx.x];
    }
    __syncthreads();
    int n = blockIdx.x * 256 + threadIdx.x;
    if (n >= n_nodes) return;

    const float4* p = (const float4*)(nf + (size_t)n * 16);
    float x[16];
    #pragma unroll
    for (int c = 0; c < 4; c++) {
        float4 v = p[c];
        x[4 * c] = v.x; x[4 * c + 1] = v.y; x[4 * c + 2] = v.z; x[4 * c + 3] = v.w;
    }

    float acc[32];
    #pragma unroll
    for (int j = 0; j < 32; j++) acc[j] = sb1[j];
    #pragma unroll 4
    for (int k = 0; k < 16; k++) {
        float xk = x[k];
        const float* wr = &sw1[k * 32];
        #pragma unroll
        for (int j = 0; j < 32; j++) acc[j] = fmaf(xk, wr[j], acc[j]);
    }
    #pragma unroll
    for (int j = 0; j < 32; j++) acc[j] = fmaxf(acc[j], 0.0f);

    float o[32];
    #pragma unroll
    for (int j = 0; j < 32; j++) o[j] = sb2[j];
    #pragma unroll 4
    for (int k = 0; k < 32; k++) {
        float hk = acc[k];
        const float* wr = &sw2[k * 32];
        #pragma unroll
        for (int j = 0; j < 32; j++) o[j] = fmaf(hk, wr[j], o[j]);
    }
    float4* hp = (float4*)(h + (size_t)n * 32);
    #pragma unroll
    for (int c = 0; c < 8; c++)
        hp[c] = make_float4(o[4 * c], o[4 * c + 1], o[4 * c + 2], o[4 * c + 3]);
}

// -------- CSR build: histogram -> exclusive scan -> fill --------

__global__ void __launch_bounds__(256)
k_hist(const int2* __restrict__ edges, int* __restrict__ cnt, int n_edges)
{
    int e = blockIdx.x * 256 + threadIdx.x;
    if (e >= n_edges) return;
    atomicAdd(&cnt[edges[e].y], 1);
}

__global__ void __launch_bounds__(256)
k_scan_block(const int* __restrict__ cnt, int* __restrict__ rs,
             int* __restrict__ bsum, int n)
{
    __shared__ int sd[256];
    int t = threadIdx.x;
    int i = blockIdx.x * 256 + t;
    int v = (i < n) ? cnt[i] : 0;
    sd[t] = v;
    __syncthreads();
    int val = v;
    for (int off = 1; off < 256; off <<= 1) {
        int add = (t >= off) ? sd[t - off] : 0;
        __syncthreads();
        val += add;
        sd[t] = val;
        __syncthreads();
    }
    if (i < n) rs[i] = val - v;           // exclusive within block
    if (t == 255) bsum[blockIdx.x] = val; // block total
}

__global__ void __launch_bounds__(1024)
k_scan_bsum(int* __restrict__ bsum, int nb, int* __restrict__ rs,
            int n_nodes, int n_edges)
{
    __shared__ int sd[1024];
    int t = threadIdx.x;
    int v = (t < nb) ? bsum[t] : 0;
    sd[t] = v;
    __syncthreads();
    int val = v;
    for (int off = 1; off < 1024; off <<= 1) {
        int add = (t >= off) ? sd[t - off] : 0;
        __syncthreads();
        val += add;
        sd[t] = val;
        __syncthreads();
    }
    if (t < nb) bsum[t] = val - v;  // exclusive prefix of block totals
    if (t == 0) rs[n_nodes] = n_edges;
}

__global__ void __launch_bounds__(256)
k_scan_add(int* __restrict__ rs, int* __restrict__ cursor,
           const int* __restrict__ bsum, int n)
{
    int i = blockIdx.x * 256 + threadIdx.x;
    if (i < n) {
        int v = rs[i] + bsum[blockIdx.x];
        rs[i] = v;
        cursor[i] = v;
    }
}

// scatter edges into dst-sorted slots: slot = (src, edge_idx, dst, 0)
__global__ void __launch_bounds__(256)
k_fill(const int2* __restrict__ edges, int* __restrict__ cursor,
       int4* __restrict__ slots, int n_edges)
{
    int e = blockIdx.x * 256 + threadIdx.x;
    if (e >= n_edges) return;
    int2 ed = edges[e];
    int pos = atomicAdd(&cursor[ed.y], 1);
    slots[pos] = make_int4(ed.x, e, ed.y, 0);
}

// -------- fused round v2: wave-per-node, lane-column, 4-edge ILP --------
// lane c owns column c; halves process interleaved slots; per half-wave,
// 4 edges in flight. x gather is 1 reg/edge (lane c loads h[src*32+c]),
// k-loop broadcasts x via __shfl(x,k,32).
__global__ void __launch_bounds__(256, 4)
k_round_wave2(const float* __restrict__ h_in, float* __restrict__ h_out,
        const int* __restrict__ row_start, const int4* __restrict__ slots,
        const float4* __restrict__ ef,
        const float* __restrict__ mw1, const float* __restrict__ mb1,
        const float* __restrict__ mw2, const float* __restrict__ mb2,
        const float* __restrict__ uw1, const float* __restrict__ ub1,
        const float* __restrict__ uw2, const float* __restrict__ ub2,
        int n_nodes)
{
    __shared__ float sW1b[32 * 32];   // msg_w1 rows 32..63 (dst half)
    __shared__ float sW2[32 * 32];
    __shared__ float sU1[64 * 32];
    __shared__ float sU2[32 * 32];
    __shared__ float sB[4 * 32];      // mb1 | mb2 | ub1 | ub2
    for (int i = threadIdx.x; i < 32 * 32; i += 256) sW1b[i] = mw1[32 * 32 + i];
    for (int i = threadIdx.x; i < 32 * 32; i += 256) sW2[i]  = mw2[i];
    for (int i = threadIdx.x; i < 64 * 32; i += 256) sU1[i]  = uw1[i];
    for (int i = threadIdx.x; i < 32 * 32; i += 256) sU2[i]  = uw2[i];
    if (threadIdx.x < 32) {
        sB[threadIdx.x]      = mb1[threadIdx.x];
        sB[32 + threadIdx.x] = mb2[threadIdx.x];
        sB[64 + threadIdx.x] = ub1[threadIdx.x];
        sB[96 + threadIdx.x] = ub2[threadIdx.x];
    }
    __syncthreads();

    const int lane = threadIdx.x & 63;
    const int c    = lane & 31;
    const int half = lane >> 5;

    // per-lane private msg-W1 src column (k=0..31) + ef column (k=0..3)
    float w1a[32], w1c[4];
    #pragma unroll
    for (int k = 0; k < 32; k++) w1a[k] = mw1[k * 32 + c];
    #pragma unroll
    for (int k = 0; k < 4; k++)  w1c[k] = mw1[(64 + k) * 32 + c];

    int wave   = (int)((blockIdx.x * 256 + threadIdx.x) >> 6);
    int nwaves = gridDim.x * 4;

    for (int n = wave; n < n_nodes; n += nwaves) {
        float hn = h_in[(size_t)n * 32 + c];

        // base = mb1 + h[n] @ W1b (dst-half hoisted out of the edge loop)
        float base = sB[c];
        #pragma unroll
        for (int k = 0; k < 32; k++)
            base = fmaf(__shfl(hn, k, 32), sW1b[k * 32 + c], base);

        int s0 = row_start[n];
        int s1 = row_start[n + 1];
        float rsum = 0.0f;

        int s = s0 + half;   // this half's slots: s, s+2, s+4, ...
        // main loop: 4 edges per half in flight
        for (; s + 6 < s1; s += 8) {
            int4 sl0 = slots[s];
            int4 sl1 = slots[s + 2];
            int4 sl2 = slots[s + 4];
            int4 sl3 = slots[s + 6];
            float x0 = h_in[(size_t)sl0.x * 32 + c];
            float x1 = h_in[(size_t)sl1.x * 32 + c];
            float x2 = h_in[(size_t)sl2.x * 32 + c];
            float x3 = h_in[(size_t)sl3.x * 32 + c];
            float4 e0 = ef[sl0.y];
            float4 e1 = ef[sl1.y];
            float4 e2 = ef[sl2.y];
            float4 e3 = ef[sl3.y];

            float a0 = base, a1 = base, a2 = base, a3 = base;
            #pragma unroll
            for (int k = 0; k < 32; k++) {
                a0 = fmaf(__shfl(x0, k, 32), w1a[k], a0);
                a1 = fmaf(__shfl(x1, k, 32), w1a[k], a1);
                a2 = fmaf(__shfl(x2, k, 32), w1a[k], a2);
                a3 = fmaf(__shfl(x3, k, 32), w1a[k], a3);
            }
            a0 = fmaf(e0.x, w1c[0], a0); a0 = fmaf(e0.y, w1c[1], a0);
            a0 = fmaf(e0.z, w1c[2], a0); a0 = fmaf(e0.w, w1c[3], a0);
            a1 = fmaf(e1.x, w1c[0], a1); a1 = fmaf(e1.y, w1c[1], a1);
            a1 = fmaf(e1.z, w1c[2], a1); a1 = fmaf(e1.w, w1c[3], a1);
            a2 = fmaf(e2.x, w1c[0], a2); a2 = fmaf(e2.y, w1c[1], a2);
            a2 = fmaf(e2.z, w1c[2], a2); a2 = fmaf(e2.w, w1c[3], a2);
            a3 = fmaf(e3.x, w1c[0], a3); a3 = fmaf(e3.y, w1c[1], a3);
            a3 = fmaf(e3.z, w1c[2], a3); a3 = fmaf(e3.w, w1c[3], a3);

            rsum += fmaxf(a0, 0.0f);
            rsum += fmaxf(a1, 0.0f);
            rsum += fmaxf(a2, 0.0f);
            rsum += fmaxf(a3, 0.0f);
        }
        // tail: one edge at a time (within a half all 32 lanes uniform, so
        // width-32 shfl stays inside the active half even if halves diverge)
        for (; s < s1; s += 2) {
            int4 sl = slots[s];
            float x = h_in[(size_t)sl.x * 32 + c];
            float4 ev = ef[sl.y];
            float a = base;
            #pragma unroll
            for (int k = 0; k < 32; k++)
                a = fmaf(__shfl(x, k, 32), w1a[k], a);
            a = fmaf(ev.x, w1c[0], a); a = fmaf(ev.y, w1c[1], a);
            a = fmaf(ev.z, w1c[2], a); a = fmaf(ev.w, w1c[3], a);
            rsum += fmaxf(a, 0.0f);
        }
        // combine halves (both halves active/converged here)
        rsum += __shfl_xor(rsum, 32, 64);

        // agg = deg*mb2 + rsum @ W2 (W2 hoisted by linearity)
        float deg = (float)(s1 - s0);
        float agg = deg * sB[32 + c];
        #pragma unroll
        for (int k = 0; k < 32; k++)
            agg = fmaf(__shfl(rsum, k, 32), sW2[k * 32 + c], agg);

        // update MLP
        float a2v = sB[64 + c];
        #pragma unroll
        for (int k = 0; k < 32; k++)
            a2v = fmaf(__shfl(hn, k, 32), sU1[k * 32 + c], a2v);
        #pragma unroll
        for (int k = 0; k < 32; k++)
            a2v = fmaf(__shfl(agg, k, 32), sU1[(32 + k) * 32 + c], a2v);
        float t = fmaxf(a2v, 0.0f);
        float o = sB[96 + c];
        #pragma unroll
        for (int k = 0; k < 32; k++)
            o = fmaf(__shfl(t, k, 32), sU2[k * 32 + c], o);

        if (lane < 32) h_out[(size_t)n * 32 + c] = hn + o;
    }
}

// -------- R14 fallback kernels (atomic path), used only if ws too small -----

__global__ void __launch_bounds__(256)
k_message(const float* __restrict__ h, const int2* __restrict__ edges,
          const float4* __restrict__ ef,
          const float* __restrict__ w1g, const float* __restrict__ b1g,
          const float* __restrict__ w2g, const float* __restrict__ b2g,
          float* __restrict__ agg, int n_edges)
{
    __shared__ float sw1[68 * 32];
    __shared__ float sw2[32 * 32];
    __shared__ float sb1[32];
    __shared__ float sb2[32];
    for (int i = threadIdx.x; i < 68 * 32; i += 256) sw1[i] = w1g[i];
    for (int i = threadIdx.x; i < 32 * 32; i += 256) sw2[i] = w2g[i];
    if (threadIdx.x < 32) {
        sb1[threadIdx.x] = b1g[threadIdx.x];
        sb2[threadIdx.x] = b2g[threadIdx.x];
    }
    __syncthreads();
    int e = blockIdx.x * 256 + threadIdx.x;
    if (e >= n_edges) return;

    int2 ed = edges[e];
    const float4* hs = (const float4*)(h + (size_t)ed.x * 32);
    const float4* hd = (const float4*)(h + (size_t)ed.y * 32);

    float acc[32];
    #pragma unroll
    for (int j = 0; j < 32; j++) acc[j] = sb1[j];
    #pragma unroll 2
    for (int cc = 0; cc < 8; cc++) {
        float4 xv = hs[cc];
        float xsv[4] = {xv.x, xv.y, xv.z, xv.w};
        #pragma unroll
        for (int kk = 0; kk < 4; kk++) {
            float xk = xsv[kk];
            const float* wr = &sw1[(cc * 4 + kk) * 32];
            #pragma unroll
            for (int j = 0; j < 32; j++) acc[j] = fmaf(xk, wr[j], acc[j]);
        }
    }
    #pragma unroll 2
    for (int cc = 0; cc < 8; cc++) {
        float4 xv = hd[cc];
        float xsv[4] = {xv.x, xv.y, xv.z, xv.w};
        #pragma unroll
        for (int kk = 0; kk < 4; kk++) {
            float xk = xsv[kk];
            const float* wr = &sw1[(32 + cc * 4 + kk) * 32];
            #pragma unroll
            for (int j = 0; j < 32; j++) acc[j] = fmaf(xk, wr[j], acc[j]);
        }
    }
    {
        float4 evv = ef[e];
        float ex[4] = {evv.x, evv.y, evv.z, evv.w};
        #pragma unroll
        for (int kk = 0; kk < 4; kk++) {
            float xk = ex[kk];
            const float* wr = &sw1[(64 + kk) * 32];
            #pragma unroll
            for (int j = 0; j < 32; j++) acc[j] = fmaf(xk, wr[j], acc[j]);
        }
    }
    #pragma unroll
    for (int j = 0; j < 32; j++) acc[j] = fmaxf(acc[j], 0.0f);

    float o[32];
    #pragma unroll
    for (int j = 0; j < 32; j++) o[j] = sb2[j];
    #pragma unroll 4
    for (int k = 0; k < 32; k++) {
        float hk = acc[k];
        const float* wr = &sw2[k * 32];
        #pragma unroll
        for (int j = 0; j < 32; j++) o[j] = fmaf(hk, wr[j], o[j]);
    }
    float* ap = agg + (size_t)ed.y * 32;
    #pragma unroll
    for (int j = 0; j < 32; j++) atomicAdd(ap + j, o[j]);
}

__global__ void __launch_bounds__(256)
k_update(float* h, const float* __restrict__ agg,
         const float* __restrict__ w1g, const float* __restrict__ b1g,
         const float* __restrict__ w2g, const float* __restrict__ b2g,
         int n_nodes)
{
    __shared__ float sw1[64 * 32];
    __shared__ float sw2[32 * 32];
    __shared__ float sb1[32];
    __shared__ float sb2[32];
    for (int i = threadIdx.x; i < 64 * 32; i += 256) sw1[i] = w1g[i];
    for (int i = threadIdx.x; i < 32 * 32; i += 256) sw2[i] = w2g[i];
    if (threadIdx.x < 32) {
        sb1[threadIdx.x] = b1g[threadIdx.x];
        sb2[threadIdx.x] = b2g[threadIdx.x];
    }
    __syncthreads();
    int n = blockIdx.x * 256 + threadIdx.x;
    if (n >= n_nodes) return;

    const float4* hp = (const float4*)(h + (size_t)n * 32);
    const float4* ap = (const float4*)(agg + (size_t)n * 32);

    float hv[32];
    float acc[32];
    #pragma unroll
    for (int j = 0; j < 32; j++) acc[j] = sb1[j];
    #pragma unroll 2
    for (int cc = 0; cc < 8; cc++) {
        float4 xv = hp[cc];
        hv[4 * cc] = xv.x; hv[4 * cc + 1] = xv.y; hv[4 * cc + 2] = xv.z; hv[4 * cc + 3] = xv.w;
        float xsv[4] = {xv.x, xv.y, xv.z, xv.w};
        #pragma unroll
        for (int kk = 0; kk < 4; kk++) {
            float xk = xsv[kk];
            const float* wr = &sw1[(cc * 4 + kk) * 32];
            #pragma unroll
            for (int j = 0; j < 32; j++) acc[j] = fmaf(xk, wr[j], acc[j]);
        }
    }
    #pragma unroll 2
    for (int cc = 0; cc < 8; cc++) {
        float4 xv = ap[cc];
        float xsv[4] = {xv.x, xv.y, xv.z, xv.w};
        #pragma unroll
        for (int kk = 0; kk < 4; kk++) {
            float xk = xsv[kk];
            const float* wr = &sw1[(32 + cc * 4 + kk) * 32];
            #pragma unroll
            for (int j = 0; j < 32; j++) acc[j] = fmaf(xk, wr[j], acc[j]);
        }
    }
    #pragma unroll
    for (int j = 0; j < 32; j++) acc[j] = fmaxf(acc[j], 0.0f);

    float o[32];
    #pragma unroll
    for (int j = 0; j < 32; j++) o[j] = sb2[j];
    #pragma unroll 4
    for (int k = 0; k < 32; k++) {
        float hk = acc[k];
        const float* wr = &sw2[k * 32];
        #pragma unroll
        for (int j = 0; j < 32; j++) o[j] = fmaf(hk, wr[j], o[j]);
    }
    float4* op = (float4*)(h + (size_t)n * 32);
    #pragma unroll
    for (int cc = 0; cc < 8; cc++)
        op[cc] = make_float4(hv[4 * cc] + o[4 * cc], hv[4 * cc + 1] + o[4 * cc + 1],
                             hv[4 * cc + 2] + o[4 * cc + 2], hv[4 * cc + 3] + o[4 * cc + 3]);
}

// head: out = (relu(h @ w1 + b1) @ w2 + b2)[:, 0]   (fp32 out)
__global__ void AtomGNN_56169582297457_kernel(const float* h, const float* w1g, const float* b1g, const float* w2g, const float* b2g, float* out, int n_nodes) {
    __shared__ float sw1[32 * 32];
    __shared__ float sb1[32];
    __shared__ float sw2[32];
    __shared__ float sb2;
    for (int i = threadIdx.x; i < 32 * 32; i += 256) sw1[i] = w1g[i];
    if (threadIdx.x < 32) {
        sb1[threadIdx.x] = b1g[threadIdx.x];
        sw2[threadIdx.x] = w2g[threadIdx.x];
    }
    if (threadIdx.x == 0) sb2 = b2g[0];
    __syncthreads();
    int n = blockIdx.x * 256 + threadIdx.x;
    if (n >= n_nodes) return;

    const float4* hp = (const float4*)(h + (size_t)n * 32);
    float x[32];
    #pragma unroll
    for (int cc = 0; cc < 8; cc++) {
        float4 xv = hp[cc];
        x[4 * cc] = xv.x; x[4 * cc + 1] = xv.y; x[4 * cc + 2] = xv.z; x[4 * cc + 3] = xv.w;
    }
    float acc[32];
    #pragma unroll
    for (int j = 0; j < 32; j++) acc[j] = sb1[j];
    #pragma unroll 4
    for (int k = 0; k < 32; k++) {
        float xk = x[k];
        const float* wr = &sw1[k * 32];
        #pragma unroll
        for (int j = 0; j < 32; j++) acc[j] = fmaf(xk, wr[j], acc[j]);
    }
    float val = sb2;
    #pragma unroll
    for (int k = 0; k < 32; k++) val = fmaf(fmaxf(acc[k], 0.0f), sw2[k], val);
    out[n] = val;
}

extern "C" void kernel_launch(void* const* d_in, const int* in_sizes, int n_in,
                              void* d_out, int out_size, void* d_ws, size_t ws_size,
                              hipStream_t stream) {
    const float* nf      = (const float*)d_in[0];
    const int2*  edges   = (const int2*)d_in[1];
    const float4* ef     = (const float4*)d_in[2];
    const float* enc_w1  = (const float*)d_in[3];
    const float* enc_b1  = (const float*)d_in[4];
    const float* enc_w2  = (const float*)d_in[5];
    const float* enc_b2  = (const float*)d_in[6];
    const float* msg_w1  = (const float*)d_in[7];
    const float* msg_b1  = (const float*)d_in[8];
    const float* msg_w2  = (const float*)d_in[9];
    const float* msg_b2  = (const float*)d_in[10];
    const float* upd_w1  = (const float*)d_in[11];
    const float* upd_b1  = (const float*)d_in[12];
    const float* upd_w2  = (const float*)d_in[13];
    const float* upd_b2  = (const float*)d_in[14];
    const float* head_w1 = (const float*)d_in[15];
    const float* head_b1 = (const float*)d_in[16];
    const float* head_w2 = (const float*)d_in[17];
    const float* head_b2 = (const float*)d_in[18];

    int n_nodes = (out_size > 0) ? out_size : NN_REF;
    int n_edges = (in_sizes && n_in > 2 && in_sizes[2] > 0) ? in_sizes[2] / 4 : NE_REF;

    int nb_nodes = (n_nodes + 255) / 256;
    int nb_edges = (n_edges + 255) / 256;

    // CSR workspace layout (proven to fit):
    //   h0 | h1 | row_start[n+1] | cursor[n] | bsum[nb] | pad | slots[E] int4
    float* h0 = (float*)d_ws;
    float* h1 = h0 + (size_t)n_nodes * 32;
    int* row_start = (int*)(h1 + (size_t)n_nodes * 32);
    int* cursor = row_start + (n_nodes + 1);
    int* bsum = cursor + n_nodes;
    uintptr_t slots_addr = ((uintptr_t)(bsum + nb_nodes) + 15) & ~(uintptr_t)15;
    int4* slots = (int4*)slots_addr;
    size_t required_csr = (slots_addr - (uintptr_t)d_ws) + (size_t)n_edges * 16;

    bool csr_ok = (nb_nodes <= 1024) &&
                  (ws_size == 0 || ws_size >= required_csr);

    if (csr_ok) {
        k_encode<<<nb_nodes, 256, 0, stream>>>(nf, enc_w1, enc_b1, enc_w2, enc_b2, h0, n_nodes);

        // build dst-CSR once (edges identical across rounds)
        k_zero<<<256, 256, 0, stream>>>((float*)cursor, n_nodes);
        k_hist<<<nb_edges, 256, 0, stream>>>(edges, cursor, n_edges);
        k_scan_block<<<nb_nodes, 256, 0, stream>>>(cursor, row_start, bsum, n_nodes);
        k_scan_bsum<<<1, 1024, 0, stream>>>(bsum, nb_nodes, row_start, n_nodes, n_edges);
        k_scan_add<<<nb_nodes, 256, 0, stream>>>(row_start, cursor, bsum, n_nodes);
        k_fill<<<nb_edges, 256, 0, stream>>>(edges, cursor, slots, n_edges);

        // ping-pong rounds: h0 -> h1 -> h0
        for (int r = 0; r < 2; r++) {
            const float* hin = (r == 0) ? h0 : h1;
            float* hout      = (r == 0) ? h1 : h0;
            k_round_wave2<<<2048, 256, 0, stream>>>(
                hin, hout, row_start, slots, ef,
                msg_w1 + (size_t)r * 68 * 32, msg_b1 + (size_t)r * 32,
                msg_w2 + (size_t)r * 32 * 32, msg_b2 + (size_t)r * 32,
                upd_w1 + (size_t)r * 64 * 32, upd_b1 + (size_t)r * 32,
                upd_w2 + (size_t)r * 32 * 32, upd_b2 + (size_t)r * 32,
                n_nodes);
        }

        AtomGNN_56169582297457_kernel<<<nb_nodes, 256, 0, stream>>>(
            h0, head_w1, head_b1, head_w2, head_b2, (float*)d_out, n_nodes);
    } else {
        // R14 fallback: atomic scatter path
        float* h   = (float*)d_ws;
        float* agg = h + (size_t)n_nodes * 32;

        k_encode<<<nb_nodes, 256, 0, stream>>>(nf, enc_w1, enc_b1, enc_w2, enc_b2, h, n_nodes);
        for (int r = 0; r < 2; r++) {
            k_zero<<<1024, 256, 0, stream>>>(agg, n_nodes * 32);
            k_message<<<nb_edges, 256, 0, stream>>>(
                h, edges, ef,
                msg_w1 + (size_t)r * 68 * 32, msg_b1 + (size_t)r * 32,
                msg_w2 + (size_t)r * 32 * 32, msg_b2 + (size_t)r * 32,
                agg, n_edges);
            k_update<<<nb_nodes, 256, 0, stream>>>(
                h, agg,
                upd_w1 + (size_t)r * 64 * 32, upd_b1 + (size_t)r * 32,
                upd_w2 + (size_t)r * 32 * 32, upd_b2 + (size_t)r * 32,
                n_nodes);
        }
        AtomGNN_56169582297457_kernel<<<nb_nodes, 256, 0, stream>>>(
            h, head_w1, head_b1, head_w2, head_b2, (float*)d_out, n_nodes);
    }
}

// Round 5
// 2025.129 us; speedup vs baseline: 1.5981x; 1.5001x over previous
//
#include <hip/hip_runtime.h>
#include <cstdio>
#include <cstdint>

// R19: algebraic gather-compression. R18 was traffic-bound: FETCH 2.06GB/round
// at ~2.08TB/s fabric BW == kernel duration; per-edge cost was 32 shfl + 32 FMA
// (VALUBusy 13.5% throttles load issue). R19 precomputes g = h @ W1a per round
// (per-NODE, 12.8MB buffer, ~40us) so the per-edge work collapses to: gather
// g[src] row (same 128B) + 4 ef FMAs + relu -> ~10 instr/edge. Slots slim to
// int2 (src,e) -- dst field was dead. Workspace ~65MB < proven 77.6MB fit.
// Held in reserve (risk): fp16 g (halves gather bytes, ~5e-4 extra error),
// cooperative src-banding (L2-resident sweep). R14 atomic path kept as
// fallback.

__attribute__((constructor)) static void atomgnn_r19_load_beacon() {
    fprintf(stderr, "ATOMGNN_R19_SOURCE_LOADED\n");
    fflush(stderr);
}

#define NN_REF 100000
#define NE_REF 3200000

// zero a float/int buffer (4B words), grid-stride
__global__ void __launch_bounds__(256)
k_zero(float* __restrict__ p, int n)
{
    int i = blockIdx.x * 256 + threadIdx.x;
    int stride = gridDim.x * 256;
    for (; i < n; i += stride) p[i] = 0.0f;
}

// encoder: h = relu(nf @ w1 + b1) @ w2 + b2   (16 -> 32 -> 32)
__global__ void __launch_bounds__(256)
k_encode(const float* __restrict__ nf,
         const float* __restrict__ w1g, const float* __restrict__ b1g,
         const float* __restrict__ w2g, const float* __restrict__ b2g,
         float* __restrict__ h, int n_nodes)
{
    __shared__ float sw1[16 * 32];
    __shared__ float sw2[32 * 32];
    __shared__ float sb1[32];
    __shared__ float sb2[32];
    for (int i = threadIdx.x; i < 16 * 32; i += 256) sw1[i] = w1g[i];
    for (int i = threadIdx.x; i < 32 * 32; i += 256) sw2[i] = w2g[i];
    if (threadIdx.x < 32) {
        sb1[threadIdx.x] = b1g[threadIdx.x];
        sb2[threadIdx.x] = b2g[threadIdx.x];
    }
    __syncthreads();
    int n = blockIdx.x * 256 + threadIdx.x;
    if (n >= n_nodes) return;

    const float4* p = (const float4*)(nf + (size_t)n * 16);
    float x[16];
    #pragma unroll
    for (int c = 0; c < 4; c++) {
        float4 v = p[c];
        x[4 * c] = v.x; x[4 * c + 1] = v.y; x[4 * c + 2] = v.z; x[4 * c + 3] = v.w;
    }

    float acc[32];
    #pragma unroll
    for (int j = 0; j < 32; j++) acc[j] = sb1[j];
    #pragma unroll 4
    for (int k = 0; k < 16; k++) {
        float xk = x[k];
        const float* wr = &sw1[k * 32];
        #pragma unroll
        for (int j = 0; j < 32; j++) acc[j] = fmaf(xk, wr[j], acc[j]);
    }
    #pragma unroll
    for (int j = 0; j < 32; j++) acc[j] = fmaxf(acc[j], 0.0f);

    float o[32];
    #pragma unroll
    for (int j = 0; j < 32; j++) o[j] = sb2[j];
    #pragma unroll 4
    for (int k = 0; k < 32; k++) {
        float hk = acc[k];
        const float* wr = &sw2[k * 32];
        #pragma unroll
        for (int j = 0; j < 32; j++) o[j] = fmaf(hk, wr[j], o[j]);
    }
    float4* hp = (float4*)(h + (size_t)n * 32);
    #pragma unroll
    for (int c = 0; c < 8; c++)
        hp[c] = make_float4(o[4 * c], o[4 * c + 1], o[4 * c + 2], o[4 * c + 3]);
}

// -------- CSR build: histogram -> exclusive scan -> fill --------

__global__ void __launch_bounds__(256)
k_hist(const int2* __restrict__ edges, int* __restrict__ cnt, int n_edges)
{
    int e = blockIdx.x * 256 + threadIdx.x;
    if (e >= n_edges) return;
    atomicAdd(&cnt[edges[e].y], 1);
}

__global__ void __launch_bounds__(256)
k_scan_block(const int* __restrict__ cnt, int* __restrict__ rs,
             int* __restrict__ bsum, int n)
{
    __shared__ int sd[256];
    int t = threadIdx.x;
    int i = blockIdx.x * 256 + t;
    int v = (i < n) ? cnt[i] : 0;
    sd[t] = v;
    __syncthreads();
    int val = v;
    for (int off = 1; off < 256; off <<= 1) {
        int add = (t >= off) ? sd[t - off] : 0;
        __syncthreads();
        val += add;
        sd[t] = val;
        __syncthreads();
    }
    if (i < n) rs[i] = val - v;           // exclusive within block
    if (t == 255) bsum[blockIdx.x] = val; // block total
}

__global__ void __launch_bounds__(1024)
k_scan_bsum(int* __restrict__ bsum, int nb, int* __restrict__ rs,
            int n_nodes, int n_edges)
{
    __shared__ int sd[1024];
    int t = threadIdx.x;
    int v = (t < nb) ? bsum[t] : 0;
    sd[t] = v;
    __syncthreads();
    int val = v;
    for (int off = 1; off < 1024; off <<= 1) {
        int add = (t >= off) ? sd[t - off] : 0;
        __syncthreads();
        val += add;
        sd[t] = val;
        __syncthreads();
    }
    if (t < nb) bsum[t] = val - v;  // exclusive prefix of block totals
    if (t == 0) rs[n_nodes] = n_edges;
}

__global__ void __launch_bounds__(256)
k_scan_add(int* __restrict__ rs, int* __restrict__ cursor,
           const int* __restrict__ bsum, int n)
{
    int i = blockIdx.x * 256 + threadIdx.x;
    if (i < n) {
        int v = rs[i] + bsum[blockIdx.x];
        rs[i] = v;
        cursor[i] = v;
    }
}

// scatter edges into dst-sorted slots: slot = (src, edge_idx)
__global__ void __launch_bounds__(256)
k_fill(const int2* __restrict__ edges, int* __restrict__ cursor,
       int2* __restrict__ slots, int n_edges)
{
    int e = blockIdx.x * 256 + threadIdx.x;
    if (e >= n_edges) return;
    int2 ed = edges[e];
    int pos = atomicAdd(&cursor[ed.y], 1);
    slots[pos] = make_int2(ed.x, e);
}

// -------- per-round precompute: g[n][c] = sum_k h[n][k] * W1a[k][c] --------
// (src half of msg layer 1; no bias -- bias lives in base). Wave per 2 nodes.
__global__ void __launch_bounds__(256)
k_gsrc(const float* __restrict__ h, const float* __restrict__ mw1,
       float* __restrict__ g, int n_nodes)
{
    __shared__ float sW[32 * 32];
    for (int i = threadIdx.x; i < 32 * 32; i += 256) sW[i] = mw1[i];
    __syncthreads();
    const int lane = threadIdx.x & 63;
    const int c    = lane & 31;
    const int half = lane >> 5;
    int wi = (int)((blockIdx.x * 256 + threadIdx.x) >> 6);
    int nw = gridDim.x * 4;
    for (; 2 * wi < n_nodes; wi += nw) {
        int nr = 2 * wi + half;
        int n  = min(nr, n_nodes - 1);
        float hn = h[(size_t)n * 32 + c];
        float b = 0.0f;
        #pragma unroll
        for (int k = 0; k < 32; k++)
            b = fmaf(__shfl(hn, k, 32), sW[k * 32 + c], b);
        if (nr < n_nodes) g[(size_t)n * 32 + c] = b;
    }
}

// -------- fused round v3: wave-per-node, g-gather, 4-edge ILP --------
// per edge: m1[c] = relu(base[dst][c] + g[src][c] + sum_k ef[k]*W1c[k][c])
// lane c owns column c; halves process interleaved slots, 4 edges in flight.
__global__ void __launch_bounds__(256, 4)
k_round_wave3(const float* __restrict__ h_in, float* __restrict__ h_out,
        const float* __restrict__ g,
        const int* __restrict__ row_start, const int2* __restrict__ slots,
        const float4* __restrict__ ef,
        const float* __restrict__ mw1, const float* __restrict__ mb1,
        const float* __restrict__ mw2, const float* __restrict__ mb2,
        const float* __restrict__ uw1, const float* __restrict__ ub1,
        const float* __restrict__ uw2, const float* __restrict__ ub2,
        int n_nodes)
{
    __shared__ float sW1b[32 * 32];   // msg_w1 rows 32..63 (dst half)
    __shared__ float sW2[32 * 32];
    __shared__ float sU1[64 * 32];
    __shared__ float sU2[32 * 32];
    __shared__ float sB[4 * 32];      // mb1 | mb2 | ub1 | ub2
    for (int i = threadIdx.x; i < 32 * 32; i += 256) sW1b[i] = mw1[32 * 32 + i];
    for (int i = threadIdx.x; i < 32 * 32; i += 256) sW2[i]  = mw2[i];
    for (int i = threadIdx.x; i < 64 * 32; i += 256) sU1[i]  = uw1[i];
    for (int i = threadIdx.x; i < 32 * 32; i += 256) sU2[i]  = uw2[i];
    if (threadIdx.x < 32) {
        sB[threadIdx.x]      = mb1[threadIdx.x];
        sB[32 + threadIdx.x] = mb2[threadIdx.x];
        sB[64 + threadIdx.x] = ub1[threadIdx.x];
        sB[96 + threadIdx.x] = ub2[threadIdx.x];
    }
    __syncthreads();

    const int lane = threadIdx.x & 63;
    const int c    = lane & 31;
    const int half = lane >> 5;

    // per-lane private ef column of msg W1 (k=0..3)
    float w1c[4];
    #pragma unroll
    for (int k = 0; k < 4; k++) w1c[k] = mw1[(64 + k) * 32 + c];

    int wave   = (int)((blockIdx.x * 256 + threadIdx.x) >> 6);
    int nwaves = gridDim.x * 4;

    for (int n = wave; n < n_nodes; n += nwaves) {
        float hn = h_in[(size_t)n * 32 + c];

        // base = mb1 + h[n] @ W1b (dst-half hoisted out of the edge loop)
        float base = sB[c];
        #pragma unroll
        for (int k = 0; k < 32; k++)
            base = fmaf(__shfl(hn, k, 32), sW1b[k * 32 + c], base);

        int s0 = row_start[n];
        int s1 = row_start[n + 1];
        float rsum = 0.0f;

        int s = s0 + half;   // this half's slots: s, s+2, s+4, ...
        // main loop: 4 edges per half in flight
        for (; s + 6 < s1; s += 8) {
            int2 sl0 = slots[s];
            int2 sl1 = slots[s + 2];
            int2 sl2 = slots[s + 4];
            int2 sl3 = slots[s + 6];
            float x0 = g[(size_t)sl0.x * 32 + c];
            float x1 = g[(size_t)sl1.x * 32 + c];
            float x2 = g[(size_t)sl2.x * 32 + c];
            float x3 = g[(size_t)sl3.x * 32 + c];
            float4 e0 = ef[sl0.y];
            float4 e1 = ef[sl1.y];
            float4 e2 = ef[sl2.y];
            float4 e3 = ef[sl3.y];

            float a0 = base + x0;
            float a1 = base + x1;
            float a2 = base + x2;
            float a3 = base + x3;
            a0 = fmaf(e0.x, w1c[0], a0); a0 = fmaf(e0.y, w1c[1], a0);
            a0 = fmaf(e0.z, w1c[2], a0); a0 = fmaf(e0.w, w1c[3], a0);
            a1 = fmaf(e1.x, w1c[0], a1); a1 = fmaf(e1.y, w1c[1], a1);
            a1 = fmaf(e1.z, w1c[2], a1); a1 = fmaf(e1.w, w1c[3], a1);
            a2 = fmaf(e2.x, w1c[0], a2); a2 = fmaf(e2.y, w1c[1], a2);
            a2 = fmaf(e2.z, w1c[2], a2); a2 = fmaf(e2.w, w1c[3], a2);
            a3 = fmaf(e3.x, w1c[0], a3); a3 = fmaf(e3.y, w1c[1], a3);
            a3 = fmaf(e3.z, w1c[2], a3); a3 = fmaf(e3.w, w1c[3], a3);

            rsum += fmaxf(a0, 0.0f);
            rsum += fmaxf(a1, 0.0f);
            rsum += fmaxf(a2, 0.0f);
            rsum += fmaxf(a3, 0.0f);
        }
        // tail: one edge at a time
        for (; s < s1; s += 2) {
            int2 sl = slots[s];
            float x = g[(size_t)sl.x * 32 + c];
            float4 ev = ef[sl.y];
            float a = base + x;
            a = fmaf(ev.x, w1c[0], a); a = fmaf(ev.y, w1c[1], a);
            a = fmaf(ev.z, w1c[2], a); a = fmaf(ev.w, w1c[3], a);
            rsum += fmaxf(a, 0.0f);
        }
        // combine halves (both halves converged here)
        rsum += __shfl_xor(rsum, 32, 64);

        // agg = deg*mb2 + rsum @ W2 (W2 hoisted by linearity)
        float deg = (float)(s1 - s0);
        float agg = deg * sB[32 + c];
        #pragma unroll
        for (int k = 0; k < 32; k++)
            agg = fmaf(__shfl(rsum, k, 32), sW2[k * 32 + c], agg);

        // update MLP
        float a2v = sB[64 + c];
        #pragma unroll
        for (int k = 0; k < 32; k++)
            a2v = fmaf(__shfl(hn, k, 32), sU1[k * 32 + c], a2v);
        #pragma unroll
        for (int k = 0; k < 32; k++)
            a2v = fmaf(__shfl(agg, k, 32), sU1[(32 + k) * 32 + c], a2v);
        float t = fmaxf(a2v, 0.0f);
        float o = sB[96 + c];
        #pragma unroll
        for (int k = 0; k < 32; k++)
            o = fmaf(__shfl(t, k, 32), sU2[k * 32 + c], o);

        if (lane < 32) h_out[(size_t)n * 32 + c] = hn + o;
    }
}

// -------- R14 fallback kernels (atomic path), used only if ws too small -----

__global__ void __launch_bounds__(256)
k_message(const float* __restrict__ h, const int2* __restrict__ edges,
          const float4* __restrict__ ef,
          const float* __restrict__ w1g, const float* __restrict__ b1g,
          const float* __restrict__ w2g, const float* __restrict__ b2g,
          float* __restrict__ agg, int n_edges)
{
    __shared__ float sw1[68 * 32];
    __shared__ float sw2[32 * 32];
    __shared__ float sb1[32];
    __shared__ float sb2[32];
    for (int i = threadIdx.x; i < 68 * 32; i += 256) sw1[i] = w1g[i];
    for (int i = threadIdx.x; i < 32 * 32; i += 256) sw2[i] = w2g[i];
    if (threadIdx.x < 32) {
        sb1[threadIdx.x] = b1g[threadIdx.x];
        sb2[threadIdx.x] = b2g[threadIdx.x];
    }
    __syncthreads();
    int e = blockIdx.x * 256 + threadIdx.x;
    if (e >= n_edges) return;

    int2 ed = edges[e];
    const float4* hs = (const float4*)(h + (size_t)ed.x * 32);
    const float4* hd = (const float4*)(h + (size_t)ed.y * 32);

    float acc[32];
    #pragma unroll
    for (int j = 0; j < 32; j++) acc[j] = sb1[j];
    #pragma unroll 2
    for (int cc = 0; cc < 8; cc++) {
        float4 xv = hs[cc];
        float xsv[4] = {xv.x, xv.y, xv.z, xv.w};
        #pragma unroll
        for (int kk = 0; kk < 4; kk++) {
            float xk = xsv[kk];
            const float* wr = &sw1[(cc * 4 + kk) * 32];
            #pragma unroll
            for (int j = 0; j < 32; j++) acc[j] = fmaf(xk, wr[j], acc[j]);
        }
    }
    #pragma unroll 2
    for (int cc = 0; cc < 8; cc++) {
        float4 xv = hd[cc];
        float xsv[4] = {xv.x, xv.y, xv.z, xv.w};
        #pragma unroll
        for (int kk = 0; kk < 4; kk++) {
            float xk = xsv[kk];
            const float* wr = &sw1[(32 + cc * 4 + kk) * 32];
            #pragma unroll
            for (int j = 0; j < 32; j++) acc[j] = fmaf(xk, wr[j], acc[j]);
        }
    }
    {
        float4 evv = ef[e];
        float ex[4] = {evv.x, evv.y, evv.z, evv.w};
        #pragma unroll
        for (int kk = 0; kk < 4; kk++) {
            float xk = ex[kk];
            const float* wr = &sw1[(64 + kk) * 32];
            #pragma unroll
            for (int j = 0; j < 32; j++) acc[j] = fmaf(xk, wr[j], acc[j]);
        }
    }
    #pragma unroll
    for (int j = 0; j < 32; j++) acc[j] = fmaxf(acc[j], 0.0f);

    float o[32];
    #pragma unroll
    for (int j = 0; j < 32; j++) o[j] = sb2[j];
    #pragma unroll 4
    for (int k = 0; k < 32; k++) {
        float hk = acc[k];
        const float* wr = &sw2[k * 32];
        #pragma unroll
        for (int j = 0; j < 32; j++) o[j] = fmaf(hk, wr[j], o[j]);
    }
    float* ap = agg + (size_t)ed.y * 32;
    #pragma unroll
    for (int j = 0; j < 32; j++) atomicAdd(ap + j, o[j]);
}

__global__ void __launch_bounds__(256)
k_update(float* h, const float* __restrict__ agg,
         const float* __restrict__ w1g, const float* __restrict__ b1g,
         const float* __restrict__ w2g, const float* __restrict__ b2g,
         int n_nodes)
{
    __shared__ float sw1[64 * 32];
    __shared__ float sw2[32 * 32];
    __shared__ float sb1[32];
    __shared__ float sb2[32];
    for (int i = threadIdx.x; i < 64 * 32; i += 256) sw1[i] = w1g[i];
    for (int i = threadIdx.x; i < 32 * 32; i += 256) sw2[i] = w2g[i];
    if (threadIdx.x < 32) {
        sb1[threadIdx.x] = b1g[threadIdx.x];
        sb2[threadIdx.x] = b2g[threadIdx.x];
    }
    __syncthreads();
    int n = blockIdx.x * 256 + threadIdx.x;
    if (n >= n_nodes) return;

    const float4* hp = (const float4*)(h + (size_t)n * 32);
    const float4* ap = (const float4*)(agg + (size_t)n * 32);

    float hv[32];
    float acc[32];
    #pragma unroll
    for (int j = 0; j < 32; j++) acc[j] = sb1[j];
    #pragma unroll 2
    for (int cc = 0; cc < 8; cc++) {
        float4 xv = hp[cc];
        hv[4 * cc] = xv.x; hv[4 * cc + 1] = xv.y; hv[4 * cc + 2] = xv.z; hv[4 * cc + 3] = xv.w;
        float xsv[4] = {xv.x, xv.y, xv.z, xv.w};
        #pragma unroll
        for (int kk = 0; kk < 4; kk++) {
            float xk = xsv[kk];
            const float* wr = &sw1[(cc * 4 + kk) * 32];
            #pragma unroll
            for (int j = 0; j < 32; j++) acc[j] = fmaf(xk, wr[j], acc[j]);
        }
    }
    #pragma unroll 2
    for (int cc = 0; cc < 8; cc++) {
        float4 xv = ap[cc];
        float xsv[4] = {xv.x, xv.y, xv.z, xv.w};
        #pragma unroll
        for (int kk = 0; kk < 4; kk++) {
            float xk = xsv[kk];
            const float* wr = &sw1[(32 + cc * 4 + kk) * 32];
            #pragma unroll
            for (int j = 0; j < 32; j++) acc[j] = fmaf(xk, wr[j], acc[j]);
        }
    }
    #pragma unroll
    for (int j = 0; j < 32; j++) acc[j] = fmaxf(acc[j], 0.0f);

    float o[32];
    #pragma unroll
    for (int j = 0; j < 32; j++) o[j] = sb2[j];
    #pragma unroll 4
    for (int k = 0; k < 32; k++) {
        float hk = acc[k];
        const float* wr = &sw2[k * 32];
        #pragma unroll
        for (int j = 0; j < 32; j++) o[j] = fmaf(hk, wr[j], o[j]);
    }
    float4* op = (float4*)(h + (size_t)n * 32);
    #pragma unroll
    for (int cc = 0; cc < 8; cc++)
        op[cc] = make_float4(hv[4 * cc] + o[4 * cc], hv[4 * cc + 1] + o[4 * cc + 1],
                             hv[4 * cc + 2] + o[4 * cc + 2], hv[4 * cc + 3] + o[4 * cc + 3]);
}

// head: out = (relu(h @ w1 + b1) @ w2 + b2)[:, 0]   (fp32 out)
__global__ void AtomGNN_56169582297457_kernel(const float* h, const float* w1g, const float* b1g, const float* w2g, const float* b2g, float* out, int n_nodes) {
    __shared__ float sw1[32 * 32];
    __shared__ float sb1[32];
    __shared__ float sw2[32];
    __shared__ float sb2;
    for (int i = threadIdx.x; i < 32 * 32; i += 256) sw1[i] = w1g[i];
    if (threadIdx.x < 32) {
        sb1[threadIdx.x] = b1g[threadIdx.x];
        sw2[threadIdx.x] = w2g[threadIdx.x];
    }
    if (threadIdx.x == 0) sb2 = b2g[0];
    __syncthreads();
    int n = blockIdx.x * 256 + threadIdx.x;
    if (n >= n_nodes) return;

    const float4* hp = (const float4*)(h + (size_t)n * 32);
    float x[32];
    #pragma unroll
    for (int cc = 0; cc < 8; cc++) {
        float4 xv = hp[cc];
        x[4 * cc] = xv.x; x[4 * cc + 1] = xv.y; x[4 * cc + 2] = xv.z; x[4 * cc + 3] = xv.w;
    }
    float acc[32];
    #pragma unroll
    for (int j = 0; j < 32; j++) acc[j] = sb1[j];
    #pragma unroll 4
    for (int k = 0; k < 32; k++) {
        float xk = x[k];
        const float* wr = &sw1[k * 32];
        #pragma unroll
        for (int j = 0; j < 32; j++) acc[j] = fmaf(xk, wr[j], acc[j]);
    }
    float val = sb2;
    #pragma unroll
    for (int k = 0; k < 32; k++) val = fmaf(fmaxf(acc[k], 0.0f), sw2[k], val);
    out[n] = val;
}

extern "C" void kernel_launch(void* const* d_in, const int* in_sizes, int n_in,
                              void* d_out, int out_size, void* d_ws, size_t ws_size,
                              hipStream_t stream) {
    const float* nf      = (const float*)d_in[0];
    const int2*  edges   = (const int2*)d_in[1];
    const float4* ef     = (const float4*)d_in[2];
    const float* enc_w1  = (const float*)d_in[3];
    const float* enc_b1  = (const float*)d_in[4];
    const float* enc_w2  = (const float*)d_in[5];
    const float* enc_b2  = (const float*)d_in[6];
    const float* msg_w1  = (const float*)d_in[7];
    const float* msg_b1  = (const float*)d_in[8];
    const float* msg_w2  = (const float*)d_in[9];
    const float* msg_b2  = (const float*)d_in[10];
    const float* upd_w1  = (const float*)d_in[11];
    const float* upd_b1  = (const float*)d_in[12];
    const float* upd_w2  = (const float*)d_in[13];
    const float* upd_b2  = (const float*)d_in[14];
    const float* head_w1 = (const float*)d_in[15];
    const float* head_b1 = (const float*)d_in[16];
    const float* head_w2 = (const float*)d_in[17];
    const float* head_b2 = (const float*)d_in[18];

    int n_nodes = (out_size > 0) ? out_size : NN_REF;
    int n_edges = (in_sizes && n_in > 2 && in_sizes[2] > 0) ? in_sizes[2] / 4 : NE_REF;

    int nb_nodes = (n_nodes + 255) / 256;
    int nb_edges = (n_edges + 255) / 256;

    // Workspace layout (~65MB, below the proven 77.6MB fit):
    //   h0 | h1 | g | row_start[n+1] | cursor[n] | bsum[nb] | pad | slots[E] int2
    float* h0 = (float*)d_ws;
    float* h1 = h0 + (size_t)n_nodes * 32;
    float* g  = h1 + (size_t)n_nodes * 32;
    int* row_start = (int*)(g + (size_t)n_nodes * 32);
    int* cursor = row_start + (n_nodes + 1);
    int* bsum = cursor + n_nodes;
    uintptr_t slots_addr = ((uintptr_t)(bsum + nb_nodes) + 15) & ~(uintptr_t)15;
    int2* slots = (int2*)slots_addr;
    size_t required_csr = (slots_addr - (uintptr_t)d_ws) + (size_t)n_edges * 8;

    bool csr_ok = (nb_nodes <= 1024) &&
                  (ws_size == 0 || ws_size >= required_csr);

    if (csr_ok) {
        k_encode<<<nb_nodes, 256, 0, stream>>>(nf, enc_w1, enc_b1, enc_w2, enc_b2, h0, n_nodes);

        // build dst-CSR once (edges identical across rounds)
        k_zero<<<256, 256, 0, stream>>>((float*)cursor, n_nodes);
        k_hist<<<nb_edges, 256, 0, stream>>>(edges, cursor, n_edges);
        k_scan_block<<<nb_nodes, 256, 0, stream>>>(cursor, row_start, bsum, n_nodes);
        k_scan_bsum<<<1, 1024, 0, stream>>>(bsum, nb_nodes, row_start, n_nodes, n_edges);
        k_scan_add<<<nb_nodes, 256, 0, stream>>>(row_start, cursor, bsum, n_nodes);
        k_fill<<<nb_edges, 256, 0, stream>>>(edges, cursor, slots, n_edges);

        // ping-pong rounds: h0 -> h1 -> h0
        for (int r = 0; r < 2; r++) {
            const float* hin = (r == 0) ? h0 : h1;
            float* hout      = (r == 0) ? h1 : h0;
            const float* mw1 = msg_w1 + (size_t)r * 68 * 32;
            k_gsrc<<<1024, 256, 0, stream>>>(hin, mw1, g, n_nodes);
            k_round_wave3<<<2048, 256, 0, stream>>>(
                hin, hout, g, row_start, slots, ef,
                mw1, msg_b1 + (size_t)r * 32,
                msg_w2 + (size_t)r * 32 * 32, msg_b2 + (size_t)r * 32,
                upd_w1 + (size_t)r * 64 * 32, upd_b1 + (size_t)r * 32,
                upd_w2 + (size_t)r * 32 * 32, upd_b2 + (size_t)r * 32,
                n_nodes);
        }

        AtomGNN_56169582297457_kernel<<<nb_nodes, 256, 0, stream>>>(
            h0, head_w1, head_b1, head_w2, head_b2, (float*)d_out, n_nodes);
    } else {
        // R14 fallback: atomic scatter path
        float* h   = (float*)d_ws;
        float* agg = h + (size_t)n_nodes * 32;

        k_encode<<<nb_nodes, 256, 0, stream>>>(nf, enc_w1, enc_b1, enc_w2, enc_b2, h, n_nodes);
        for (int r = 0; r < 2; r++) {
            k_zero<<<1024, 256, 0, stream>>>(agg, n_nodes * 32);
            k_message<<<nb_edges, 256, 0, stream>>>(
                h, edges, ef,
                msg_w1 + (size_t)r * 68 * 32, msg_b1 + (size_t)r * 32,
                msg_w2 + (size_t)r * 32 * 32, msg_b2 + (size_t)r * 32,
                agg, n_edges);
            k_update<<<nb_nodes, 256, 0, stream>>>(
                h, agg,
                upd_w1 + (size_t)r * 64 * 32, upd_b1 + (size_t)r * 32,
                upd_w2 + (size_t)r * 32 * 32, upd_b2 + (size_t)r * 32,
                n_nodes);
        }
        AtomGNN_56169582297457_kernel<<<nb_nodes, 256, 0, stream>>>(
            h, head_w1, head_b1, head_w2, head_b2, (float*)d_out, n_nodes);
    }
}

// Round 6
// 1944.923 us; speedup vs baseline: 1.6640x; 1.0412x over previous
//
#include <hip/hip_runtime.h>
#include <hip/hip_fp16.h>
#include <cstdio>
#include <cstdint>

// R20: cut the two dominant traffic terms. R19 counters: k_round_wave3 is
// L2-miss-traffic-bound (2.09GB/round at 2.68TB/s == duration, VALU 11%).
// Audit: g gather 410MB compulsory (12.8MB table >> 4MB XCD L2 -> ~all miss),
// ef random 16B-of-line reads ~205-410MB, slots 25.6MB, ~2x refetch thrash.
// Fix 1: g stored fp16 -> 64B/edge gather, 6.4MB table (much better L2
// residency). Error budget ~+2e-4 final (fp16 ulp 2.4e-4 attenuated by two
// 0.1-scale matmuls). Fix 2: ef permuted into slot order at CSR build ->
// sequential 51.2MB stream/round instead of random lines; slots split SoA
// (round reads only srcs[], 12.8MB). efp gated on ws>=110MB (base 58.5MB is
// below the proven-good 77.6MB); without it kernel reads ef[eidx[s]].
// R14 atomic path kept as deep fallback.

__attribute__((constructor)) static void atomgnn_r20_load_beacon() {
    fprintf(stderr, "ATOMGNN_R20_SOURCE_LOADED\n");
    fflush(stderr);
}

#define NN_REF 100000
#define NE_REF 3200000

// zero a float/int buffer (4B words), grid-stride
__global__ void __launch_bounds__(256)
k_zero(float* __restrict__ p, int n)
{
    int i = blockIdx.x * 256 + threadIdx.x;
    int stride = gridDim.x * 256;
    for (; i < n; i += stride) p[i] = 0.0f;
}

// encoder: h = relu(nf @ w1 + b1) @ w2 + b2   (16 -> 32 -> 32)
__global__ void __launch_bounds__(256)
k_encode(const float* __restrict__ nf,
         const float* __restrict__ w1g, const float* __restrict__ b1g,
         const float* __restrict__ w2g, const float* __restrict__ b2g,
         float* __restrict__ h, int n_nodes)
{
    __shared__ float sw1[16 * 32];
    __shared__ float sw2[32 * 32];
    __shared__ float sb1[32];
    __shared__ float sb2[32];
    for (int i = threadIdx.x; i < 16 * 32; i += 256) sw1[i] = w1g[i];
    for (int i = threadIdx.x; i < 32 * 32; i += 256) sw2[i] = w2g[i];
    if (threadIdx.x < 32) {
        sb1[threadIdx.x] = b1g[threadIdx.x];
        sb2[threadIdx.x] = b2g[threadIdx.x];
    }
    __syncthreads();
    int n = blockIdx.x * 256 + threadIdx.x;
    if (n >= n_nodes) return;

    const float4* p = (const float4*)(nf + (size_t)n * 16);
    float x[16];
    #pragma unroll
    for (int c = 0; c < 4; c++) {
        float4 v = p[c];
        x[4 * c] = v.x; x[4 * c + 1] = v.y; x[4 * c + 2] = v.z; x[4 * c + 3] = v.w;
    }

    float acc[32];
    #pragma unroll
    for (int j = 0; j < 32; j++) acc[j] = sb1[j];
    #pragma unroll 4
    for (int k = 0; k < 16; k++) {
        float xk = x[k];
        const float* wr = &sw1[k * 32];
        #pragma unroll
        for (int j = 0; j < 32; j++) acc[j] = fmaf(xk, wr[j], acc[j]);
    }
    #pragma unroll
    for (int j = 0; j < 32; j++) acc[j] = fmaxf(acc[j], 0.0f);

    float o[32];
    #pragma unroll
    for (int j = 0; j < 32; j++) o[j] = sb2[j];
    #pragma unroll 4
    for (int k = 0; k < 32; k++) {
        float hk = acc[k];
        const float* wr = &sw2[k * 32];
        #pragma unroll
        for (int j = 0; j < 32; j++) o[j] = fmaf(hk, wr[j], o[j]);
    }
    float4* hp = (float4*)(h + (size_t)n * 32);
    #pragma unroll
    for (int c = 0; c < 8; c++)
        hp[c] = make_float4(o[4 * c], o[4 * c + 1], o[4 * c + 2], o[4 * c + 3]);
}

// -------- CSR build: histogram -> exclusive scan -> fill --------

__global__ void __launch_bounds__(256)
k_hist(const int2* __restrict__ edges, int* __restrict__ cnt, int n_edges)
{
    int e = blockIdx.x * 256 + threadIdx.x;
    if (e >= n_edges) return;
    atomicAdd(&cnt[edges[e].y], 1);
}

__global__ void __launch_bounds__(256)
k_scan_block(const int* __restrict__ cnt, int* __restrict__ rs,
             int* __restrict__ bsum, int n)
{
    __shared__ int sd[256];
    int t = threadIdx.x;
    int i = blockIdx.x * 256 + t;
    int v = (i < n) ? cnt[i] : 0;
    sd[t] = v;
    __syncthreads();
    int val = v;
    for (int off = 1; off < 256; off <<= 1) {
        int add = (t >= off) ? sd[t - off] : 0;
        __syncthreads();
        val += add;
        sd[t] = val;
        __syncthreads();
    }
    if (i < n) rs[i] = val - v;           // exclusive within block
    if (t == 255) bsum[blockIdx.x] = val; // block total
}

__global__ void __launch_bounds__(1024)
k_scan_bsum(int* __restrict__ bsum, int nb, int* __restrict__ rs,
            int n_nodes, int n_edges)
{
    __shared__ int sd[1024];
    int t = threadIdx.x;
    int v = (t < nb) ? bsum[t] : 0;
    sd[t] = v;
    __syncthreads();
    int val = v;
    for (int off = 1; off < 1024; off <<= 1) {
        int add = (t >= off) ? sd[t - off] : 0;
        __syncthreads();
        val += add;
        sd[t] = val;
        __syncthreads();
    }
    if (t < nb) bsum[t] = val - v;  // exclusive prefix of block totals
    if (t == 0) rs[n_nodes] = n_edges;
}

__global__ void __launch_bounds__(256)
k_scan_add(int* __restrict__ rs, int* __restrict__ cursor,
           const int* __restrict__ bsum, int n)
{
    int i = blockIdx.x * 256 + threadIdx.x;
    if (i < n) {
        int v = rs[i] + bsum[blockIdx.x];
        rs[i] = v;
        cursor[i] = v;
    }
}

// scatter edges into dst-sorted SoA slots; optionally permute ef into slot
// order (efp[pos] = ef[e]) so round kernels read ef sequentially.
__global__ void __launch_bounds__(256)
k_fill2(const int2* __restrict__ edges, const float4* __restrict__ ef,
        int* __restrict__ cursor, int* __restrict__ srcs,
        int* __restrict__ eidx, float4* __restrict__ efp,
        int n_edges, int build_perm)
{
    int e = blockIdx.x * 256 + threadIdx.x;
    if (e >= n_edges) return;
    int2 ed = edges[e];
    int pos = atomicAdd(&cursor[ed.y], 1);
    srcs[pos] = ed.x;
    eidx[pos] = e;
    if (build_perm) efp[pos] = ef[e];
}

// -------- per-round precompute: g16[n][c] = fp16( sum_k h[n][k]*W1a[k][c] )
__global__ void __launch_bounds__(256)
k_gsrc16(const float* __restrict__ h, const float* __restrict__ mw1,
         __half* __restrict__ g16, int n_nodes)
{
    __shared__ float sW[32 * 32];
    for (int i = threadIdx.x; i < 32 * 32; i += 256) sW[i] = mw1[i];
    __syncthreads();
    const int lane = threadIdx.x & 63;
    const int c    = lane & 31;
    const int half = lane >> 5;
    int wi = (int)((blockIdx.x * 256 + threadIdx.x) >> 6);
    int nw = gridDim.x * 4;
    for (; 2 * wi < n_nodes; wi += nw) {
        int nr = 2 * wi + half;
        int n  = min(nr, n_nodes - 1);
        float hn = h[(size_t)n * 32 + c];
        float b = 0.0f;
        #pragma unroll
        for (int k = 0; k < 32; k++)
            b = fmaf(__shfl(hn, k, 32), sW[k * 32 + c], b);
        if (nr < n_nodes) g16[(size_t)n * 32 + c] = __float2half(b);
    }
}

// -------- fused round v4: wave-per-node, fp16-g gather, seq-ef, 4-edge ILP --
// per edge: m1[c] = relu(base[dst][c] + g[src][c] + sum_k ef[k]*W1c[k][c])
__global__ void __launch_bounds__(256, 4)
k_round_wave4(const float* __restrict__ h_in, float* __restrict__ h_out,
        const __half* __restrict__ g16,
        const int* __restrict__ row_start, const int* __restrict__ srcs,
        const int* __restrict__ eidx,
        const float4* __restrict__ efp,   // slot-ordered ef (may be null)
        const float4* __restrict__ ef,    // original ef (used if efp null)
        const float* __restrict__ mw1, const float* __restrict__ mb1,
        const float* __restrict__ mw2, const float* __restrict__ mb2,
        const float* __restrict__ uw1, const float* __restrict__ ub1,
        const float* __restrict__ uw2, const float* __restrict__ ub2,
        int n_nodes, int use_perm)
{
    __shared__ float sW1b[32 * 32];   // msg_w1 rows 32..63 (dst half)
    __shared__ float sW2[32 * 32];
    __shared__ float sU1[64 * 32];
    __shared__ float sU2[32 * 32];
    __shared__ float sB[4 * 32];      // mb1 | mb2 | ub1 | ub2
    for (int i = threadIdx.x; i < 32 * 32; i += 256) sW1b[i] = mw1[32 * 32 + i];
    for (int i = threadIdx.x; i < 32 * 32; i += 256) sW2[i]  = mw2[i];
    for (int i = threadIdx.x; i < 64 * 32; i += 256) sU1[i]  = uw1[i];
    for (int i = threadIdx.x; i < 32 * 32; i += 256) sU2[i]  = uw2[i];
    if (threadIdx.x < 32) {
        sB[threadIdx.x]      = mb1[threadIdx.x];
        sB[32 + threadIdx.x] = mb2[threadIdx.x];
        sB[64 + threadIdx.x] = ub1[threadIdx.x];
        sB[96 + threadIdx.x] = ub2[threadIdx.x];
    }
    __syncthreads();

    const int lane = threadIdx.x & 63;
    const int c    = lane & 31;
    const int half = lane >> 5;

    // per-lane private ef column of msg W1 (k=0..3)
    float w1c[4];
    #pragma unroll
    for (int k = 0; k < 4; k++) w1c[k] = mw1[(64 + k) * 32 + c];

    int wave   = (int)((blockIdx.x * 256 + threadIdx.x) >> 6);
    int nwaves = gridDim.x * 4;

    for (int n = wave; n < n_nodes; n += nwaves) {
        float hn = h_in[(size_t)n * 32 + c];

        // base = mb1 + h[n] @ W1b (dst-half hoisted out of the edge loop)
        float base = sB[c];
        #pragma unroll
        for (int k = 0; k < 32; k++)
            base = fmaf(__shfl(hn, k, 32), sW1b[k * 32 + c], base);

        int s0 = row_start[n];
        int s1 = row_start[n + 1];
        float rsum = 0.0f;

        int s = s0 + half;   // this half's slots: s, s+2, s+4, ...
        // main loop: 4 edges per half in flight
        for (; s + 6 < s1; s += 8) {
            int i0 = srcs[s];
            int i1 = srcs[s + 2];
            int i2 = srcs[s + 4];
            int i3 = srcs[s + 6];
            float x0 = __half2float(g16[(size_t)i0 * 32 + c]);
            float x1 = __half2float(g16[(size_t)i1 * 32 + c]);
            float x2 = __half2float(g16[(size_t)i2 * 32 + c]);
            float x3 = __half2float(g16[(size_t)i3 * 32 + c]);
            float4 e0, e1, e2, e3;
            if (use_perm) {
                e0 = efp[s];     e1 = efp[s + 2];
                e2 = efp[s + 4]; e3 = efp[s + 6];
            } else {
                e0 = ef[eidx[s]];     e1 = ef[eidx[s + 2]];
                e2 = ef[eidx[s + 4]]; e3 = ef[eidx[s + 6]];
            }

            float a0 = base + x0;
            float a1 = base + x1;
            float a2 = base + x2;
            float a3 = base + x3;
            a0 = fmaf(e0.x, w1c[0], a0); a0 = fmaf(e0.y, w1c[1], a0);
            a0 = fmaf(e0.z, w1c[2], a0); a0 = fmaf(e0.w, w1c[3], a0);
            a1 = fmaf(e1.x, w1c[0], a1); a1 = fmaf(e1.y, w1c[1], a1);
            a1 = fmaf(e1.z, w1c[2], a1); a1 = fmaf(e1.w, w1c[3], a1);
            a2 = fmaf(e2.x, w1c[0], a2); a2 = fmaf(e2.y, w1c[1], a2);
            a2 = fmaf(e2.z, w1c[2], a2); a2 = fmaf(e2.w, w1c[3], a2);
            a3 = fmaf(e3.x, w1c[0], a3); a3 = fmaf(e3.y, w1c[1], a3);
            a3 = fmaf(e3.z, w1c[2], a3); a3 = fmaf(e3.w, w1c[3], a3);

            rsum += fmaxf(a0, 0.0f);
            rsum += fmaxf(a1, 0.0f);
            rsum += fmaxf(a2, 0.0f);
            rsum += fmaxf(a3, 0.0f);
        }
        // tail: one edge at a time
        for (; s < s1; s += 2) {
            int i0 = srcs[s];
            float x = __half2float(g16[(size_t)i0 * 32 + c]);
            float4 ev = use_perm ? efp[s] : ef[eidx[s]];
            float a = base + x;
            a = fmaf(ev.x, w1c[0], a); a = fmaf(ev.y, w1c[1], a);
            a = fmaf(ev.z, w1c[2], a); a = fmaf(ev.w, w1c[3], a);
            rsum += fmaxf(a, 0.0f);
        }
        // combine halves (both halves converged here)
        rsum += __shfl_xor(rsum, 32, 64);

        // agg = deg*mb2 + rsum @ W2 (W2 hoisted by linearity)
        float deg = (float)(s1 - s0);
        float agg = deg * sB[32 + c];
        #pragma unroll
        for (int k = 0; k < 32; k++)
            agg = fmaf(__shfl(rsum, k, 32), sW2[k * 32 + c], agg);

        // update MLP
        float a2v = sB[64 + c];
        #pragma unroll
        for (int k = 0; k < 32; k++)
            a2v = fmaf(__shfl(hn, k, 32), sU1[k * 32 + c], a2v);
        #pragma unroll
        for (int k = 0; k < 32; k++)
            a2v = fmaf(__shfl(agg, k, 32), sU1[(32 + k) * 32 + c], a2v);
        float t = fmaxf(a2v, 0.0f);
        float o = sB[96 + c];
        #pragma unroll
        for (int k = 0; k < 32; k++)
            o = fmaf(__shfl(t, k, 32), sU2[k * 32 + c], o);

        if (lane < 32) h_out[(size_t)n * 32 + c] = hn + o;
    }
}

// -------- R14 fallback kernels (atomic path), used only if ws too small -----

__global__ void __launch_bounds__(256)
k_message(const float* __restrict__ h, const int2* __restrict__ edges,
          const float4* __restrict__ ef,
          const float* __restrict__ w1g, const float* __restrict__ b1g,
          const float* __restrict__ w2g, const float* __restrict__ b2g,
          float* __restrict__ agg, int n_edges)
{
    __shared__ float sw1[68 * 32];
    __shared__ float sw2[32 * 32];
    __shared__ float sb1[32];
    __shared__ float sb2[32];
    for (int i = threadIdx.x; i < 68 * 32; i += 256) sw1[i] = w1g[i];
    for (int i = threadIdx.x; i < 32 * 32; i += 256) sw2[i] = w2g[i];
    if (threadIdx.x < 32) {
        sb1[threadIdx.x] = b1g[threadIdx.x];
        sb2[threadIdx.x] = b2g[threadIdx.x];
    }
    __syncthreads();
    int e = blockIdx.x * 256 + threadIdx.x;
    if (e >= n_edges) return;

    int2 ed = edges[e];
    const float4* hs = (const float4*)(h + (size_t)ed.x * 32);
    const float4* hd = (const float4*)(h + (size_t)ed.y * 32);

    float acc[32];
    #pragma unroll
    for (int j = 0; j < 32; j++) acc[j] = sb1[j];
    #pragma unroll 2
    for (int cc = 0; cc < 8; cc++) {
        float4 xv = hs[cc];
        float xsv[4] = {xv.x, xv.y, xv.z, xv.w};
        #pragma unroll
        for (int kk = 0; kk < 4; kk++) {
            float xk = xsv[kk];
            const float* wr = &sw1[(cc * 4 + kk) * 32];
            #pragma unroll
            for (int j = 0; j < 32; j++) acc[j] = fmaf(xk, wr[j], acc[j]);
        }
    }
    #pragma unroll 2
    for (int cc = 0; cc < 8; cc++) {
        float4 xv = hd[cc];
        float xsv[4] = {xv.x, xv.y, xv.z, xv.w};
        #pragma unroll
        for (int kk = 0; kk < 4; kk++) {
            float xk = xsv[kk];
            const float* wr = &sw1[(32 + cc * 4 + kk) * 32];
            #pragma unroll
            for (int j = 0; j < 32; j++) acc[j] = fmaf(xk, wr[j], acc[j]);
        }
    }
    {
        float4 evv = ef[e];
        float ex[4] = {evv.x, evv.y, evv.z, evv.w};
        #pragma unroll
        for (int kk = 0; kk < 4; kk++) {
            float xk = ex[kk];
            const float* wr = &sw1[(64 + kk) * 32];
            #pragma unroll
            for (int j = 0; j < 32; j++) acc[j] = fmaf(xk, wr[j], acc[j]);
        }
    }
    #pragma unroll
    for (int j = 0; j < 32; j++) acc[j] = fmaxf(acc[j], 0.0f);

    float o[32];
    #pragma unroll
    for (int j = 0; j < 32; j++) o[j] = sb2[j];
    #pragma unroll 4
    for (int k = 0; k < 32; k++) {
        float hk = acc[k];
        const float* wr = &sw2[k * 32];
        #pragma unroll
        for (int j = 0; j < 32; j++) o[j] = fmaf(hk, wr[j], o[j]);
    }
    float* ap = agg + (size_t)ed.y * 32;
    #pragma unroll
    for (int j = 0; j < 32; j++) atomicAdd(ap + j, o[j]);
}

__global__ void __launch_bounds__(256)
k_update(float* h, const float* __restrict__ agg,
         const float* __restrict__ w1g, const float* __restrict__ b1g,
         const float* __restrict__ w2g, const float* __restrict__ b2g,
         int n_nodes)
{
    __shared__ float sw1[64 * 32];
    __shared__ float sw2[32 * 32];
    __shared__ float sb1[32];
    __shared__ float sb2[32];
    for (int i = threadIdx.x; i < 64 * 32; i += 256) sw1[i] = w1g[i];
    for (int i = threadIdx.x; i < 32 * 32; i += 256) sw2[i] = w2g[i];
    if (threadIdx.x < 32) {
        sb1[threadIdx.x] = b1g[threadIdx.x];
        sb2[threadIdx.x] = b2g[threadIdx.x];
    }
    __syncthreads();
    int n = blockIdx.x * 256 + threadIdx.x;
    if (n >= n_nodes) return;

    const float4* hp = (const float4*)(h + (size_t)n * 32);
    const float4* ap = (const float4*)(agg + (size_t)n * 32);

    float hv[32];
    float acc[32];
    #pragma unroll
    for (int j = 0; j < 32; j++) acc[j] = sb1[j];
    #pragma unroll 2
    for (int cc = 0; cc < 8; cc++) {
        float4 xv = hp[cc];
        hv[4 * cc] = xv.x; hv[4 * cc + 1] = xv.y; hv[4 * cc + 2] = xv.z; hv[4 * cc + 3] = xv.w;
        float xsv[4] = {xv.x, xv.y, xv.z, xv.w};
        #pragma unroll
        for (int kk = 0; kk < 4; kk++) {
            float xk = xsv[kk];
            const float* wr = &sw1[(cc * 4 + kk) * 32];
            #pragma unroll
            for (int j = 0; j < 32; j++) acc[j] = fmaf(xk, wr[j], acc[j]);
        }
    }
    #pragma unroll 2
    for (int cc = 0; cc < 8; cc++) {
        float4 xv = ap[cc];
        float xsv[4] = {xv.x, xv.y, xv.z, xv.w};
        #pragma unroll
        for (int kk = 0; kk < 4; kk++) {
            float xk = xsv[kk];
            const float* wr = &sw1[(32 + cc * 4 + kk) * 32];
            #pragma unroll
            for (int j = 0; j < 32; j++) acc[j] = fmaf(xk, wr[j], acc[j]);
        }
    }
    #pragma unroll
    for (int j = 0; j < 32; j++) acc[j] = fmaxf(acc[j], 0.0f);

    float o[32];
    #pragma unroll
    for (int j = 0; j < 32; j++) o[j] = sb2[j];
    #pragma unroll 4
    for (int k = 0; k < 32; k++) {
        float hk = acc[k];
        const float* wr = &sw2[k * 32];
        #pragma unroll
        for (int j = 0; j < 32; j++) o[j] = fmaf(hk, wr[j], o[j]);
    }
    float4* op = (float4*)(h + (size_t)n * 32);
    #pragma unroll
    for (int cc = 0; cc < 8; cc++)
        op[cc] = make_float4(hv[4 * cc] + o[4 * cc], hv[4 * cc + 1] + o[4 * cc + 1],
                             hv[4 * cc + 2] + o[4 * cc + 2], hv[4 * cc + 3] + o[4 * cc + 3]);
}

// head: out = (relu(h @ w1 + b1) @ w2 + b2)[:, 0]   (fp32 out)
__global__ void AtomGNN_56169582297457_kernel(const float* h, const float* w1g, const float* b1g, const float* w2g, const float* b2g, float* out, int n_nodes) {
    __shared__ float sw1[32 * 32];
    __shared__ float sb1[32];
    __shared__ float sw2[32];
    __shared__ float sb2;
    for (int i = threadIdx.x; i < 32 * 32; i += 256) sw1[i] = w1g[i];
    if (threadIdx.x < 32) {
        sb1[threadIdx.x] = b1g[threadIdx.x];
        sw2[threadIdx.x] = w2g[threadIdx.x];
    }
    if (threadIdx.x == 0) sb2 = b2g[0];
    __syncthreads();
    int n = blockIdx.x * 256 + threadIdx.x;
    if (n >= n_nodes) return;

    const float4* hp = (const float4*)(h + (size_t)n * 32);
    float x[32];
    #pragma unroll
    for (int cc = 0; cc < 8; cc++) {
        float4 xv = hp[cc];
        x[4 * cc] = xv.x; x[4 * cc + 1] = xv.y; x[4 * cc + 2] = xv.z; x[4 * cc + 3] = xv.w;
    }
    float acc[32];
    #pragma unroll
    for (int j = 0; j < 32; j++) acc[j] = sb1[j];
    #pragma unroll 4
    for (int k = 0; k < 32; k++) {
        float xk = x[k];
        const float* wr = &sw1[k * 32];
        #pragma unroll
        for (int j = 0; j < 32; j++) acc[j] = fmaf(xk, wr[j], acc[j]);
    }
    float val = sb2;
    #pragma unroll
    for (int k = 0; k < 32; k++) val = fmaf(fmaxf(acc[k], 0.0f), sw2[k], val);
    out[n] = val;
}

extern "C" void kernel_launch(void* const* d_in, const int* in_sizes, int n_in,
                              void* d_out, int out_size, void* d_ws, size_t ws_size,
                              hipStream_t stream) {
    const float* nf      = (const float*)d_in[0];
    const int2*  edges   = (const int2*)d_in[1];
    const float4* ef     = (const float4*)d_in[2];
    const float* enc_w1  = (const float*)d_in[3];
    const float* enc_b1  = (const float*)d_in[4];
    const float* enc_w2  = (const float*)d_in[5];
    const float* enc_b2  = (const float*)d_in[6];
    const float* msg_w1  = (const float*)d_in[7];
    const float* msg_b1  = (const float*)d_in[8];
    const float* msg_w2  = (const float*)d_in[9];
    const float* msg_b2  = (const float*)d_in[10];
    const float* upd_w1  = (const float*)d_in[11];
    const float* upd_b1  = (const float*)d_in[12];
    const float* upd_w2  = (const float*)d_in[13];
    const float* upd_b2  = (const float*)d_in[14];
    const float* head_w1 = (const float*)d_in[15];
    const float* head_b1 = (const float*)d_in[16];
    const float* head_w2 = (const float*)d_in[17];
    const float* head_b2 = (const float*)d_in[18];

    int n_nodes = (out_size > 0) ? out_size : NN_REF;
    int n_edges = (in_sizes && n_in > 2 && in_sizes[2] > 0) ? in_sizes[2] / 4 : NE_REF;

    int nb_nodes = (n_nodes + 255) / 256;
    int nb_edges = (n_edges + 255) / 256;

    // Workspace layout:
    //   h0 | h1 | g16(half) | row_start[n+1] | cursor[n] | bsum[nb]
    //   | srcs[E] | eidx[E] | pad16 | efp[E] float4 (optional)
    float* h0 = (float*)d_ws;
    float* h1 = h0 + (size_t)n_nodes * 32;
    __half* g16 = (__half*)(h1 + (size_t)n_nodes * 32);
    int* row_start = (int*)(g16 + (size_t)n_nodes * 32);
    int* cursor = row_start + (n_nodes + 1);
    int* bsum = cursor + n_nodes;
    int* srcs = bsum + nb_nodes;
    int* eidx = srcs + n_edges;
    uintptr_t efp_addr = ((uintptr_t)(eidx + n_edges) + 15) & ~(uintptr_t)15;
    float4* efp = (float4*)efp_addr;

    size_t required_base = (efp_addr - (uintptr_t)d_ws);
    size_t required_perm = required_base + (size_t)n_edges * 16;

    bool ws_any  = (ws_size == 0);
    bool csr_ok  = (nb_nodes <= 1024) && (ws_any || ws_size >= required_base);
    bool perm_ok = csr_ok && (ws_any || ws_size >= required_perm);

    if (csr_ok) {
        k_encode<<<nb_nodes, 256, 0, stream>>>(nf, enc_w1, enc_b1, enc_w2, enc_b2, h0, n_nodes);

        // build dst-CSR once (edges identical across rounds)
        k_zero<<<256, 256, 0, stream>>>((float*)cursor, n_nodes);
        k_hist<<<nb_edges, 256, 0, stream>>>(edges, cursor, n_edges);
        k_scan_block<<<nb_nodes, 256, 0, stream>>>(cursor, row_start, bsum, n_nodes);
        k_scan_bsum<<<1, 1024, 0, stream>>>(bsum, nb_nodes, row_start, n_nodes, n_edges);
        k_scan_add<<<nb_nodes, 256, 0, stream>>>(row_start, cursor, bsum, n_nodes);
        k_fill2<<<nb_edges, 256, 0, stream>>>(edges, ef, cursor, srcs, eidx, efp,
                                              n_edges, perm_ok ? 1 : 0);

        // ping-pong rounds: h0 -> h1 -> h0
        for (int r = 0; r < 2; r++) {
            const float* hin = (r == 0) ? h0 : h1;
            float* hout      = (r == 0) ? h1 : h0;
            const float* mw1 = msg_w1 + (size_t)r * 68 * 32;
            k_gsrc16<<<1024, 256, 0, stream>>>(hin, mw1, g16, n_nodes);
            k_round_wave4<<<2048, 256, 0, stream>>>(
                hin, hout, g16, row_start, srcs, eidx, efp, ef,
                mw1, msg_b1 + (size_t)r * 32,
                msg_w2 + (size_t)r * 32 * 32, msg_b2 + (size_t)r * 32,
                upd_w1 + (size_t)r * 64 * 32, upd_b1 + (size_t)r * 32,
                upd_w2 + (size_t)r * 32 * 32, upd_b2 + (size_t)r * 32,
                n_nodes, perm_ok ? 1 : 0);
        }

        AtomGNN_56169582297457_kernel<<<nb_nodes, 256, 0, stream>>>(
            h0, head_w1, head_b1, head_w2, head_b2, (float*)d_out, n_nodes);
    } else {
        // R14 fallback: atomic scatter path
        float* h   = (float*)d_ws;
        float* agg = h + (size_t)n_nodes * 32;

        k_encode<<<nb_nodes, 256, 0, stream>>>(nf, enc_w1, enc_b1, enc_w2, enc_b2, h, n_nodes);
        for (int r = 0; r < 2; r++) {
            k_zero<<<1024, 256, 0, stream>>>(agg, n_nodes * 32);
            k_message<<<nb_edges, 256, 0, stream>>>(
                h, edges, ef,
                msg_w1 + (size_t)r * 68 * 32, msg_b1 + (size_t)r * 32,
                msg_w2 + (size_t)r * 32 * 32, msg_b2 + (size_t)r * 32,
                agg, n_edges);
            k_update<<<nb_nodes, 256, 0, stream>>>(
                h, agg,
                upd_w1 + (size_t)r * 64 * 32, upd_b1 + (size_t)r * 32,
                upd_w2 + (size_t)r * 32 * 32, upd_b2 + (size_t)r * 32,
                n_nodes);
        }
        AtomGNN_56169582297457_kernel<<<nb_nodes, 256, 0, stream>>>(
            h, head_w1, head_b1, head_w2, head_b2, (float*)d_out, n_nodes);
    }
}

// Round 7
// 1749.703 us; speedup vs baseline: 1.8497x; 1.1116x over previous
//
#include <hip/hip_runtime.h>
#include <hip/hip_fp16.h>
#include <cstdio>
#include <cstdint>

// R21: kill the random-ef line reads with certainty. R20's FETCH only dropped
// 1.74->1.56 GB with fp16 g (miss LINES dominate the gather, not payload), and
// 486 B/edge implies the ef[eidx[s]] random 16-of-128B reads (~410MB + eidx)
// were live => perm_ok was false (ws < 110MB). R21 packs (src, fp16 ef) into
// ONE 12B slot record written at CSR fill; the round kernel streams a single
// sequential 38.4MB record array. Workspace = 71.2MB < proven-fitting 77.6MB
// -> no gating, no fallback ambiguity. fp16 ef error ~5e-5 (passing absmax is
// 9.77e-4). Reserve lever if gather still dominates (FETCH>=0.9GB/round):
// per-row src sort -> order-statistics L2 window. R14 atomic path kept as
// deep fallback.

__attribute__((constructor)) static void atomgnn_r21_load_beacon() {
    fprintf(stderr, "ATOMGNN_R21_SOURCE_LOADED\n");
    fflush(stderr);
}

#define NN_REF 100000
#define NE_REF 3200000

// zero a float/int buffer (4B words), grid-stride
__global__ void __launch_bounds__(256)
k_zero(float* __restrict__ p, int n)
{
    int i = blockIdx.x * 256 + threadIdx.x;
    int stride = gridDim.x * 256;
    for (; i < n; i += stride) p[i] = 0.0f;
}

// encoder: h = relu(nf @ w1 + b1) @ w2 + b2   (16 -> 32 -> 32)
__global__ void __launch_bounds__(256)
k_encode(const float* __restrict__ nf,
         const float* __restrict__ w1g, const float* __restrict__ b1g,
         const float* __restrict__ w2g, const float* __restrict__ b2g,
         float* __restrict__ h, int n_nodes)
{
    __shared__ float sw1[16 * 32];
    __shared__ float sw2[32 * 32];
    __shared__ float sb1[32];
    __shared__ float sb2[32];
    for (int i = threadIdx.x; i < 16 * 32; i += 256) sw1[i] = w1g[i];
    for (int i = threadIdx.x; i < 32 * 32; i += 256) sw2[i] = w2g[i];
    if (threadIdx.x < 32) {
        sb1[threadIdx.x] = b1g[threadIdx.x];
        sb2[threadIdx.x] = b2g[threadIdx.x];
    }
    __syncthreads();
    int n = blockIdx.x * 256 + threadIdx.x;
    if (n >= n_nodes) return;

    const float4* p = (const float4*)(nf + (size_t)n * 16);
    float x[16];
    #pragma unroll
    for (int c = 0; c < 4; c++) {
        float4 v = p[c];
        x[4 * c] = v.x; x[4 * c + 1] = v.y; x[4 * c + 2] = v.z; x[4 * c + 3] = v.w;
    }

    float acc[32];
    #pragma unroll
    for (int j = 0; j < 32; j++) acc[j] = sb1[j];
    #pragma unroll 4
    for (int k = 0; k < 16; k++) {
        float xk = x[k];
        const float* wr = &sw1[k * 32];
        #pragma unroll
        for (int j = 0; j < 32; j++) acc[j] = fmaf(xk, wr[j], acc[j]);
    }
    #pragma unroll
    for (int j = 0; j < 32; j++) acc[j] = fmaxf(acc[j], 0.0f);

    float o[32];
    #pragma unroll
    for (int j = 0; j < 32; j++) o[j] = sb2[j];
    #pragma unroll 4
    for (int k = 0; k < 32; k++) {
        float hk = acc[k];
        const float* wr = &sw2[k * 32];
        #pragma unroll
        for (int j = 0; j < 32; j++) o[j] = fmaf(hk, wr[j], o[j]);
    }
    float4* hp = (float4*)(h + (size_t)n * 32);
    #pragma unroll
    for (int c = 0; c < 8; c++)
        hp[c] = make_float4(o[4 * c], o[4 * c + 1], o[4 * c + 2], o[4 * c + 3]);
}

// -------- CSR build: histogram -> exclusive scan -> fill --------

__global__ void __launch_bounds__(256)
k_hist(const int2* __restrict__ edges, int* __restrict__ cnt, int n_edges)
{
    int e = blockIdx.x * 256 + threadIdx.x;
    if (e >= n_edges) return;
    atomicAdd(&cnt[edges[e].y], 1);
}

__global__ void __launch_bounds__(256)
k_scan_block(const int* __restrict__ cnt, int* __restrict__ rs,
             int* __restrict__ bsum, int n)
{
    __shared__ int sd[256];
    int t = threadIdx.x;
    int i = blockIdx.x * 256 + t;
    int v = (i < n) ? cnt[i] : 0;
    sd[t] = v;
    __syncthreads();
    int val = v;
    for (int off = 1; off < 256; off <<= 1) {
        int add = (t >= off) ? sd[t - off] : 0;
        __syncthreads();
        val += add;
        sd[t] = val;
        __syncthreads();
    }
    if (i < n) rs[i] = val - v;           // exclusive within block
    if (t == 255) bsum[blockIdx.x] = val; // block total
}

__global__ void __launch_bounds__(1024)
k_scan_bsum(int* __restrict__ bsum, int nb, int* __restrict__ rs,
            int n_nodes, int n_edges)
{
    __shared__ int sd[1024];
    int t = threadIdx.x;
    int v = (t < nb) ? bsum[t] : 0;
    sd[t] = v;
    __syncthreads();
    int val = v;
    for (int off = 1; off < 1024; off <<= 1) {
        int add = (t >= off) ? sd[t - off] : 0;
        __syncthreads();
        val += add;
        sd[t] = val;
        __syncthreads();
    }
    if (t < nb) bsum[t] = val - v;  // exclusive prefix of block totals
    if (t == 0) rs[n_nodes] = n_edges;
}

__global__ void __launch_bounds__(256)
k_scan_add(int* __restrict__ rs, int* __restrict__ cursor,
           const int* __restrict__ bsum, int n)
{
    int i = blockIdx.x * 256 + threadIdx.x;
    if (i < n) {
        int v = rs[i] + bsum[blockIdx.x];
        rs[i] = v;
        cursor[i] = v;
    }
}

// scatter edges into dst-sorted packed slot records:
//   recs[3*pos] = src, recs[3*pos+1] = half2(ef.x,ef.y),
//   recs[3*pos+2] = half2(ef.z,ef.w)
__global__ void __launch_bounds__(256)
k_fill3(const int2* __restrict__ edges, const float4* __restrict__ ef,
        int* __restrict__ cursor, int* __restrict__ recs, int n_edges)
{
    int e = blockIdx.x * 256 + threadIdx.x;
    if (e >= n_edges) return;
    int2 ed = edges[e];
    float4 v = ef[e];
    int pos = atomicAdd(&cursor[ed.y], 1);
    __half2 h01 = __floats2half2_rn(v.x, v.y);
    __half2 h23 = __floats2half2_rn(v.z, v.w);
    recs[3 * pos]     = ed.x;
    recs[3 * pos + 1] = *reinterpret_cast<int*>(&h01);
    recs[3 * pos + 2] = *reinterpret_cast<int*>(&h23);
}

// -------- per-round precompute: g16[n][c] = fp16( sum_k h[n][k]*W1a[k][c] )
__global__ void __launch_bounds__(256)
k_gsrc16(const float* __restrict__ h, const float* __restrict__ mw1,
         __half* __restrict__ g16, int n_nodes)
{
    __shared__ float sW[32 * 32];
    for (int i = threadIdx.x; i < 32 * 32; i += 256) sW[i] = mw1[i];
    __syncthreads();
    const int lane = threadIdx.x & 63;
    const int c    = lane & 31;
    const int half = lane >> 5;
    int wi = (int)((blockIdx.x * 256 + threadIdx.x) >> 6);
    int nw = gridDim.x * 4;
    for (; 2 * wi < n_nodes; wi += nw) {
        int nr = 2 * wi + half;
        int n  = min(nr, n_nodes - 1);
        float hn = h[(size_t)n * 32 + c];
        float b = 0.0f;
        #pragma unroll
        for (int k = 0; k < 32; k++)
            b = fmaf(__shfl(hn, k, 32), sW[k * 32 + c], b);
        if (nr < n_nodes) g16[(size_t)n * 32 + c] = __float2half(b);
    }
}

// -------- fused round v5: wave-per-node, fp16-g gather, packed records ------
// per edge: m1[c] = relu(base[dst][c] + g[src][c] + sum_k ef[k]*W1c[k][c])
// records stream sequentially; g16 is the only random access.
__global__ void __launch_bounds__(256, 4)
k_round_wave5(const float* __restrict__ h_in, float* __restrict__ h_out,
        const __half* __restrict__ g16,
        const int* __restrict__ row_start, const int* __restrict__ recs,
        const float* __restrict__ mw1, const float* __restrict__ mb1,
        const float* __restrict__ mw2, const float* __restrict__ mb2,
        const float* __restrict__ uw1, const float* __restrict__ ub1,
        const float* __restrict__ uw2, const float* __restrict__ ub2,
        int n_nodes)
{
    __shared__ float sW1b[32 * 32];   // msg_w1 rows 32..63 (dst half)
    __shared__ float sW2[32 * 32];
    __shared__ float sU1[64 * 32];
    __shared__ float sU2[32 * 32];
    __shared__ float sB[4 * 32];      // mb1 | mb2 | ub1 | ub2
    for (int i = threadIdx.x; i < 32 * 32; i += 256) sW1b[i] = mw1[32 * 32 + i];
    for (int i = threadIdx.x; i < 32 * 32; i += 256) sW2[i]  = mw2[i];
    for (int i = threadIdx.x; i < 64 * 32; i += 256) sU1[i]  = uw1[i];
    for (int i = threadIdx.x; i < 32 * 32; i += 256) sU2[i]  = uw2[i];
    if (threadIdx.x < 32) {
        sB[threadIdx.x]      = mb1[threadIdx.x];
        sB[32 + threadIdx.x] = mb2[threadIdx.x];
        sB[64 + threadIdx.x] = ub1[threadIdx.x];
        sB[96 + threadIdx.x] = ub2[threadIdx.x];
    }
    __syncthreads();

    const int lane = threadIdx.x & 63;
    const int c    = lane & 31;
    const int half = lane >> 5;

    // per-lane private ef column of msg W1 (k=0..3)
    float w1c[4];
    #pragma unroll
    for (int k = 0; k < 4; k++) w1c[k] = mw1[(64 + k) * 32 + c];

    int wave   = (int)((blockIdx.x * 256 + threadIdx.x) >> 6);
    int nwaves = gridDim.x * 4;

    for (int n = wave; n < n_nodes; n += nwaves) {
        float hn = h_in[(size_t)n * 32 + c];

        // base = mb1 + h[n] @ W1b (dst-half hoisted out of the edge loop)
        float base = sB[c];
        #pragma unroll
        for (int k = 0; k < 32; k++)
            base = fmaf(__shfl(hn, k, 32), sW1b[k * 32 + c], base);

        int s0 = row_start[n];
        int s1 = row_start[n + 1];
        float rsum = 0.0f;

        int s = s0 + half;   // this half's slots: s, s+2, s+4, ...
        // main loop: 4 edges per half in flight
        for (; s + 6 < s1; s += 8) {
            int b0 = 3 * s;
            int b1 = 3 * (s + 2);
            int b2 = 3 * (s + 4);
            int b3 = 3 * (s + 6);
            int i0 = recs[b0];
            int i1 = recs[b1];
            int i2 = recs[b2];
            int i3 = recs[b3];
            uint32_t u01_0 = (uint32_t)recs[b0 + 1], u23_0 = (uint32_t)recs[b0 + 2];
            uint32_t u01_1 = (uint32_t)recs[b1 + 1], u23_1 = (uint32_t)recs[b1 + 2];
            uint32_t u01_2 = (uint32_t)recs[b2 + 1], u23_2 = (uint32_t)recs[b2 + 2];
            uint32_t u01_3 = (uint32_t)recs[b3 + 1], u23_3 = (uint32_t)recs[b3 + 2];
            float x0 = __half2float(g16[(size_t)i0 * 32 + c]);
            float x1 = __half2float(g16[(size_t)i1 * 32 + c]);
            float x2 = __half2float(g16[(size_t)i2 * 32 + c]);
            float x3 = __half2float(g16[(size_t)i3 * 32 + c]);

            float2 eA0 = __half22float2(*reinterpret_cast<const __half2*>(&u01_0));
            float2 eB0 = __half22float2(*reinterpret_cast<const __half2*>(&u23_0));
            float2 eA1 = __half22float2(*reinterpret_cast<const __half2*>(&u01_1));
            float2 eB1 = __half22float2(*reinterpret_cast<const __half2*>(&u23_1));
            float2 eA2 = __half22float2(*reinterpret_cast<const __half2*>(&u01_2));
            float2 eB2 = __half22float2(*reinterpret_cast<const __half2*>(&u23_2));
            float2 eA3 = __half22float2(*reinterpret_cast<const __half2*>(&u01_3));
            float2 eB3 = __half22float2(*reinterpret_cast<const __half2*>(&u23_3));

            float a0 = base + x0;
            float a1 = base + x1;
            float a2 = base + x2;
            float a3 = base + x3;
            a0 = fmaf(eA0.x, w1c[0], a0); a0 = fmaf(eA0.y, w1c[1], a0);
            a0 = fmaf(eB0.x, w1c[2], a0); a0 = fmaf(eB0.y, w1c[3], a0);
            a1 = fmaf(eA1.x, w1c[0], a1); a1 = fmaf(eA1.y, w1c[1], a1);
            a1 = fmaf(eB1.x, w1c[2], a1); a1 = fmaf(eB1.y, w1c[3], a1);
            a2 = fmaf(eA2.x, w1c[0], a2); a2 = fmaf(eA2.y, w1c[1], a2);
            a2 = fmaf(eB2.x, w1c[2], a2); a2 = fmaf(eB2.y, w1c[3], a2);
            a3 = fmaf(eA3.x, w1c[0], a3); a3 = fmaf(eA3.y, w1c[1], a3);
            a3 = fmaf(eB3.x, w1c[2], a3); a3 = fmaf(eB3.y, w1c[3], a3);

            rsum += fmaxf(a0, 0.0f);
            rsum += fmaxf(a1, 0.0f);
            rsum += fmaxf(a2, 0.0f);
            rsum += fmaxf(a3, 0.0f);
        }
        // tail: one edge at a time
        for (; s < s1; s += 2) {
            int b = 3 * s;
            int i0 = recs[b];
            uint32_t u01 = (uint32_t)recs[b + 1], u23 = (uint32_t)recs[b + 2];
            float x = __half2float(g16[(size_t)i0 * 32 + c]);
            float2 eA = __half22float2(*reinterpret_cast<const __half2*>(&u01));
            float2 eB = __half22float2(*reinterpret_cast<const __half2*>(&u23));
            float a = base + x;
            a = fmaf(eA.x, w1c[0], a); a = fmaf(eA.y, w1c[1], a);
            a = fmaf(eB.x, w1c[2], a); a = fmaf(eB.y, w1c[3], a);
            rsum += fmaxf(a, 0.0f);
        }
        // combine halves (both halves converged here)
        rsum += __shfl_xor(rsum, 32, 64);

        // agg = deg*mb2 + rsum @ W2 (W2 hoisted by linearity)
        float deg = (float)(s1 - s0);
        float agg = deg * sB[32 + c];
        #pragma unroll
        for (int k = 0; k < 32; k++)
            agg = fmaf(__shfl(rsum, k, 32), sW2[k * 32 + c], agg);

        // update MLP
        float a2v = sB[64 + c];
        #pragma unroll
        for (int k = 0; k < 32; k++)
            a2v = fmaf(__shfl(hn, k, 32), sU1[k * 32 + c], a2v);
        #pragma unroll
        for (int k = 0; k < 32; k++)
            a2v = fmaf(__shfl(agg, k, 32), sU1[(32 + k) * 32 + c], a2v);
        float t = fmaxf(a2v, 0.0f);
        float o = sB[96 + c];
        #pragma unroll
        for (int k = 0; k < 32; k++)
            o = fmaf(__shfl(t, k, 32), sU2[k * 32 + c], o);

        if (lane < 32) h_out[(size_t)n * 32 + c] = hn + o;
    }
}

// -------- R14 fallback kernels (atomic path), used only if ws too small -----

__global__ void __launch_bounds__(256)
k_message(const float* __restrict__ h, const int2* __restrict__ edges,
          const float4* __restrict__ ef,
          const float* __restrict__ w1g, const float* __restrict__ b1g,
          const float* __restrict__ w2g, const float* __restrict__ b2g,
          float* __restrict__ agg, int n_edges)
{
    __shared__ float sw1[68 * 32];
    __shared__ float sw2[32 * 32];
    __shared__ float sb1[32];
    __shared__ float sb2[32];
    for (int i = threadIdx.x; i < 68 * 32; i += 256) sw1[i] = w1g[i];
    for (int i = threadIdx.x; i < 32 * 32; i += 256) sw2[i] = w2g[i];
    if (threadIdx.x < 32) {
        sb1[threadIdx.x] = b1g[threadIdx.x];
        sb2[threadIdx.x] = b2g[threadIdx.x];
    }
    __syncthreads();
    int e = blockIdx.x * 256 + threadIdx.x;
    if (e >= n_edges) return;

    int2 ed = edges[e];
    const float4* hs = (const float4*)(h + (size_t)ed.x * 32);
    const float4* hd = (const float4*)(h + (size_t)ed.y * 32);

    float acc[32];
    #pragma unroll
    for (int j = 0; j < 32; j++) acc[j] = sb1[j];
    #pragma unroll 2
    for (int cc = 0; cc < 8; cc++) {
        float4 xv = hs[cc];
        float xsv[4] = {xv.x, xv.y, xv.z, xv.w};
        #pragma unroll
        for (int kk = 0; kk < 4; kk++) {
            float xk = xsv[kk];
            const float* wr = &sw1[(cc * 4 + kk) * 32];
            #pragma unroll
            for (int j = 0; j < 32; j++) acc[j] = fmaf(xk, wr[j], acc[j]);
        }
    }
    #pragma unroll 2
    for (int cc = 0; cc < 8; cc++) {
        float4 xv = hd[cc];
        float xsv[4] = {xv.x, xv.y, xv.z, xv.w};
        #pragma unroll
        for (int kk = 0; kk < 4; kk++) {
            float xk = xsv[kk];
            const float* wr = &sw1[(32 + cc * 4 + kk) * 32];
            #pragma unroll
            for (int j = 0; j < 32; j++) acc[j] = fmaf(xk, wr[j], acc[j]);
        }
    }
    {
        float4 evv = ef[e];
        float ex[4] = {evv.x, evv.y, evv.z, evv.w};
        #pragma unroll
        for (int kk = 0; kk < 4; kk++) {
            float xk = ex[kk];
            const float* wr = &sw1[(64 + kk) * 32];
            #pragma unroll
            for (int j = 0; j < 32; j++) acc[j] = fmaf(xk, wr[j], acc[j]);
        }
    }
    #pragma unroll
    for (int j = 0; j < 32; j++) acc[j] = fmaxf(acc[j], 0.0f);

    float o[32];
    #pragma unroll
    for (int j = 0; j < 32; j++) o[j] = sb2[j];
    #pragma unroll 4
    for (int k = 0; k < 32; k++) {
        float hk = acc[k];
        const float* wr = &sw2[k * 32];
        #pragma unroll
        for (int j = 0; j < 32; j++) o[j] = fmaf(hk, wr[j], o[j]);
    }
    float* ap = agg + (size_t)ed.y * 32;
    #pragma unroll
    for (int j = 0; j < 32; j++) atomicAdd(ap + j, o[j]);
}

__global__ void __launch_bounds__(256)
k_update(float* h, const float* __restrict__ agg,
         const float* __restrict__ w1g, const float* __restrict__ b1g,
         const float* __restrict__ w2g, const float* __restrict__ b2g,
         int n_nodes)
{
    __shared__ float sw1[64 * 32];
    __shared__ float sw2[32 * 32];
    __shared__ float sb1[32];
    __shared__ float sb2[32];
    for (int i = threadIdx.x; i < 64 * 32; i += 256) sw1[i] = w1g[i];
    for (int i = threadIdx.x; i < 32 * 32; i += 256) sw2[i] = w2g[i];
    if (threadIdx.x < 32) {
        sb1[threadIdx.x] = b1g[threadIdx.x];
        sb2[threadIdx.x] = b2g[threadIdx.x];
    }
    __syncthreads();
    int n = blockIdx.x * 256 + threadIdx.x;
    if (n >= n_nodes) return;

    const float4* hp = (const float4*)(h + (size_t)n * 32);
    const float4* ap = (const float4*)(agg + (size_t)n * 32);

    float hv[32];
    float acc[32];
    #pragma unroll
    for (int j = 0; j < 32; j++) acc[j] = sb1[j];
    #pragma unroll 2
    for (int cc = 0; cc < 8; cc++) {
        float4 xv = hp[cc];
        hv[4 * cc] = xv.x; hv[4 * cc + 1] = xv.y; hv[4 * cc + 2] = xv.z; hv[4 * cc + 3] = xv.w;
        float xsv[4] = {xv.x, xv.y, xv.z, xv.w};
        #pragma unroll
        for (int kk = 0; kk < 4; kk++) {
            float xk = xsv[kk];
            const float* wr = &sw1[(cc * 4 + kk) * 32];
            #pragma unroll
            for (int j = 0; j < 32; j++) acc[j] = fmaf(xk, wr[j], acc[j]);
        }
    }
    #pragma unroll 2
    for (int cc = 0; cc < 8; cc++) {
        float4 xv = ap[cc];
        float xsv[4] = {xv.x, xv.y, xv.z, xv.w};
        #pragma unroll
        for (int kk = 0; kk < 4; kk++) {
            float xk = xsv[kk];
            const float* wr = &sw1[(32 + cc * 4 + kk) * 32];
            #pragma unroll
            for (int j = 0; j < 32; j++) acc[j] = fmaf(xk, wr[j], acc[j]);
        }
    }
    #pragma unroll
    for (int j = 0; j < 32; j++) acc[j] = fmaxf(acc[j], 0.0f);

    float o[32];
    #pragma unroll
    for (int j = 0; j < 32; j++) o[j] = sb2[j];
    #pragma unroll 4
    for (int k = 0; k < 32; k++) {
        float hk = acc[k];
        const float* wr = &sw2[k * 32];
        #pragma unroll
        for (int j = 0; j < 32; j++) o[j] = fmaf(hk, wr[j], o[j]);
    }
    float4* op = (float4*)(h + (size_t)n * 32);
    #pragma unroll
    for (int cc = 0; cc < 8; cc++)
        op[cc] = make_float4(hv[4 * cc] + o[4 * cc], hv[4 * cc + 1] + o[4 * cc + 1],
                             hv[4 * cc + 2] + o[4 * cc + 2], hv[4 * cc + 3] + o[4 * cc + 3]);
}

// head: out = (relu(h @ w1 + b1) @ w2 + b2)[:, 0]   (fp32 out)
__global__ void AtomGNN_56169582297457_kernel(const float* h, const float* w1g, const float* b1g, const float* w2g, const float* b2g, float* out, int n_nodes) {
    __shared__ float sw1[32 * 32];
    __shared__ float sb1[32];
    __shared__ float sw2[32];
    __shared__ float sb2;
    for (int i = threadIdx.x; i < 32 * 32; i += 256) sw1[i] = w1g[i];
    if (threadIdx.x < 32) {
        sb1[threadIdx.x] = b1g[threadIdx.x];
        sw2[threadIdx.x] = w2g[threadIdx.x];
    }
    if (threadIdx.x == 0) sb2 = b2g[0];
    __syncthreads();
    int n = blockIdx.x * 256 + threadIdx.x;
    if (n >= n_nodes) return;

    const float4* hp = (const float4*)(h + (size_t)n * 32);
    float x[32];
    #pragma unroll
    for (int cc = 0; cc < 8; cc++) {
        float4 xv = hp[cc];
        x[4 * cc] = xv.x; x[4 * cc + 1] = xv.y; x[4 * cc + 2] = xv.z; x[4 * cc + 3] = xv.w;
    }
    float acc[32];
    #pragma unroll
    for (int j = 0; j < 32; j++) acc[j] = sb1[j];
    #pragma unroll 4
    for (int k = 0; k < 32; k++) {
        float xk = x[k];
        const float* wr = &sw1[k * 32];
        #pragma unroll
        for (int j = 0; j < 32; j++) acc[j] = fmaf(xk, wr[j], acc[j]);
    }
    float val = sb2;
    #pragma unroll
    for (int k = 0; k < 32; k++) val = fmaf(fmaxf(acc[k], 0.0f), sw2[k], val);
    out[n] = val;
}

extern "C" void kernel_launch(void* const* d_in, const int* in_sizes, int n_in,
                              void* d_out, int out_size, void* d_ws, size_t ws_size,
                              hipStream_t stream) {
    const float* nf      = (const float*)d_in[0];
    const int2*  edges   = (const int2*)d_in[1];
    const float4* ef     = (const float4*)d_in[2];
    const float* enc_w1  = (const float*)d_in[3];
    const float* enc_b1  = (const float*)d_in[4];
    const float* enc_w2  = (const float*)d_in[5];
    const float* enc_b2  = (const float*)d_in[6];
    const float* msg_w1  = (const float*)d_in[7];
    const float* msg_b1  = (const float*)d_in[8];
    const float* msg_w2  = (const float*)d_in[9];
    const float* msg_b2  = (const float*)d_in[10];
    const float* upd_w1  = (const float*)d_in[11];
    const float* upd_b1  = (const float*)d_in[12];
    const float* upd_w2  = (const float*)d_in[13];
    const float* upd_b2  = (const float*)d_in[14];
    const float* head_w1 = (const float*)d_in[15];
    const float* head_b1 = (const float*)d_in[16];
    const float* head_w2 = (const float*)d_in[17];
    const float* head_b2 = (const float*)d_in[18];

    int n_nodes = (out_size > 0) ? out_size : NN_REF;
    int n_edges = (in_sizes && n_in > 2 && in_sizes[2] > 0) ? in_sizes[2] / 4 : NE_REF;

    int nb_nodes = (n_nodes + 255) / 256;
    int nb_edges = (n_edges + 255) / 256;

    // Workspace layout (~71.2MB total, below proven-fitting 77.6MB):
    //   h0 | h1 | g16(half) | row_start[n+1] | cursor[n] | bsum[nb]
    //   | recs[3*E] int (packed: src, half2 ef01, half2 ef23)
    float* h0 = (float*)d_ws;
    float* h1 = h0 + (size_t)n_nodes * 32;
    __half* g16 = (__half*)(h1 + (size_t)n_nodes * 32);
    int* row_start = (int*)(g16 + (size_t)n_nodes * 32);
    int* cursor = row_start + (n_nodes + 1);
    int* bsum = cursor + n_nodes;
    int* recs = bsum + nb_nodes;
    size_t required = ((uintptr_t)(recs + (size_t)3 * n_edges) - (uintptr_t)d_ws);

    bool csr_ok = (nb_nodes <= 1024) &&
                  (ws_size == 0 || ws_size >= required);

    if (csr_ok) {
        k_encode<<<nb_nodes, 256, 0, stream>>>(nf, enc_w1, enc_b1, enc_w2, enc_b2, h0, n_nodes);

        // build dst-CSR once (edges identical across rounds)
        k_zero<<<256, 256, 0, stream>>>((float*)cursor, n_nodes);
        k_hist<<<nb_edges, 256, 0, stream>>>(edges, cursor, n_edges);
        k_scan_block<<<nb_nodes, 256, 0, stream>>>(cursor, row_start, bsum, n_nodes);
        k_scan_bsum<<<1, 1024, 0, stream>>>(bsum, nb_nodes, row_start, n_nodes, n_edges);
        k_scan_add<<<nb_nodes, 256, 0, stream>>>(row_start, cursor, bsum, n_nodes);
        k_fill3<<<nb_edges, 256, 0, stream>>>(edges, ef, cursor, recs, n_edges);

        // ping-pong rounds: h0 -> h1 -> h0
        for (int r = 0; r < 2; r++) {
            const float* hin = (r == 0) ? h0 : h1;
            float* hout      = (r == 0) ? h1 : h0;
            const float* mw1 = msg_w1 + (size_t)r * 68 * 32;
            k_gsrc16<<<1024, 256, 0, stream>>>(hin, mw1, g16, n_nodes);
            k_round_wave5<<<2048, 256, 0, stream>>>(
                hin, hout, g16, row_start, recs,
                mw1, msg_b1 + (size_t)r * 32,
                msg_w2 + (size_t)r * 32 * 32, msg_b2 + (size_t)r * 32,
                upd_w1 + (size_t)r * 64 * 32, upd_b1 + (size_t)r * 32,
                upd_w2 + (size_t)r * 32 * 32, upd_b2 + (size_t)r * 32,
                n_nodes);
        }

        AtomGNN_56169582297457_kernel<<<nb_nodes, 256, 0, stream>>>(
            h0, head_w1, head_b1, head_w2, head_b2, (float*)d_out, n_nodes);
    } else {
        // R14 fallback: atomic scatter path
        float* h   = (float*)d_ws;
        float* agg = h + (size_t)n_nodes * 32;

        k_encode<<<nb_nodes, 256, 0, stream>>>(nf, enc_w1, enc_b1, enc_w2, enc_b2, h, n_nodes);
        for (int r = 0; r < 2; r++) {
            k_zero<<<1024, 256, 0, stream>>>(agg, n_nodes * 32);
            k_message<<<nb_edges, 256, 0, stream>>>(
                h, edges, ef,
                msg_w1 + (size_t)r * 68 * 32, msg_b1 + (size_t)r * 32,
                msg_w2 + (size_t)r * 32 * 32, msg_b2 + (size_t)r * 32,
                agg, n_edges);
            k_update<<<nb_nodes, 256, 0, stream>>>(
                h, agg,
                upd_w1 + (size_t)r * 64 * 32, upd_b1 + (size_t)r * 32,
                upd_w2 + (size_t)r * 32 * 32, upd_b2 + (size_t)r * 32,
                n_nodes);
        }
        AtomGNN_56169582297457_kernel<<<nb_nodes, 256, 0, stream>>>(
            h, head_w1, head_b1, head_w2, head_b2, (float*)d_out, n_nodes);
    }
}

// Round 8
// 1553.028 us; speedup vs baseline: 2.0840x; 1.1266x over previous
//
#include <hip/hip_runtime.h>
#include <hip/hip_fp16.h>
#include <cstdio>
#include <cstdint>

// R22: kill the scratch spill. Counter archaeology: R16 (no min-occupancy
// bound, VGPR=140) wrote exactly h_out (12.5MB); R18-R21 with
// __launch_bounds__(256,4) (VGPR capped 64) write 296-583MB -- spill traffic
// scaling with inner-loop liveness, not data (R19 vs R20 identical 304MB).
// ~600MB/round of the 1.85GB traffic-bound total is scratch. Fix: relax to
// __launch_bounds__(256,3) (170 VGPR budget); compiler allocates ~80-100 ->
// zero spill, occupancy by ACTUAL use = 512/~90 = ~5 waves/SIMD (better than
// measured 45%). Single change vs R21 for clean attribution. If WRITE stays
// ~300MB the theory is wrong -> pivot to src-sorted L2 window.

__attribute__((constructor)) static void atomgnn_r22_load_beacon() {
    fprintf(stderr, "ATOMGNN_R22_SOURCE_LOADED\n");
    fflush(stderr);
}

#define NN_REF 100000
#define NE_REF 3200000

// zero a float/int buffer (4B words), grid-stride
__global__ void __launch_bounds__(256)
k_zero(float* __restrict__ p, int n)
{
    int i = blockIdx.x * 256 + threadIdx.x;
    int stride = gridDim.x * 256;
    for (; i < n; i += stride) p[i] = 0.0f;
}

// encoder: h = relu(nf @ w1 + b1) @ w2 + b2   (16 -> 32 -> 32)
__global__ void __launch_bounds__(256)
k_encode(const float* __restrict__ nf,
         const float* __restrict__ w1g, const float* __restrict__ b1g,
         const float* __restrict__ w2g, const float* __restrict__ b2g,
         float* __restrict__ h, int n_nodes)
{
    __shared__ float sw1[16 * 32];
    __shared__ float sw2[32 * 32];
    __shared__ float sb1[32];
    __shared__ float sb2[32];
    for (int i = threadIdx.x; i < 16 * 32; i += 256) sw1[i] = w1g[i];
    for (int i = threadIdx.x; i < 32 * 32; i += 256) sw2[i] = w2g[i];
    if (threadIdx.x < 32) {
        sb1[threadIdx.x] = b1g[threadIdx.x];
        sb2[threadIdx.x] = b2g[threadIdx.x];
    }
    __syncthreads();
    int n = blockIdx.x * 256 + threadIdx.x;
    if (n >= n_nodes) return;

    const float4* p = (const float4*)(nf + (size_t)n * 16);
    float x[16];
    #pragma unroll
    for (int c = 0; c < 4; c++) {
        float4 v = p[c];
        x[4 * c] = v.x; x[4 * c + 1] = v.y; x[4 * c + 2] = v.z; x[4 * c + 3] = v.w;
    }

    float acc[32];
    #pragma unroll
    for (int j = 0; j < 32; j++) acc[j] = sb1[j];
    #pragma unroll 4
    for (int k = 0; k < 16; k++) {
        float xk = x[k];
        const float* wr = &sw1[k * 32];
        #pragma unroll
        for (int j = 0; j < 32; j++) acc[j] = fmaf(xk, wr[j], acc[j]);
    }
    #pragma unroll
    for (int j = 0; j < 32; j++) acc[j] = fmaxf(acc[j], 0.0f);

    float o[32];
    #pragma unroll
    for (int j = 0; j < 32; j++) o[j] = sb2[j];
    #pragma unroll 4
    for (int k = 0; k < 32; k++) {
        float hk = acc[k];
        const float* wr = &sw2[k * 32];
        #pragma unroll
        for (int j = 0; j < 32; j++) o[j] = fmaf(hk, wr[j], o[j]);
    }
    float4* hp = (float4*)(h + (size_t)n * 32);
    #pragma unroll
    for (int c = 0; c < 8; c++)
        hp[c] = make_float4(o[4 * c], o[4 * c + 1], o[4 * c + 2], o[4 * c + 3]);
}

// -------- CSR build: histogram -> exclusive scan -> fill --------

__global__ void __launch_bounds__(256)
k_hist(const int2* __restrict__ edges, int* __restrict__ cnt, int n_edges)
{
    int e = blockIdx.x * 256 + threadIdx.x;
    if (e >= n_edges) return;
    atomicAdd(&cnt[edges[e].y], 1);
}

__global__ void __launch_bounds__(256)
k_scan_block(const int* __restrict__ cnt, int* __restrict__ rs,
             int* __restrict__ bsum, int n)
{
    __shared__ int sd[256];
    int t = threadIdx.x;
    int i = blockIdx.x * 256 + t;
    int v = (i < n) ? cnt[i] : 0;
    sd[t] = v;
    __syncthreads();
    int val = v;
    for (int off = 1; off < 256; off <<= 1) {
        int add = (t >= off) ? sd[t - off] : 0;
        __syncthreads();
        val += add;
        sd[t] = val;
        __syncthreads();
    }
    if (i < n) rs[i] = val - v;           // exclusive within block
    if (t == 255) bsum[blockIdx.x] = val; // block total
}

__global__ void __launch_bounds__(1024)
k_scan_bsum(int* __restrict__ bsum, int nb, int* __restrict__ rs,
            int n_nodes, int n_edges)
{
    __shared__ int sd[1024];
    int t = threadIdx.x;
    int v = (t < nb) ? bsum[t] : 0;
    sd[t] = v;
    __syncthreads();
    int val = v;
    for (int off = 1; off < 1024; off <<= 1) {
        int add = (t >= off) ? sd[t - off] : 0;
        __syncthreads();
        val += add;
        sd[t] = val;
        __syncthreads();
    }
    if (t < nb) bsum[t] = val - v;  // exclusive prefix of block totals
    if (t == 0) rs[n_nodes] = n_edges;
}

__global__ void __launch_bounds__(256)
k_scan_add(int* __restrict__ rs, int* __restrict__ cursor,
           const int* __restrict__ bsum, int n)
{
    int i = blockIdx.x * 256 + threadIdx.x;
    if (i < n) {
        int v = rs[i] + bsum[blockIdx.x];
        rs[i] = v;
        cursor[i] = v;
    }
}

// scatter edges into dst-sorted packed slot records:
//   recs[3*pos] = src, recs[3*pos+1] = half2(ef.x,ef.y),
//   recs[3*pos+2] = half2(ef.z,ef.w)
__global__ void __launch_bounds__(256)
k_fill3(const int2* __restrict__ edges, const float4* __restrict__ ef,
        int* __restrict__ cursor, int* __restrict__ recs, int n_edges)
{
    int e = blockIdx.x * 256 + threadIdx.x;
    if (e >= n_edges) return;
    int2 ed = edges[e];
    float4 v = ef[e];
    int pos = atomicAdd(&cursor[ed.y], 1);
    __half2 h01 = __floats2half2_rn(v.x, v.y);
    __half2 h23 = __floats2half2_rn(v.z, v.w);
    recs[3 * pos]     = ed.x;
    recs[3 * pos + 1] = *reinterpret_cast<int*>(&h01);
    recs[3 * pos + 2] = *reinterpret_cast<int*>(&h23);
}

// -------- per-round precompute: g16[n][c] = fp16( sum_k h[n][k]*W1a[k][c] )
__global__ void __launch_bounds__(256)
k_gsrc16(const float* __restrict__ h, const float* __restrict__ mw1,
         __half* __restrict__ g16, int n_nodes)
{
    __shared__ float sW[32 * 32];
    for (int i = threadIdx.x; i < 32 * 32; i += 256) sW[i] = mw1[i];
    __syncthreads();
    const int lane = threadIdx.x & 63;
    const int c    = lane & 31;
    const int half = lane >> 5;
    int wi = (int)((blockIdx.x * 256 + threadIdx.x) >> 6);
    int nw = gridDim.x * 4;
    for (; 2 * wi < n_nodes; wi += nw) {
        int nr = 2 * wi + half;
        int n  = min(nr, n_nodes - 1);
        float hn = h[(size_t)n * 32 + c];
        float b = 0.0f;
        #pragma unroll
        for (int k = 0; k < 32; k++)
            b = fmaf(__shfl(hn, k, 32), sW[k * 32 + c], b);
        if (nr < n_nodes) g16[(size_t)n * 32 + c] = __float2half(b);
    }
}

// -------- fused round v5b: wave-per-node, fp16-g gather, packed records -----
// per edge: m1[c] = relu(base[dst][c] + g[src][c] + sum_k ef[k]*W1c[k][c])
// records stream sequentially; g16 is the only random access.
// (256,3): 170-VGPR budget -> compiler allocates actual need (~80-100),
// no scratch spill; occupancy set by actual use (~5 waves/SIMD).
__global__ void __launch_bounds__(256, 3)
k_round_wave5(const float* __restrict__ h_in, float* __restrict__ h_out,
        const __half* __restrict__ g16,
        const int* __restrict__ row_start, const int* __restrict__ recs,
        const float* __restrict__ mw1, const float* __restrict__ mb1,
        const float* __restrict__ mw2, const float* __restrict__ mb2,
        const float* __restrict__ uw1, const float* __restrict__ ub1,
        const float* __restrict__ uw2, const float* __restrict__ ub2,
        int n_nodes)
{
    __shared__ float sW1b[32 * 32];   // msg_w1 rows 32..63 (dst half)
    __shared__ float sW2[32 * 32];
    __shared__ float sU1[64 * 32];
    __shared__ float sU2[32 * 32];
    __shared__ float sB[4 * 32];      // mb1 | mb2 | ub1 | ub2
    for (int i = threadIdx.x; i < 32 * 32; i += 256) sW1b[i] = mw1[32 * 32 + i];
    for (int i = threadIdx.x; i < 32 * 32; i += 256) sW2[i]  = mw2[i];
    for (int i = threadIdx.x; i < 64 * 32; i += 256) sU1[i]  = uw1[i];
    for (int i = threadIdx.x; i < 32 * 32; i += 256) sU2[i]  = uw2[i];
    if (threadIdx.x < 32) {
        sB[threadIdx.x]      = mb1[threadIdx.x];
        sB[32 + threadIdx.x] = mb2[threadIdx.x];
        sB[64 + threadIdx.x] = ub1[threadIdx.x];
        sB[96 + threadIdx.x] = ub2[threadIdx.x];
    }
    __syncthreads();

    const int lane = threadIdx.x & 63;
    const int c    = lane & 31;
    const int half = lane >> 5;

    // per-lane private ef column of msg W1 (k=0..3)
    float w1c[4];
    #pragma unroll
    for (int k = 0; k < 4; k++) w1c[k] = mw1[(64 + k) * 32 + c];

    int wave   = (int)((blockIdx.x * 256 + threadIdx.x) >> 6);
    int nwaves = gridDim.x * 4;

    for (int n = wave; n < n_nodes; n += nwaves) {
        float hn = h_in[(size_t)n * 32 + c];

        // base = mb1 + h[n] @ W1b (dst-half hoisted out of the edge loop)
        float base = sB[c];
        #pragma unroll
        for (int k = 0; k < 32; k++)
            base = fmaf(__shfl(hn, k, 32), sW1b[k * 32 + c], base);

        int s0 = row_start[n];
        int s1 = row_start[n + 1];
        float rsum = 0.0f;

        int s = s0 + half;   // this half's slots: s, s+2, s+4, ...
        // main loop: 4 edges per half in flight
        for (; s + 6 < s1; s += 8) {
            int b0 = 3 * s;
            int b1 = 3 * (s + 2);
            int b2 = 3 * (s + 4);
            int b3 = 3 * (s + 6);
            int i0 = recs[b0];
            int i1 = recs[b1];
            int i2 = recs[b2];
            int i3 = recs[b3];
            uint32_t u01_0 = (uint32_t)recs[b0 + 1], u23_0 = (uint32_t)recs[b0 + 2];
            uint32_t u01_1 = (uint32_t)recs[b1 + 1], u23_1 = (uint32_t)recs[b1 + 2];
            uint32_t u01_2 = (uint32_t)recs[b2 + 1], u23_2 = (uint32_t)recs[b2 + 2];
            uint32_t u01_3 = (uint32_t)recs[b3 + 1], u23_3 = (uint32_t)recs[b3 + 2];
            float x0 = __half2float(g16[(size_t)i0 * 32 + c]);
            float x1 = __half2float(g16[(size_t)i1 * 32 + c]);
            float x2 = __half2float(g16[(size_t)i2 * 32 + c]);
            float x3 = __half2float(g16[(size_t)i3 * 32 + c]);

            float2 eA0 = __half22float2(*reinterpret_cast<const __half2*>(&u01_0));
            float2 eB0 = __half22float2(*reinterpret_cast<const __half2*>(&u23_0));
            float2 eA1 = __half22float2(*reinterpret_cast<const __half2*>(&u01_1));
            float2 eB1 = __half22float2(*reinterpret_cast<const __half2*>(&u23_1));
            float2 eA2 = __half22float2(*reinterpret_cast<const __half2*>(&u01_2));
            float2 eB2 = __half22float2(*reinterpret_cast<const __half2*>(&u23_2));
            float2 eA3 = __half22float2(*reinterpret_cast<const __half2*>(&u01_3));
            float2 eB3 = __half22float2(*reinterpret_cast<const __half2*>(&u23_3));

            float a0 = base + x0;
            float a1 = base + x1;
            float a2 = base + x2;
            float a3 = base + x3;
            a0 = fmaf(eA0.x, w1c[0], a0); a0 = fmaf(eA0.y, w1c[1], a0);
            a0 = fmaf(eB0.x, w1c[2], a0); a0 = fmaf(eB0.y, w1c[3], a0);
            a1 = fmaf(eA1.x, w1c[0], a1); a1 = fmaf(eA1.y, w1c[1], a1);
            a1 = fmaf(eB1.x, w1c[2], a1); a1 = fmaf(eB1.y, w1c[3], a1);
            a2 = fmaf(eA2.x, w1c[0], a2); a2 = fmaf(eA2.y, w1c[1], a2);
            a2 = fmaf(eB2.x, w1c[2], a2); a2 = fmaf(eB2.y, w1c[3], a2);
            a3 = fmaf(eA3.x, w1c[0], a3); a3 = fmaf(eA3.y, w1c[1], a3);
            a3 = fmaf(eB3.x, w1c[2], a3); a3 = fmaf(eB3.y, w1c[3], a3);

            rsum += fmaxf(a0, 0.0f);
            rsum += fmaxf(a1, 0.0f);
            rsum += fmaxf(a2, 0.0f);
            rsum += fmaxf(a3, 0.0f);
        }
        // tail: one edge at a time
        for (; s < s1; s += 2) {
            int b = 3 * s;
            int i0 = recs[b];
            uint32_t u01 = (uint32_t)recs[b + 1], u23 = (uint32_t)recs[b + 2];
            float x = __half2float(g16[(size_t)i0 * 32 + c]);
            float2 eA = __half22float2(*reinterpret_cast<const __half2*>(&u01));
            float2 eB = __half22float2(*reinterpret_cast<const __half2*>(&u23));
            float a = base + x;
            a = fmaf(eA.x, w1c[0], a); a = fmaf(eA.y, w1c[1], a);
            a = fmaf(eB.x, w1c[2], a); a = fmaf(eB.y, w1c[3], a);
            rsum += fmaxf(a, 0.0f);
        }
        // combine halves (both halves converged here)
        rsum += __shfl_xor(rsum, 32, 64);

        // agg = deg*mb2 + rsum @ W2 (W2 hoisted by linearity)
        float deg = (float)(s1 - s0);
        float agg = deg * sB[32 + c];
        #pragma unroll
        for (int k = 0; k < 32; k++)
            agg = fmaf(__shfl(rsum, k, 32), sW2[k * 32 + c], agg);

        // update MLP
        float a2v = sB[64 + c];
        #pragma unroll
        for (int k = 0; k < 32; k++)
            a2v = fmaf(__shfl(hn, k, 32), sU1[k * 32 + c], a2v);
        #pragma unroll
        for (int k = 0; k < 32; k++)
            a2v = fmaf(__shfl(agg, k, 32), sU1[(32 + k) * 32 + c], a2v);
        float t = fmaxf(a2v, 0.0f);
        float o = sB[96 + c];
        #pragma unroll
        for (int k = 0; k < 32; k++)
            o = fmaf(__shfl(t, k, 32), sU2[k * 32 + c], o);

        if (lane < 32) h_out[(size_t)n * 32 + c] = hn + o;
    }
}

// -------- R14 fallback kernels (atomic path), used only if ws too small -----

__global__ void __launch_bounds__(256)
k_message(const float* __restrict__ h, const int2* __restrict__ edges,
          const float4* __restrict__ ef,
          const float* __restrict__ w1g, const float* __restrict__ b1g,
          const float* __restrict__ w2g, const float* __restrict__ b2g,
          float* __restrict__ agg, int n_edges)
{
    __shared__ float sw1[68 * 32];
    __shared__ float sw2[32 * 32];
    __shared__ float sb1[32];
    __shared__ float sb2[32];
    for (int i = threadIdx.x; i < 68 * 32; i += 256) sw1[i] = w1g[i];
    for (int i = threadIdx.x; i < 32 * 32; i += 256) sw2[i] = w2g[i];
    if (threadIdx.x < 32) {
        sb1[threadIdx.x] = b1g[threadIdx.x];
        sb2[threadIdx.x] = b2g[threadIdx.x];
    }
    __syncthreads();
    int e = blockIdx.x * 256 + threadIdx.x;
    if (e >= n_edges) return;

    int2 ed = edges[e];
    const float4* hs = (const float4*)(h + (size_t)ed.x * 32);
    const float4* hd = (const float4*)(h + (size_t)ed.y * 32);

    float acc[32];
    #pragma unroll
    for (int j = 0; j < 32; j++) acc[j] = sb1[j];
    #pragma unroll 2
    for (int cc = 0; cc < 8; cc++) {
        float4 xv = hs[cc];
        float xsv[4] = {xv.x, xv.y, xv.z, xv.w};
        #pragma unroll
        for (int kk = 0; kk < 4; kk++) {
            float xk = xsv[kk];
            const float* wr = &sw1[(cc * 4 + kk) * 32];
            #pragma unroll
            for (int j = 0; j < 32; j++) acc[j] = fmaf(xk, wr[j], acc[j]);
        }
    }
    #pragma unroll 2
    for (int cc = 0; cc < 8; cc++) {
        float4 xv = hd[cc];
        float xsv[4] = {xv.x, xv.y, xv.z, xv.w};
        #pragma unroll
        for (int kk = 0; kk < 4; kk++) {
            float xk = xsv[kk];
            const float* wr = &sw1[(32 + cc * 4 + kk) * 32];
            #pragma unroll
            for (int j = 0; j < 32; j++) acc[j] = fmaf(xk, wr[j], acc[j]);
        }
    }
    {
        float4 evv = ef[e];
        float ex[4] = {evv.x, evv.y, evv.z, evv.w};
        #pragma unroll
        for (int kk = 0; kk < 4; kk++) {
            float xk = ex[kk];
            const float* wr = &sw1[(64 + kk) * 32];
            #pragma unroll
            for (int j = 0; j < 32; j++) acc[j] = fmaf(xk, wr[j], acc[j]);
        }
    }
    #pragma unroll
    for (int j = 0; j < 32; j++) acc[j] = fmaxf(acc[j], 0.0f);

    float o[32];
    #pragma unroll
    for (int j = 0; j < 32; j++) o[j] = sb2[j];
    #pragma unroll 4
    for (int k = 0; k < 32; k++) {
        float hk = acc[k];
        const float* wr = &sw2[k * 32];
        #pragma unroll
        for (int j = 0; j < 32; j++) o[j] = fmaf(hk, wr[j], o[j]);
    }
    float* ap = agg + (size_t)ed.y * 32;
    #pragma unroll
    for (int j = 0; j < 32; j++) atomicAdd(ap + j, o[j]);
}

__global__ void __launch_bounds__(256)
k_update(float* h, const float* __restrict__ agg,
         const float* __restrict__ w1g, const float* __restrict__ b1g,
         const float* __restrict__ w2g, const float* __restrict__ b2g,
         int n_nodes)
{
    __shared__ float sw1[64 * 32];
    __shared__ float sw2[32 * 32];
    __shared__ float sb1[32];
    __shared__ float sb2[32];
    for (int i = threadIdx.x; i < 64 * 32; i += 256) sw1[i] = w1g[i];
    for (int i = threadIdx.x; i < 32 * 32; i += 256) sw2[i] = w2g[i];
    if (threadIdx.x < 32) {
        sb1[threadIdx.x] = b1g[threadIdx.x];
        sb2[threadIdx.x] = b2g[threadIdx.x];
    }
    __syncthreads();
    int n = blockIdx.x * 256 + threadIdx.x;
    if (n >= n_nodes) return;

    const float4* hp = (const float4*)(h + (size_t)n * 32);
    const float4* ap = (const float4*)(agg + (size_t)n * 32);

    float hv[32];
    float acc[32];
    #pragma unroll
    for (int j = 0; j < 32; j++) acc[j] = sb1[j];
    #pragma unroll 2
    for (int cc = 0; cc < 8; cc++) {
        float4 xv = hp[cc];
        hv[4 * cc] = xv.x; hv[4 * cc + 1] = xv.y; hv[4 * cc + 2] = xv.z; hv[4 * cc + 3] = xv.w;
        float xsv[4] = {xv.x, xv.y, xv.z, xv.w};
        #pragma unroll
        for (int kk = 0; kk < 4; kk++) {
            float xk = xsv[kk];
            const float* wr = &sw1[(cc * 4 + kk) * 32];
            #pragma unroll
            for (int j = 0; j < 32; j++) acc[j] = fmaf(xk, wr[j], acc[j]);
        }
    }
    #pragma unroll 2
    for (int cc = 0; cc < 8; cc++) {
        float4 xv = ap[cc];
        float xsv[4] = {xv.x, xv.y, xv.z, xv.w};
        #pragma unroll
        for (int kk = 0; kk < 4; kk++) {
            float xk = xsv[kk];
            const float* wr = &sw1[(32 + cc * 4 + kk) * 32];
            #pragma unroll
            for (int j = 0; j < 32; j++) acc[j] = fmaf(xk, wr[j], acc[j]);
        }
    }
    #pragma unroll
    for (int j = 0; j < 32; j++) acc[j] = fmaxf(acc[j], 0.0f);

    float o[32];
    #pragma unroll
    for (int j = 0; j < 32; j++) o[j] = sb2[j];
    #pragma unroll 4
    for (int k = 0; k < 32; k++) {
        float hk = acc[k];
        const float* wr = &sw2[k * 32];
        #pragma unroll
        for (int j = 0; j < 32; j++) o[j] = fmaf(hk, wr[j], o[j]);
    }
    float4* op = (float4*)(h + (size_t)n * 32);
    #pragma unroll
    for (int cc = 0; cc < 8; cc++)
        op[cc] = make_float4(hv[4 * cc] + o[4 * cc], hv[4 * cc + 1] + o[4 * cc + 1],
                             hv[4 * cc + 2] + o[4 * cc + 2], hv[4 * cc + 3] + o[4 * cc + 3]);
}

// head: out = (relu(h @ w1 + b1) @ w2 + b2)[:, 0]   (fp32 out)
__global__ void AtomGNN_56169582297457_kernel(const float* h, const float* w1g, const float* b1g, const float* w2g, const float* b2g, float* out, int n_nodes) {
    __shared__ float sw1[32 * 32];
    __shared__ float sb1[32];
    __shared__ float sw2[32];
    __shared__ float sb2;
    for (int i = threadIdx.x; i < 32 * 32; i += 256) sw1[i] = w1g[i];
    if (threadIdx.x < 32) {
        sb1[threadIdx.x] = b1g[threadIdx.x];
        sw2[threadIdx.x] = w2g[threadIdx.x];
    }
    if (threadIdx.x == 0) sb2 = b2g[0];
    __syncthreads();
    int n = blockIdx.x * 256 + threadIdx.x;
    if (n >= n_nodes) return;

    const float4* hp = (const float4*)(h + (size_t)n * 32);
    float x[32];
    #pragma unroll
    for (int cc = 0; cc < 8; cc++) {
        float4 xv = hp[cc];
        x[4 * cc] = xv.x; x[4 * cc + 1] = xv.y; x[4 * cc + 2] = xv.z; x[4 * cc + 3] = xv.w;
    }
    float acc[32];
    #pragma unroll
    for (int j = 0; j < 32; j++) acc[j] = sb1[j];
    #pragma unroll 4
    for (int k = 0; k < 32; k++) {
        float xk = x[k];
        const float* wr = &sw1[k * 32];
        #pragma unroll
        for (int j = 0; j < 32; j++) acc[j] = fmaf(xk, wr[j], acc[j]);
    }
    float val = sb2;
    #pragma unroll
    for (int k = 0; k < 32; k++) val = fmaf(fmaxf(acc[k], 0.0f), sw2[k], val);
    out[n] = val;
}

extern "C" void kernel_launch(void* const* d_in, const int* in_sizes, int n_in,
                              void* d_out, int out_size, void* d_ws, size_t ws_size,
                              hipStream_t stream) {
    const float* nf      = (const float*)d_in[0];
    const int2*  edges   = (const int2*)d_in[1];
    const float4* ef     = (const float4*)d_in[2];
    const float* enc_w1  = (const float*)d_in[3];
    const float* enc_b1  = (const float*)d_in[4];
    const float* enc_w2  = (const float*)d_in[5];
    const float* enc_b2  = (const float*)d_in[6];
    const float* msg_w1  = (const float*)d_in[7];
    const float* msg_b1  = (const float*)d_in[8];
    const float* msg_w2  = (const float*)d_in[9];
    const float* msg_b2  = (const float*)d_in[10];
    const float* upd_w1  = (const float*)d_in[11];
    const float* upd_b1  = (const float*)d_in[12];
    const float* upd_w2  = (const float*)d_in[13];
    const float* upd_b2  = (const float*)d_in[14];
    const float* head_w1 = (const float*)d_in[15];
    const float* head_b1 = (const float*)d_in[16];
    const float* head_w2 = (const float*)d_in[17];
    const float* head_b2 = (const float*)d_in[18];

    int n_nodes = (out_size > 0) ? out_size : NN_REF;
    int n_edges = (in_sizes && n_in > 2 && in_sizes[2] > 0) ? in_sizes[2] / 4 : NE_REF;

    int nb_nodes = (n_nodes + 255) / 256;
    int nb_edges = (n_edges + 255) / 256;

    // Workspace layout (~71.2MB total, below proven-fitting 77.6MB):
    //   h0 | h1 | g16(half) | row_start[n+1] | cursor[n] | bsum[nb]
    //   | recs[3*E] int (packed: src, half2 ef01, half2 ef23)
    float* h0 = (float*)d_ws;
    float* h1 = h0 + (size_t)n_nodes * 32;
    __half* g16 = (__half*)(h1 + (size_t)n_nodes * 32);
    int* row_start = (int*)(g16 + (size_t)n_nodes * 32);
    int* cursor = row_start + (n_nodes + 1);
    int* bsum = cursor + n_nodes;
    int* recs = bsum + nb_nodes;
    size_t required = ((uintptr_t)(recs + (size_t)3 * n_edges) - (uintptr_t)d_ws);

    bool csr_ok = (nb_nodes <= 1024) &&
                  (ws_size == 0 || ws_size >= required);

    if (csr_ok) {
        k_encode<<<nb_nodes, 256, 0, stream>>>(nf, enc_w1, enc_b1, enc_w2, enc_b2, h0, n_nodes);

        // build dst-CSR once (edges identical across rounds)
        k_zero<<<256, 256, 0, stream>>>((float*)cursor, n_nodes);
        k_hist<<<nb_edges, 256, 0, stream>>>(edges, cursor, n_edges);
        k_scan_block<<<nb_nodes, 256, 0, stream>>>(cursor, row_start, bsum, n_nodes);
        k_scan_bsum<<<1, 1024, 0, stream>>>(bsum, nb_nodes, row_start, n_nodes, n_edges);
        k_scan_add<<<nb_nodes, 256, 0, stream>>>(row_start, cursor, bsum, n_nodes);
        k_fill3<<<nb_edges, 256, 0, stream>>>(edges, ef, cursor, recs, n_edges);

        // ping-pong rounds: h0 -> h1 -> h0
        for (int r = 0; r < 2; r++) {
            const float* hin = (r == 0) ? h0 : h1;
            float* hout      = (r == 0) ? h1 : h0;
            const float* mw1 = msg_w1 + (size_t)r * 68 * 32;
            k_gsrc16<<<1024, 256, 0, stream>>>(hin, mw1, g16, n_nodes);
            k_round_wave5<<<2048, 256, 0, stream>>>(
                hin, hout, g16, row_start, recs,
                mw1, msg_b1 + (size_t)r * 32,
                msg_w2 + (size_t)r * 32 * 32, msg_b2 + (size_t)r * 32,
                upd_w1 + (size_t)r * 64 * 32, upd_b1 + (size_t)r * 32,
                upd_w2 + (size_t)r * 32 * 32, upd_b2 + (size_t)r * 32,
                n_nodes);
        }

        AtomGNN_56169582297457_kernel<<<nb_nodes, 256, 0, stream>>>(
            h0, head_w1, head_b1, head_w2, head_b2, (float*)d_out, n_nodes);
    } else {
        // R14 fallback: atomic scatter path
        float* h   = (float*)d_ws;
        float* agg = h + (size_t)n_nodes * 32;

        k_encode<<<nb_nodes, 256, 0, stream>>>(nf, enc_w1, enc_b1, enc_w2, enc_b2, h, n_nodes);
        for (int r = 0; r < 2; r++) {
            k_zero<<<1024, 256, 0, stream>>>(agg, n_nodes * 32);
            k_message<<<nb_edges, 256, 0, stream>>>(
                h, edges, ef,
                msg_w1 + (size_t)r * 68 * 32, msg_b1 + (size_t)r * 32,
                msg_w2 + (size_t)r * 32 * 32, msg_b2 + (size_t)r * 32,
                agg, n_edges);
            k_update<<<nb_nodes, 256, 0, stream>>>(
                h, agg,
                upd_w1 + (size_t)r * 64 * 32, upd_b1 + (size_t)r * 32,
                upd_w2 + (size_t)r * 32 * 32, upd_b2 + (size_t)r * 32,
                n_nodes);
        }
        AtomGNN_56169582297457_kernel<<<nb_nodes, 256, 0, stream>>>(
            h, head_w1, head_b1, head_w2, head_b2, (float*)d_out, n_nodes);
    }
}

// Round 9
// 1194.378 us; speedup vs baseline: 2.7097x; 1.3003x over previous
//
#include <hip/hip_runtime.h>
#include <hip/hip_fp16.h>
#include <cstdio>
#include <cstdint>

// R23: finish killing the spill. R22 ((256,3)) halved it (WRITE 296->218MB,
// FETCH 1.51->0.98GB, 650->547us) but the allocator still spilled the ILP-4
// in-flight load cluster: excess WRITE = exactly 64B/edge. The only proven
// zero-spill config this session is R16's plain __launch_bounds__(256)
// (compiler chose 140 VGPR, WRITE == h_out exactly). Single change vs R22:
// drop the min-occupancy hint. 3-4 waves/SIMD x 8 edges in flight = 24-32
// outstanding lines/SIMD, ample for a traffic-bound kernel. Decisive signal:
// WRITE ~13MB. Next lever if still traffic-bound at ~0.55GB FETCH: column-
// split g16 into 2x3.2MB tables (<=4MB XCD L2) for an L2-resident gather.

__attribute__((constructor)) static void atomgnn_r23_load_beacon() {
    fprintf(stderr, "ATOMGNN_R23_SOURCE_LOADED\n");
    fflush(stderr);
}

#define NN_REF 100000
#define NE_REF 3200000

// zero a float/int buffer (4B words), grid-stride
__global__ void __launch_bounds__(256)
k_zero(float* __restrict__ p, int n)
{
    int i = blockIdx.x * 256 + threadIdx.x;
    int stride = gridDim.x * 256;
    for (; i < n; i += stride) p[i] = 0.0f;
}

// encoder: h = relu(nf @ w1 + b1) @ w2 + b2   (16 -> 32 -> 32)
__global__ void __launch_bounds__(256)
k_encode(const float* __restrict__ nf,
         const float* __restrict__ w1g, const float* __restrict__ b1g,
         const float* __restrict__ w2g, const float* __restrict__ b2g,
         float* __restrict__ h, int n_nodes)
{
    __shared__ float sw1[16 * 32];
    __shared__ float sw2[32 * 32];
    __shared__ float sb1[32];
    __shared__ float sb2[32];
    for (int i = threadIdx.x; i < 16 * 32; i += 256) sw1[i] = w1g[i];
    for (int i = threadIdx.x; i < 32 * 32; i += 256) sw2[i] = w2g[i];
    if (threadIdx.x < 32) {
        sb1[threadIdx.x] = b1g[threadIdx.x];
        sb2[threadIdx.x] = b2g[threadIdx.x];
    }
    __syncthreads();
    int n = blockIdx.x * 256 + threadIdx.x;
    if (n >= n_nodes) return;

    const float4* p = (const float4*)(nf + (size_t)n * 16);
    float x[16];
    #pragma unroll
    for (int c = 0; c < 4; c++) {
        float4 v = p[c];
        x[4 * c] = v.x; x[4 * c + 1] = v.y; x[4 * c + 2] = v.z; x[4 * c + 3] = v.w;
    }

    float acc[32];
    #pragma unroll
    for (int j = 0; j < 32; j++) acc[j] = sb1[j];
    #pragma unroll 4
    for (int k = 0; k < 16; k++) {
        float xk = x[k];
        const float* wr = &sw1[k * 32];
        #pragma unroll
        for (int j = 0; j < 32; j++) acc[j] = fmaf(xk, wr[j], acc[j]);
    }
    #pragma unroll
    for (int j = 0; j < 32; j++) acc[j] = fmaxf(acc[j], 0.0f);

    float o[32];
    #pragma unroll
    for (int j = 0; j < 32; j++) o[j] = sb2[j];
    #pragma unroll 4
    for (int k = 0; k < 32; k++) {
        float hk = acc[k];
        const float* wr = &sw2[k * 32];
        #pragma unroll
        for (int j = 0; j < 32; j++) o[j] = fmaf(hk, wr[j], o[j]);
    }
    float4* hp = (float4*)(h + (size_t)n * 32);
    #pragma unroll
    for (int c = 0; c < 8; c++)
        hp[c] = make_float4(o[4 * c], o[4 * c + 1], o[4 * c + 2], o[4 * c + 3]);
}

// -------- CSR build: histogram -> exclusive scan -> fill --------

__global__ void __launch_bounds__(256)
k_hist(const int2* __restrict__ edges, int* __restrict__ cnt, int n_edges)
{
    int e = blockIdx.x * 256 + threadIdx.x;
    if (e >= n_edges) return;
    atomicAdd(&cnt[edges[e].y], 1);
}

__global__ void __launch_bounds__(256)
k_scan_block(const int* __restrict__ cnt, int* __restrict__ rs,
             int* __restrict__ bsum, int n)
{
    __shared__ int sd[256];
    int t = threadIdx.x;
    int i = blockIdx.x * 256 + t;
    int v = (i < n) ? cnt[i] : 0;
    sd[t] = v;
    __syncthreads();
    int val = v;
    for (int off = 1; off < 256; off <<= 1) {
        int add = (t >= off) ? sd[t - off] : 0;
        __syncthreads();
        val += add;
        sd[t] = val;
        __syncthreads();
    }
    if (i < n) rs[i] = val - v;           // exclusive within block
    if (t == 255) bsum[blockIdx.x] = val; // block total
}

__global__ void __launch_bounds__(1024)
k_scan_bsum(int* __restrict__ bsum, int nb, int* __restrict__ rs,
            int n_nodes, int n_edges)
{
    __shared__ int sd[1024];
    int t = threadIdx.x;
    int v = (t < nb) ? bsum[t] : 0;
    sd[t] = v;
    __syncthreads();
    int val = v;
    for (int off = 1; off < 1024; off <<= 1) {
        int add = (t >= off) ? sd[t - off] : 0;
        __syncthreads();
        val += add;
        sd[t] = val;
        __syncthreads();
    }
    if (t < nb) bsum[t] = val - v;  // exclusive prefix of block totals
    if (t == 0) rs[n_nodes] = n_edges;
}

__global__ void __launch_bounds__(256)
k_scan_add(int* __restrict__ rs, int* __restrict__ cursor,
           const int* __restrict__ bsum, int n)
{
    int i = blockIdx.x * 256 + threadIdx.x;
    if (i < n) {
        int v = rs[i] + bsum[blockIdx.x];
        rs[i] = v;
        cursor[i] = v;
    }
}

// scatter edges into dst-sorted packed slot records:
//   recs[3*pos] = src, recs[3*pos+1] = half2(ef.x,ef.y),
//   recs[3*pos+2] = half2(ef.z,ef.w)
__global__ void __launch_bounds__(256)
k_fill3(const int2* __restrict__ edges, const float4* __restrict__ ef,
        int* __restrict__ cursor, int* __restrict__ recs, int n_edges)
{
    int e = blockIdx.x * 256 + threadIdx.x;
    if (e >= n_edges) return;
    int2 ed = edges[e];
    float4 v = ef[e];
    int pos = atomicAdd(&cursor[ed.y], 1);
    __half2 h01 = __floats2half2_rn(v.x, v.y);
    __half2 h23 = __floats2half2_rn(v.z, v.w);
    recs[3 * pos]     = ed.x;
    recs[3 * pos + 1] = *reinterpret_cast<int*>(&h01);
    recs[3 * pos + 2] = *reinterpret_cast<int*>(&h23);
}

// -------- per-round precompute: g16[n][c] = fp16( sum_k h[n][k]*W1a[k][c] )
__global__ void __launch_bounds__(256)
k_gsrc16(const float* __restrict__ h, const float* __restrict__ mw1,
         __half* __restrict__ g16, int n_nodes)
{
    __shared__ float sW[32 * 32];
    for (int i = threadIdx.x; i < 32 * 32; i += 256) sW[i] = mw1[i];
    __syncthreads();
    const int lane = threadIdx.x & 63;
    const int c    = lane & 31;
    const int half = lane >> 5;
    int wi = (int)((blockIdx.x * 256 + threadIdx.x) >> 6);
    int nw = gridDim.x * 4;
    for (; 2 * wi < n_nodes; wi += nw) {
        int nr = 2 * wi + half;
        int n  = min(nr, n_nodes - 1);
        float hn = h[(size_t)n * 32 + c];
        float b = 0.0f;
        #pragma unroll
        for (int k = 0; k < 32; k++)
            b = fmaf(__shfl(hn, k, 32), sW[k * 32 + c], b);
        if (nr < n_nodes) g16[(size_t)n * 32 + c] = __float2half(b);
    }
}

// -------- fused round v5c: wave-per-node, fp16-g gather, packed records -----
// per edge: m1[c] = relu(base[dst][c] + g[src][c] + sum_k ef[k]*W1c[k][c])
// records stream sequentially; g16 is the only random access.
// Plain __launch_bounds__(256): unbounded allocator = proven zero-spill
// (R16: WRITE == h_out exactly). (256,4)/(256,3) both spilled the ILP-4
// load cluster (64B/edge of scratch writes).
__global__ void __launch_bounds__(256)
k_round_wave5(const float* __restrict__ h_in, float* __restrict__ h_out,
        const __half* __restrict__ g16,
        const int* __restrict__ row_start, const int* __restrict__ recs,
        const float* __restrict__ mw1, const float* __restrict__ mb1,
        const float* __restrict__ mw2, const float* __restrict__ mb2,
        const float* __restrict__ uw1, const float* __restrict__ ub1,
        const float* __restrict__ uw2, const float* __restrict__ ub2,
        int n_nodes)
{
    __shared__ float sW1b[32 * 32];   // msg_w1 rows 32..63 (dst half)
    __shared__ float sW2[32 * 32];
    __shared__ float sU1[64 * 32];
    __shared__ float sU2[32 * 32];
    __shared__ float sB[4 * 32];      // mb1 | mb2 | ub1 | ub2
    for (int i = threadIdx.x; i < 32 * 32; i += 256) sW1b[i] = mw1[32 * 32 + i];
    for (int i = threadIdx.x; i < 32 * 32; i += 256) sW2[i]  = mw2[i];
    for (int i = threadIdx.x; i < 64 * 32; i += 256) sU1[i]  = uw1[i];
    for (int i = threadIdx.x; i < 32 * 32; i += 256) sU2[i]  = uw2[i];
    if (threadIdx.x < 32) {
        sB[threadIdx.x]      = mb1[threadIdx.x];
        sB[32 + threadIdx.x] = mb2[threadIdx.x];
        sB[64 + threadIdx.x] = ub1[threadIdx.x];
        sB[96 + threadIdx.x] = ub2[threadIdx.x];
    }
    __syncthreads();

    const int lane = threadIdx.x & 63;
    const int c    = lane & 31;
    const int half = lane >> 5;

    // per-lane private ef column of msg W1 (k=0..3)
    float w1c[4];
    #pragma unroll
    for (int k = 0; k < 4; k++) w1c[k] = mw1[(64 + k) * 32 + c];

    int wave   = (int)((blockIdx.x * 256 + threadIdx.x) >> 6);
    int nwaves = gridDim.x * 4;

    for (int n = wave; n < n_nodes; n += nwaves) {
        float hn = h_in[(size_t)n * 32 + c];

        // base = mb1 + h[n] @ W1b (dst-half hoisted out of the edge loop)
        float base = sB[c];
        #pragma unroll
        for (int k = 0; k < 32; k++)
            base = fmaf(__shfl(hn, k, 32), sW1b[k * 32 + c], base);

        int s0 = row_start[n];
        int s1 = row_start[n + 1];
        float rsum = 0.0f;

        int s = s0 + half;   // this half's slots: s, s+2, s+4, ...
        // main loop: 4 edges per half in flight
        for (; s + 6 < s1; s += 8) {
            int b0 = 3 * s;
            int b1 = 3 * (s + 2);
            int b2 = 3 * (s + 4);
            int b3 = 3 * (s + 6);
            int i0 = recs[b0];
            int i1 = recs[b1];
            int i2 = recs[b2];
            int i3 = recs[b3];
            uint32_t u01_0 = (uint32_t)recs[b0 + 1], u23_0 = (uint32_t)recs[b0 + 2];
            uint32_t u01_1 = (uint32_t)recs[b1 + 1], u23_1 = (uint32_t)recs[b1 + 2];
            uint32_t u01_2 = (uint32_t)recs[b2 + 1], u23_2 = (uint32_t)recs[b2 + 2];
            uint32_t u01_3 = (uint32_t)recs[b3 + 1], u23_3 = (uint32_t)recs[b3 + 2];
            float x0 = __half2float(g16[(size_t)i0 * 32 + c]);
            float x1 = __half2float(g16[(size_t)i1 * 32 + c]);
            float x2 = __half2float(g16[(size_t)i2 * 32 + c]);
            float x3 = __half2float(g16[(size_t)i3 * 32 + c]);

            float2 eA0 = __half22float2(*reinterpret_cast<const __half2*>(&u01_0));
            float2 eB0 = __half22float2(*reinterpret_cast<const __half2*>(&u23_0));
            float2 eA1 = __half22float2(*reinterpret_cast<const __half2*>(&u01_1));
            float2 eB1 = __half22float2(*reinterpret_cast<const __half2*>(&u23_1));
            float2 eA2 = __half22float2(*reinterpret_cast<const __half2*>(&u01_2));
            float2 eB2 = __half22float2(*reinterpret_cast<const __half2*>(&u23_2));
            float2 eA3 = __half22float2(*reinterpret_cast<const __half2*>(&u01_3));
            float2 eB3 = __half22float2(*reinterpret_cast<const __half2*>(&u23_3));

            float a0 = base + x0;
            float a1 = base + x1;
            float a2 = base + x2;
            float a3 = base + x3;
            a0 = fmaf(eA0.x, w1c[0], a0); a0 = fmaf(eA0.y, w1c[1], a0);
            a0 = fmaf(eB0.x, w1c[2], a0); a0 = fmaf(eB0.y, w1c[3], a0);
            a1 = fmaf(eA1.x, w1c[0], a1); a1 = fmaf(eA1.y, w1c[1], a1);
            a1 = fmaf(eB1.x, w1c[2], a1); a1 = fmaf(eB1.y, w1c[3], a1);
            a2 = fmaf(eA2.x, w1c[0], a2); a2 = fmaf(eA2.y, w1c[1], a2);
            a2 = fmaf(eB2.x, w1c[2], a2); a2 = fmaf(eB2.y, w1c[3], a2);
            a3 = fmaf(eA3.x, w1c[0], a3); a3 = fmaf(eA3.y, w1c[1], a3);
            a3 = fmaf(eB3.x, w1c[2], a3); a3 = fmaf(eB3.y, w1c[3], a3);

            rsum += fmaxf(a0, 0.0f);
            rsum += fmaxf(a1, 0.0f);
            rsum += fmaxf(a2, 0.0f);
            rsum += fmaxf(a3, 0.0f);
        }
        // tail: one edge at a time
        for (; s < s1; s += 2) {
            int b = 3 * s;
            int i0 = recs[b];
            uint32_t u01 = (uint32_t)recs[b + 1], u23 = (uint32_t)recs[b + 2];
            float x = __half2float(g16[(size_t)i0 * 32 + c]);
            float2 eA = __half22float2(*reinterpret_cast<const __half2*>(&u01));
            float2 eB = __half22float2(*reinterpret_cast<const __half2*>(&u23));
            float a = base + x;
            a = fmaf(eA.x, w1c[0], a); a = fmaf(eA.y, w1c[1], a);
            a = fmaf(eB.x, w1c[2], a); a = fmaf(eB.y, w1c[3], a);
            rsum += fmaxf(a, 0.0f);
        }
        // combine halves (both halves converged here)
        rsum += __shfl_xor(rsum, 32, 64);

        // agg = deg*mb2 + rsum @ W2 (W2 hoisted by linearity)
        float deg = (float)(s1 - s0);
        float agg = deg * sB[32 + c];
        #pragma unroll
        for (int k = 0; k < 32; k++)
            agg = fmaf(__shfl(rsum, k, 32), sW2[k * 32 + c], agg);

        // update MLP
        float a2v = sB[64 + c];
        #pragma unroll
        for (int k = 0; k < 32; k++)
            a2v = fmaf(__shfl(hn, k, 32), sU1[k * 32 + c], a2v);
        #pragma unroll
        for (int k = 0; k < 32; k++)
            a2v = fmaf(__shfl(agg, k, 32), sU1[(32 + k) * 32 + c], a2v);
        float t = fmaxf(a2v, 0.0f);
        float o = sB[96 + c];
        #pragma unroll
        for (int k = 0; k < 32; k++)
            o = fmaf(__shfl(t, k, 32), sU2[k * 32 + c], o);

        if (lane < 32) h_out[(size_t)n * 32 + c] = hn + o;
    }
}

// -------- R14 fallback kernels (atomic path), used only if ws too small -----

__global__ void __launch_bounds__(256)
k_message(const float* __restrict__ h, const int2* __restrict__ edges,
          const float4* __restrict__ ef,
          const float* __restrict__ w1g, const float* __restrict__ b1g,
          const float* __restrict__ w2g, const float* __restrict__ b2g,
          float* __restrict__ agg, int n_edges)
{
    __shared__ float sw1[68 * 32];
    __shared__ float sw2[32 * 32];
    __shared__ float sb1[32];
    __shared__ float sb2[32];
    for (int i = threadIdx.x; i < 68 * 32; i += 256) sw1[i] = w1g[i];
    for (int i = threadIdx.x; i < 32 * 32; i += 256) sw2[i] = w2g[i];
    if (threadIdx.x < 32) {
        sb1[threadIdx.x] = b1g[threadIdx.x];
        sb2[threadIdx.x] = b2g[threadIdx.x];
    }
    __syncthreads();
    int e = blockIdx.x * 256 + threadIdx.x;
    if (e >= n_edges) return;

    int2 ed = edges[e];
    const float4* hs = (const float4*)(h + (size_t)ed.x * 32);
    const float4* hd = (const float4*)(h + (size_t)ed.y * 32);

    float acc[32];
    #pragma unroll
    for (int j = 0; j < 32; j++) acc[j] = sb1[j];
    #pragma unroll 2
    for (int cc = 0; cc < 8; cc++) {
        float4 xv = hs[cc];
        float xsv[4] = {xv.x, xv.y, xv.z, xv.w};
        #pragma unroll
        for (int kk = 0; kk < 4; kk++) {
            float xk = xsv[kk];
            const float* wr = &sw1[(cc * 4 + kk) * 32];
            #pragma unroll
            for (int j = 0; j < 32; j++) acc[j] = fmaf(xk, wr[j], acc[j]);
        }
    }
    #pragma unroll 2
    for (int cc = 0; cc < 8; cc++) {
        float4 xv = hd[cc];
        float xsv[4] = {xv.x, xv.y, xv.z, xv.w};
        #pragma unroll
        for (int kk = 0; kk < 4; kk++) {
            float xk = xsv[kk];
            const float* wr = &sw1[(32 + cc * 4 + kk) * 32];
            #pragma unroll
            for (int j = 0; j < 32; j++) acc[j] = fmaf(xk, wr[j], acc[j]);
        }
    }
    {
        float4 evv = ef[e];
        float ex[4] = {evv.x, evv.y, evv.z, evv.w};
        #pragma unroll
        for (int kk = 0; kk < 4; kk++) {
            float xk = ex[kk];
            const float* wr = &sw1[(64 + kk) * 32];
            #pragma unroll
            for (int j = 0; j < 32; j++) acc[j] = fmaf(xk, wr[j], acc[j]);
        }
    }
    #pragma unroll
    for (int j = 0; j < 32; j++) acc[j] = fmaxf(acc[j], 0.0f);

    float o[32];
    #pragma unroll
    for (int j = 0; j < 32; j++) o[j] = sb2[j];
    #pragma unroll 4
    for (int k = 0; k < 32; k++) {
        float hk = acc[k];
        const float* wr = &sw2[k * 32];
        #pragma unroll
        for (int j = 0; j < 32; j++) o[j] = fmaf(hk, wr[j], o[j]);
    }
    float* ap = agg + (size_t)ed.y * 32;
    #pragma unroll
    for (int j = 0; j < 32; j++) atomicAdd(ap + j, o[j]);
}

__global__ void __launch_bounds__(256)
k_update(float* h, const float* __restrict__ agg,
         const float* __restrict__ w1g, const float* __restrict__ b1g,
         const float* __restrict__ w2g, const float* __restrict__ b2g,
         int n_nodes)
{
    __shared__ float sw1[64 * 32];
    __shared__ float sw2[32 * 32];
    __shared__ float sb1[32];
    __shared__ float sb2[32];
    for (int i = threadIdx.x; i < 64 * 32; i += 256) sw1[i] = w1g[i];
    for (int i = threadIdx.x; i < 32 * 32; i += 256) sw2[i] = w2g[i];
    if (threadIdx.x < 32) {
        sb1[threadIdx.x] = b1g[threadIdx.x];
        sb2[threadIdx.x] = b2g[threadIdx.x];
    }
    __syncthreads();
    int n = blockIdx.x * 256 + threadIdx.x;
    if (n >= n_nodes) return;

    const float4* hp = (const float4*)(h + (size_t)n * 32);
    const float4* ap = (const float4*)(agg + (size_t)n * 32);

    float hv[32];
    float acc[32];
    #pragma unroll
    for (int j = 0; j < 32; j++) acc[j] = sb1[j];
    #pragma unroll 2
    for (int cc = 0; cc < 8; cc++) {
        float4 xv = hp[cc];
        hv[4 * cc] = xv.x; hv[4 * cc + 1] = xv.y; hv[4 * cc + 2] = xv.z; hv[4 * cc + 3] = xv.w;
        float xsv[4] = {xv.x, xv.y, xv.z, xv.w};
        #pragma unroll
        for (int kk = 0; kk < 4; kk++) {
            float xk = xsv[kk];
            const float* wr = &sw1[(cc * 4 + kk) * 32];
            #pragma unroll
            for (int j = 0; j < 32; j++) acc[j] = fmaf(xk, wr[j], acc[j]);
        }
    }
    #pragma unroll 2
    for (int cc = 0; cc < 8; cc++) {
        float4 xv = ap[cc];
        float xsv[4] = {xv.x, xv.y, xv.z, xv.w};
        #pragma unroll
        for (int kk = 0; kk < 4; kk++) {
            float xk = xsv[kk];
            const float* wr = &sw1[(32 + cc * 4 + kk) * 32];
            #pragma unroll
            for (int j = 0; j < 32; j++) acc[j] = fmaf(xk, wr[j], acc[j]);
        }
    }
    #pragma unroll
    for (int j = 0; j < 32; j++) acc[j] = fmaxf(acc[j], 0.0f);

    float o[32];
    #pragma unroll
    for (int j = 0; j < 32; j++) o[j] = sb2[j];
    #pragma unroll 4
    for (int k = 0; k < 32; k++) {
        float hk = acc[k];
        const float* wr = &sw2[k * 32];
        #pragma unroll
        for (int j = 0; j < 32; j++) o[j] = fmaf(hk, wr[j], o[j]);
    }
    float4* op = (float4*)(h + (size_t)n * 32);
    #pragma unroll
    for (int cc = 0; cc < 8; cc++)
        op[cc] = make_float4(hv[4 * cc] + o[4 * cc], hv[4 * cc + 1] + o[4 * cc + 1],
                             hv[4 * cc + 2] + o[4 * cc + 2], hv[4 * cc + 3] + o[4 * cc + 3]);
}

// head: out = (relu(h @ w1 + b1) @ w2 + b2)[:, 0]   (fp32 out)
__global__ void AtomGNN_56169582297457_kernel(const float* h, const float* w1g, const float* b1g, const float* w2g, const float* b2g, float* out, int n_nodes) {
    __shared__ float sw1[32 * 32];
    __shared__ float sb1[32];
    __shared__ float sw2[32];
    __shared__ float sb2;
    for (int i = threadIdx.x; i < 32 * 32; i += 256) sw1[i] = w1g[i];
    if (threadIdx.x < 32) {
        sb1[threadIdx.x] = b1g[threadIdx.x];
        sw2[threadIdx.x] = w2g[threadIdx.x];
    }
    if (threadIdx.x == 0) sb2 = b2g[0];
    __syncthreads();
    int n = blockIdx.x * 256 + threadIdx.x;
    if (n >= n_nodes) return;

    const float4* hp = (const float4*)(h + (size_t)n * 32);
    float x[32];
    #pragma unroll
    for (int cc = 0; cc < 8; cc++) {
        float4 xv = hp[cc];
        x[4 * cc] = xv.x; x[4 * cc + 1] = xv.y; x[4 * cc + 2] = xv.z; x[4 * cc + 3] = xv.w;
    }
    float acc[32];
    #pragma unroll
    for (int j = 0; j < 32; j++) acc[j] = sb1[j];
    #pragma unroll 4
    for (int k = 0; k < 32; k++) {
        float xk = x[k];
        const float* wr = &sw1[k * 32];
        #pragma unroll
        for (int j = 0; j < 32; j++) acc[j] = fmaf(xk, wr[j], acc[j]);
    }
    float val = sb2;
    #pragma unroll
    for (int k = 0; k < 32; k++) val = fmaf(fmaxf(acc[k], 0.0f), sw2[k], val);
    out[n] = val;
}

extern "C" void kernel_launch(void* const* d_in, const int* in_sizes, int n_in,
                              void* d_out, int out_size, void* d_ws, size_t ws_size,
                              hipStream_t stream) {
    const float* nf      = (const float*)d_in[0];
    const int2*  edges   = (const int2*)d_in[1];
    const float4* ef     = (const float4*)d_in[2];
    const float* enc_w1  = (const float*)d_in[3];
    const float* enc_b1  = (const float*)d_in[4];
    const float* enc_w2  = (const float*)d_in[5];
    const float* enc_b2  = (const float*)d_in[6];
    const float* msg_w1  = (const float*)d_in[7];
    const float* msg_b1  = (const float*)d_in[8];
    const float* msg_w2  = (const float*)d_in[9];
    const float* msg_b2  = (const float*)d_in[10];
    const float* upd_w1  = (const float*)d_in[11];
    const float* upd_b1  = (const float*)d_in[12];
    const float* upd_w2  = (const float*)d_in[13];
    const float* upd_b2  = (const float*)d_in[14];
    const float* head_w1 = (const float*)d_in[15];
    const float* head_b1 = (const float*)d_in[16];
    const float* head_w2 = (const float*)d_in[17];
    const float* head_b2 = (const float*)d_in[18];

    int n_nodes = (out_size > 0) ? out_size : NN_REF;
    int n_edges = (in_sizes && n_in > 2 && in_sizes[2] > 0) ? in_sizes[2] / 4 : NE_REF;

    int nb_nodes = (n_nodes + 255) / 256;
    int nb_edges = (n_edges + 255) / 256;

    // Workspace layout (~71.2MB total, below proven-fitting 77.6MB):
    //   h0 | h1 | g16(half) | row_start[n+1] | cursor[n] | bsum[nb]
    //   | recs[3*E] int (packed: src, half2 ef01, half2 ef23)
    float* h0 = (float*)d_ws;
    float* h1 = h0 + (size_t)n_nodes * 32;
    __half* g16 = (__half*)(h1 + (size_t)n_nodes * 32);
    int* row_start = (int*)(g16 + (size_t)n_nodes * 32);
    int* cursor = row_start + (n_nodes + 1);
    int* bsum = cursor + n_nodes;
    int* recs = bsum + nb_nodes;
    size_t required = ((uintptr_t)(recs + (size_t)3 * n_edges) - (uintptr_t)d_ws);

    bool csr_ok = (nb_nodes <= 1024) &&
                  (ws_size == 0 || ws_size >= required);

    if (csr_ok) {
        k_encode<<<nb_nodes, 256, 0, stream>>>(nf, enc_w1, enc_b1, enc_w2, enc_b2, h0, n_nodes);

        // build dst-CSR once (edges identical across rounds)
        k_zero<<<256, 256, 0, stream>>>((float*)cursor, n_nodes);
        k_hist<<<nb_edges, 256, 0, stream>>>(edges, cursor, n_edges);
        k_scan_block<<<nb_nodes, 256, 0, stream>>>(cursor, row_start, bsum, n_nodes);
        k_scan_bsum<<<1, 1024, 0, stream>>>(bsum, nb_nodes, row_start, n_nodes, n_edges);
        k_scan_add<<<nb_nodes, 256, 0, stream>>>(row_start, cursor, bsum, n_nodes);
        k_fill3<<<nb_edges, 256, 0, stream>>>(edges, ef, cursor, recs, n_edges);

        // ping-pong rounds: h0 -> h1 -> h0
        for (int r = 0; r < 2; r++) {
            const float* hin = (r == 0) ? h0 : h1;
            float* hout      = (r == 0) ? h1 : h0;
            const float* mw1 = msg_w1 + (size_t)r * 68 * 32;
            k_gsrc16<<<1024, 256, 0, stream>>>(hin, mw1, g16, n_nodes);
            k_round_wave5<<<2048, 256, 0, stream>>>(
                hin, hout, g16, row_start, recs,
                mw1, msg_b1 + (size_t)r * 32,
                msg_w2 + (size_t)r * 32 * 32, msg_b2 + (size_t)r * 32,
                upd_w1 + (size_t)r * 64 * 32, upd_b1 + (size_t)r * 32,
                upd_w2 + (size_t)r * 32 * 32, upd_b2 + (size_t)r * 32,
                n_nodes);
        }

        AtomGNN_56169582297457_kernel<<<nb_nodes, 256, 0, stream>>>(
            h0, head_w1, head_b1, head_w2, head_b2, (float*)d_out, n_nodes);
    } else {
        // R14 fallback: atomic scatter path
        float* h   = (float*)d_ws;
        float* agg = h + (size_t)n_nodes * 32;

        k_encode<<<nb_nodes, 256, 0, stream>>>(nf, enc_w1, enc_b1, enc_w2, enc_b2, h, n_nodes);
        for (int r = 0; r < 2; r++) {
            k_zero<<<1024, 256, 0, stream>>>(agg, n_nodes * 32);
            k_message<<<nb_edges, 256, 0, stream>>>(
                h, edges, ef,
                msg_w1 + (size_t)r * 68 * 32, msg_b1 + (size_t)r * 32,
                msg_w2 + (size_t)r * 32 * 32, msg_b2 + (size_t)r * 32,
                agg, n_edges);
            k_update<<<nb_nodes, 256, 0, stream>>>(
                h, agg,
                upd_w1 + (size_t)r * 64 * 32, upd_b1 + (size_t)r * 32,
                upd_w2 + (size_t)r * 32 * 32, upd_b2 + (size_t)r * 32,
                n_nodes);
        }
        AtomGNN_56169582297457_kernel<<<nb_nodes, 256, 0, stream>>>(
            h, head_w1, head_b1, head_w2, head_b2, (float*)d_out, n_nodes);
    }
}

// Round 10
// 1186.412 us; speedup vs baseline: 2.7279x; 1.0067x over previous
//
#include <hip/hip_runtime.h>
#include <hip/hip_fp16.h>
#include <cstdio>
#include <cstdint>

// R24: cut the dependent shfl-chain latency. R23 killed the spill (WRITE ==
// h_out exactly, FETCH 143MB/round, 336us/round) leaving k_round_wave5
// latency-bound (VALU 22%, HBM 5%): four 32-step serial shfl->fma chains per
// node (~4000cy) dominate the ~1000cy ILP-4 edge loop. Fix: 4-way split
// accumulators -- each 32-step chain becomes 4 interleaved 8-step chains
// (k in [0,8)/[8,16)/[16,24)/[24,32)) summed at the end; dependent latency
// /4, pure fp32 reassociation. Applied to all 4 matmuls in the round kernel
// + k_gsrc16. Zero workspace/gating risk. If null: chains weren't the stall
// -> pivot to split-kernel or fill3 scatter.

__attribute__((constructor)) static void atomgnn_r24_load_beacon() {
    fprintf(stderr, "ATOMGNN_R24_SOURCE_LOADED\n");
    fflush(stderr);
}

#define NN_REF 100000
#define NE_REF 3200000

// zero a float/int buffer (4B words), grid-stride
__global__ void __launch_bounds__(256)
k_zero(float* __restrict__ p, int n)
{
    int i = blockIdx.x * 256 + threadIdx.x;
    int stride = gridDim.x * 256;
    for (; i < n; i += stride) p[i] = 0.0f;
}

// encoder: h = relu(nf @ w1 + b1) @ w2 + b2   (16 -> 32 -> 32)
__global__ void __launch_bounds__(256)
k_encode(const float* __restrict__ nf,
         const float* __restrict__ w1g, const float* __restrict__ b1g,
         const float* __restrict__ w2g, const float* __restrict__ b2g,
         float* __restrict__ h, int n_nodes)
{
    __shared__ float sw1[16 * 32];
    __shared__ float sw2[32 * 32];
    __shared__ float sb1[32];
    __shared__ float sb2[32];
    for (int i = threadIdx.x; i < 16 * 32; i += 256) sw1[i] = w1g[i];
    for (int i = threadIdx.x; i < 32 * 32; i += 256) sw2[i] = w2g[i];
    if (threadIdx.x < 32) {
        sb1[threadIdx.x] = b1g[threadIdx.x];
        sb2[threadIdx.x] = b2g[threadIdx.x];
    }
    __syncthreads();
    int n = blockIdx.x * 256 + threadIdx.x;
    if (n >= n_nodes) return;

    const float4* p = (const float4*)(nf + (size_t)n * 16);
    float x[16];
    #pragma unroll
    for (int c = 0; c < 4; c++) {
        float4 v = p[c];
        x[4 * c] = v.x; x[4 * c + 1] = v.y; x[4 * c + 2] = v.z; x[4 * c + 3] = v.w;
    }

    float acc[32];
    #pragma unroll
    for (int j = 0; j < 32; j++) acc[j] = sb1[j];
    #pragma unroll 4
    for (int k = 0; k < 16; k++) {
        float xk = x[k];
        const float* wr = &sw1[k * 32];
        #pragma unroll
        for (int j = 0; j < 32; j++) acc[j] = fmaf(xk, wr[j], acc[j]);
    }
    #pragma unroll
    for (int j = 0; j < 32; j++) acc[j] = fmaxf(acc[j], 0.0f);

    float o[32];
    #pragma unroll
    for (int j = 0; j < 32; j++) o[j] = sb2[j];
    #pragma unroll 4
    for (int k = 0; k < 32; k++) {
        float hk = acc[k];
        const float* wr = &sw2[k * 32];
        #pragma unroll
        for (int j = 0; j < 32; j++) o[j] = fmaf(hk, wr[j], o[j]);
    }
    float4* hp = (float4*)(h + (size_t)n * 32);
    #pragma unroll
    for (int c = 0; c < 8; c++)
        hp[c] = make_float4(o[4 * c], o[4 * c + 1], o[4 * c + 2], o[4 * c + 3]);
}

// -------- CSR build: histogram -> exclusive scan -> fill --------

__global__ void __launch_bounds__(256)
k_hist(const int2* __restrict__ edges, int* __restrict__ cnt, int n_edges)
{
    int e = blockIdx.x * 256 + threadIdx.x;
    if (e >= n_edges) return;
    atomicAdd(&cnt[edges[e].y], 1);
}

__global__ void __launch_bounds__(256)
k_scan_block(const int* __restrict__ cnt, int* __restrict__ rs,
             int* __restrict__ bsum, int n)
{
    __shared__ int sd[256];
    int t = threadIdx.x;
    int i = blockIdx.x * 256 + t;
    int v = (i < n) ? cnt[i] : 0;
    sd[t] = v;
    __syncthreads();
    int val = v;
    for (int off = 1; off < 256; off <<= 1) {
        int add = (t >= off) ? sd[t - off] : 0;
        __syncthreads();
        val += add;
        sd[t] = val;
        __syncthreads();
    }
    if (i < n) rs[i] = val - v;           // exclusive within block
    if (t == 255) bsum[blockIdx.x] = val; // block total
}

__global__ void __launch_bounds__(1024)
k_scan_bsum(int* __restrict__ bsum, int nb, int* __restrict__ rs,
            int n_nodes, int n_edges)
{
    __shared__ int sd[1024];
    int t = threadIdx.x;
    int v = (t < nb) ? bsum[t] : 0;
    sd[t] = v;
    __syncthreads();
    int val = v;
    for (int off = 1; off < 1024; off <<= 1) {
        int add = (t >= off) ? sd[t - off] : 0;
        __syncthreads();
        val += add;
        sd[t] = val;
        __syncthreads();
    }
    if (t < nb) bsum[t] = val - v;  // exclusive prefix of block totals
    if (t == 0) rs[n_nodes] = n_edges;
}

__global__ void __launch_bounds__(256)
k_scan_add(int* __restrict__ rs, int* __restrict__ cursor,
           const int* __restrict__ bsum, int n)
{
    int i = blockIdx.x * 256 + threadIdx.x;
    if (i < n) {
        int v = rs[i] + bsum[blockIdx.x];
        rs[i] = v;
        cursor[i] = v;
    }
}

// scatter edges into dst-sorted packed slot records:
//   recs[3*pos] = src, recs[3*pos+1] = half2(ef.x,ef.y),
//   recs[3*pos+2] = half2(ef.z,ef.w)
__global__ void __launch_bounds__(256)
k_fill3(const int2* __restrict__ edges, const float4* __restrict__ ef,
        int* __restrict__ cursor, int* __restrict__ recs, int n_edges)
{
    int e = blockIdx.x * 256 + threadIdx.x;
    if (e >= n_edges) return;
    int2 ed = edges[e];
    float4 v = ef[e];
    int pos = atomicAdd(&cursor[ed.y], 1);
    __half2 h01 = __floats2half2_rn(v.x, v.y);
    __half2 h23 = __floats2half2_rn(v.z, v.w);
    recs[3 * pos]     = ed.x;
    recs[3 * pos + 1] = *reinterpret_cast<int*>(&h01);
    recs[3 * pos + 2] = *reinterpret_cast<int*>(&h23);
}

// -------- per-round precompute: g16[n][c] = fp16( sum_k h[n][k]*W1a[k][c] )
// 4-way split accumulator chains (latency /4).
__global__ void __launch_bounds__(256)
k_gsrc16(const float* __restrict__ h, const float* __restrict__ mw1,
         __half* __restrict__ g16, int n_nodes)
{
    __shared__ float sW[32 * 32];
    for (int i = threadIdx.x; i < 32 * 32; i += 256) sW[i] = mw1[i];
    __syncthreads();
    const int lane = threadIdx.x & 63;
    const int c    = lane & 31;
    const int half = lane >> 5;
    int wi = (int)((blockIdx.x * 256 + threadIdx.x) >> 6);
    int nw = gridDim.x * 4;
    for (; 2 * wi < n_nodes; wi += nw) {
        int nr = 2 * wi + half;
        int n  = min(nr, n_nodes - 1);
        float hn = h[(size_t)n * 32 + c];
        float p0 = 0.0f, p1 = 0.0f, p2 = 0.0f, p3 = 0.0f;
        #pragma unroll
        for (int k = 0; k < 8; k++) {
            p0 = fmaf(__shfl(hn, k,      32), sW[(k)      * 32 + c], p0);
            p1 = fmaf(__shfl(hn, k + 8,  32), sW[(k + 8)  * 32 + c], p1);
            p2 = fmaf(__shfl(hn, k + 16, 32), sW[(k + 16) * 32 + c], p2);
            p3 = fmaf(__shfl(hn, k + 24, 32), sW[(k + 24) * 32 + c], p3);
        }
        float b = (p0 + p1) + (p2 + p3);
        if (nr < n_nodes) g16[(size_t)n * 32 + c] = __float2half(b);
    }
}

// -------- fused round v6: wave-per-node, split-chain matmuls ------
// per edge: m1[c] = relu(base[dst][c] + g[src][c] + sum_k ef[k]*W1c[k][c])
// records stream sequentially; g16 is the only random access.
// Plain __launch_bounds__(256): proven zero-spill. All four 32-step
// shfl->fma matmul chains split into 4 interleaved 8-step chains.
__global__ void __launch_bounds__(256)
k_round_wave5(const float* __restrict__ h_in, float* __restrict__ h_out,
        const __half* __restrict__ g16,
        const int* __restrict__ row_start, const int* __restrict__ recs,
        const float* __restrict__ mw1, const float* __restrict__ mb1,
        const float* __restrict__ mw2, const float* __restrict__ mb2,
        const float* __restrict__ uw1, const float* __restrict__ ub1,
        const float* __restrict__ uw2, const float* __restrict__ ub2,
        int n_nodes)
{
    __shared__ float sW1b[32 * 32];   // msg_w1 rows 32..63 (dst half)
    __shared__ float sW2[32 * 32];
    __shared__ float sU1[64 * 32];
    __shared__ float sU2[32 * 32];
    __shared__ float sB[4 * 32];      // mb1 | mb2 | ub1 | ub2
    for (int i = threadIdx.x; i < 32 * 32; i += 256) sW1b[i] = mw1[32 * 32 + i];
    for (int i = threadIdx.x; i < 32 * 32; i += 256) sW2[i]  = mw2[i];
    for (int i = threadIdx.x; i < 64 * 32; i += 256) sU1[i]  = uw1[i];
    for (int i = threadIdx.x; i < 32 * 32; i += 256) sU2[i]  = uw2[i];
    if (threadIdx.x < 32) {
        sB[threadIdx.x]      = mb1[threadIdx.x];
        sB[32 + threadIdx.x] = mb2[threadIdx.x];
        sB[64 + threadIdx.x] = ub1[threadIdx.x];
        sB[96 + threadIdx.x] = ub2[threadIdx.x];
    }
    __syncthreads();

    const int lane = threadIdx.x & 63;
    const int c    = lane & 31;
    const int half = lane >> 5;

    // per-lane private ef column of msg W1 (k=0..3)
    float w1c[4];
    #pragma unroll
    for (int k = 0; k < 4; k++) w1c[k] = mw1[(64 + k) * 32 + c];

    int wave   = (int)((blockIdx.x * 256 + threadIdx.x) >> 6);
    int nwaves = gridDim.x * 4;

    for (int n = wave; n < n_nodes; n += nwaves) {
        float hn = h_in[(size_t)n * 32 + c];

        // base = mb1 + h[n] @ W1b  (4-way split chains)
        float base;
        {
            float p0 = sB[c], p1 = 0.0f, p2 = 0.0f, p3 = 0.0f;
            #pragma unroll
            for (int k = 0; k < 8; k++) {
                p0 = fmaf(__shfl(hn, k,      32), sW1b[(k)      * 32 + c], p0);
                p1 = fmaf(__shfl(hn, k + 8,  32), sW1b[(k + 8)  * 32 + c], p1);
                p2 = fmaf(__shfl(hn, k + 16, 32), sW1b[(k + 16) * 32 + c], p2);
                p3 = fmaf(__shfl(hn, k + 24, 32), sW1b[(k + 24) * 32 + c], p3);
            }
            base = (p0 + p1) + (p2 + p3);
        }

        int s0 = row_start[n];
        int s1 = row_start[n + 1];
        float rsum = 0.0f;

        int s = s0 + half;   // this half's slots: s, s+2, s+4, ...
        // main loop: 4 edges per half in flight
        for (; s + 6 < s1; s += 8) {
            int b0 = 3 * s;
            int b1 = 3 * (s + 2);
            int b2 = 3 * (s + 4);
            int b3 = 3 * (s + 6);
            int i0 = recs[b0];
            int i1 = recs[b1];
            int i2 = recs[b2];
            int i3 = recs[b3];
            uint32_t u01_0 = (uint32_t)recs[b0 + 1], u23_0 = (uint32_t)recs[b0 + 2];
            uint32_t u01_1 = (uint32_t)recs[b1 + 1], u23_1 = (uint32_t)recs[b1 + 2];
            uint32_t u01_2 = (uint32_t)recs[b2 + 1], u23_2 = (uint32_t)recs[b2 + 2];
            uint32_t u01_3 = (uint32_t)recs[b3 + 1], u23_3 = (uint32_t)recs[b3 + 2];
            float x0 = __half2float(g16[(size_t)i0 * 32 + c]);
            float x1 = __half2float(g16[(size_t)i1 * 32 + c]);
            float x2 = __half2float(g16[(size_t)i2 * 32 + c]);
            float x3 = __half2float(g16[(size_t)i3 * 32 + c]);

            float2 eA0 = __half22float2(*reinterpret_cast<const __half2*>(&u01_0));
            float2 eB0 = __half22float2(*reinterpret_cast<const __half2*>(&u23_0));
            float2 eA1 = __half22float2(*reinterpret_cast<const __half2*>(&u01_1));
            float2 eB1 = __half22float2(*reinterpret_cast<const __half2*>(&u23_1));
            float2 eA2 = __half22float2(*reinterpret_cast<const __half2*>(&u01_2));
            float2 eB2 = __half22float2(*reinterpret_cast<const __half2*>(&u23_2));
            float2 eA3 = __half22float2(*reinterpret_cast<const __half2*>(&u01_3));
            float2 eB3 = __half22float2(*reinterpret_cast<const __half2*>(&u23_3));

            float a0 = base + x0;
            float a1 = base + x1;
            float a2 = base + x2;
            float a3 = base + x3;
            a0 = fmaf(eA0.x, w1c[0], a0); a0 = fmaf(eA0.y, w1c[1], a0);
            a0 = fmaf(eB0.x, w1c[2], a0); a0 = fmaf(eB0.y, w1c[3], a0);
            a1 = fmaf(eA1.x, w1c[0], a1); a1 = fmaf(eA1.y, w1c[1], a1);
            a1 = fmaf(eB1.x, w1c[2], a1); a1 = fmaf(eB1.y, w1c[3], a1);
            a2 = fmaf(eA2.x, w1c[0], a2); a2 = fmaf(eA2.y, w1c[1], a2);
            a2 = fmaf(eB2.x, w1c[2], a2); a2 = fmaf(eB2.y, w1c[3], a2);
            a3 = fmaf(eA3.x, w1c[0], a3); a3 = fmaf(eA3.y, w1c[1], a3);
            a3 = fmaf(eB3.x, w1c[2], a3); a3 = fmaf(eB3.y, w1c[3], a3);

            rsum += fmaxf(a0, 0.0f);
            rsum += fmaxf(a1, 0.0f);
            rsum += fmaxf(a2, 0.0f);
            rsum += fmaxf(a3, 0.0f);
        }
        // tail: one edge at a time
        for (; s < s1; s += 2) {
            int b = 3 * s;
            int i0 = recs[b];
            uint32_t u01 = (uint32_t)recs[b + 1], u23 = (uint32_t)recs[b + 2];
            float x = __half2float(g16[(size_t)i0 * 32 + c]);
            float2 eA = __half22float2(*reinterpret_cast<const __half2*>(&u01));
            float2 eB = __half22float2(*reinterpret_cast<const __half2*>(&u23));
            float a = base + x;
            a = fmaf(eA.x, w1c[0], a); a = fmaf(eA.y, w1c[1], a);
            a = fmaf(eB.x, w1c[2], a); a = fmaf(eB.y, w1c[3], a);
            rsum += fmaxf(a, 0.0f);
        }
        // combine halves (both halves converged here)
        rsum += __shfl_xor(rsum, 32, 64);

        // agg = deg*mb2 + rsum @ W2  (4-way split chains)
        float deg = (float)(s1 - s0);
        float agg;
        {
            float p0 = deg * sB[32 + c], p1 = 0.0f, p2 = 0.0f, p3 = 0.0f;
            #pragma unroll
            for (int k = 0; k < 8; k++) {
                p0 = fmaf(__shfl(rsum, k,      32), sW2[(k)      * 32 + c], p0);
                p1 = fmaf(__shfl(rsum, k + 8,  32), sW2[(k + 8)  * 32 + c], p1);
                p2 = fmaf(__shfl(rsum, k + 16, 32), sW2[(k + 16) * 32 + c], p2);
                p3 = fmaf(__shfl(rsum, k + 24, 32), sW2[(k + 24) * 32 + c], p3);
            }
            agg = (p0 + p1) + (p2 + p3);
        }

        // update MLP layer 1: ub1 + h[n]@U1[0:32] + agg@U1[32:64]
        // (two 32-matmuls -> 8 interleaved 8-step chains)
        float a2v;
        {
            float p0 = sB[64 + c], p1 = 0.0f, p2 = 0.0f, p3 = 0.0f;
            float q0 = 0.0f, q1 = 0.0f, q2 = 0.0f, q3 = 0.0f;
            #pragma unroll
            for (int k = 0; k < 8; k++) {
                p0 = fmaf(__shfl(hn, k,       32), sU1[(k)      * 32 + c], p0);
                p1 = fmaf(__shfl(hn, k + 8,   32), sU1[(k + 8)  * 32 + c], p1);
                p2 = fmaf(__shfl(hn, k + 16,  32), sU1[(k + 16) * 32 + c], p2);
                p3 = fmaf(__shfl(hn, k + 24,  32), sU1[(k + 24) * 32 + c], p3);
                q0 = fmaf(__shfl(agg, k,      32), sU1[(32 + k)      * 32 + c], q0);
                q1 = fmaf(__shfl(agg, k + 8,  32), sU1[(32 + k + 8)  * 32 + c], q1);
                q2 = fmaf(__shfl(agg, k + 16, 32), sU1[(32 + k + 16) * 32 + c], q2);
                q3 = fmaf(__shfl(agg, k + 24, 32), sU1[(32 + k + 24) * 32 + c], q3);
            }
            a2v = ((p0 + p1) + (p2 + p3)) + ((q0 + q1) + (q2 + q3));
        }
        float t = fmaxf(a2v, 0.0f);

        // update MLP layer 2: ub2 + t @ U2  (4-way split chains)
        float o;
        {
            float p0 = sB[96 + c], p1 = 0.0f, p2 = 0.0f, p3 = 0.0f;
            #pragma unroll
            for (int k = 0; k < 8; k++) {
                p0 = fmaf(__shfl(t, k,      32), sU2[(k)      * 32 + c], p0);
                p1 = fmaf(__shfl(t, k + 8,  32), sU2[(k + 8)  * 32 + c], p1);
                p2 = fmaf(__shfl(t, k + 16, 32), sU2[(k + 16) * 32 + c], p2);
                p3 = fmaf(__shfl(t, k + 24, 32), sU2[(k + 24) * 32 + c], p3);
            }
            o = (p0 + p1) + (p2 + p3);
        }

        if (lane < 32) h_out[(size_t)n * 32 + c] = hn + o;
    }
}

// -------- R14 fallback kernels (atomic path), used only if ws too small -----

__global__ void __launch_bounds__(256)
k_message(const float* __restrict__ h, const int2* __restrict__ edges,
          const float4* __restrict__ ef,
          const float* __restrict__ w1g, const float* __restrict__ b1g,
          const float* __restrict__ w2g, const float* __restrict__ b2g,
          float* __restrict__ agg, int n_edges)
{
    __shared__ float sw1[68 * 32];
    __shared__ float sw2[32 * 32];
    __shared__ float sb1[32];
    __shared__ float sb2[32];
    for (int i = threadIdx.x; i < 68 * 32; i += 256) sw1[i] = w1g[i];
    for (int i = threadIdx.x; i < 32 * 32; i += 256) sw2[i] = w2g[i];
    if (threadIdx.x < 32) {
        sb1[threadIdx.x] = b1g[threadIdx.x];
        sb2[threadIdx.x] = b2g[threadIdx.x];
    }
    __syncthreads();
    int e = blockIdx.x * 256 + threadIdx.x;
    if (e >= n_edges) return;

    int2 ed = edges[e];
    const float4* hs = (const float4*)(h + (size_t)ed.x * 32);
    const float4* hd = (const float4*)(h + (size_t)ed.y * 32);

    float acc[32];
    #pragma unroll
    for (int j = 0; j < 32; j++) acc[j] = sb1[j];
    #pragma unroll 2
    for (int cc = 0; cc < 8; cc++) {
        float4 xv = hs[cc];
        float xsv[4] = {xv.x, xv.y, xv.z, xv.w};
        #pragma unroll
        for (int kk = 0; kk < 4; kk++) {
            float xk = xsv[kk];
            const float* wr = &sw1[(cc * 4 + kk) * 32];
            #pragma unroll
            for (int j = 0; j < 32; j++) acc[j] = fmaf(xk, wr[j], acc[j]);
        }
    }
    #pragma unroll 2
    for (int cc = 0; cc < 8; cc++) {
        float4 xv = hd[cc];
        float xsv[4] = {xv.x, xv.y, xv.z, xv.w};
        #pragma unroll
        for (int kk = 0; kk < 4; kk++) {
            float xk = xsv[kk];
            const float* wr = &sw1[(32 + cc * 4 + kk) * 32];
            #pragma unroll
            for (int j = 0; j < 32; j++) acc[j] = fmaf(xk, wr[j], acc[j]);
        }
    }
    {
        float4 evv = ef[e];
        float ex[4] = {evv.x, evv.y, evv.z, evv.w};
        #pragma unroll
        for (int kk = 0; kk < 4; kk++) {
            float xk = ex[kk];
            const float* wr = &sw1[(64 + kk) * 32];
            #pragma unroll
            for (int j = 0; j < 32; j++) acc[j] = fmaf(xk, wr[j], acc[j]);
        }
    }
    #pragma unroll
    for (int j = 0; j < 32; j++) acc[j] = fmaxf(acc[j], 0.0f);

    float o[32];
    #pragma unroll
    for (int j = 0; j < 32; j++) o[j] = sb2[j];
    #pragma unroll 4
    for (int k = 0; k < 32; k++) {
        float hk = acc[k];
        const float* wr = &sw2[k * 32];
        #pragma unroll
        for (int j = 0; j < 32; j++) o[j] = fmaf(hk, wr[j], o[j]);
    }
    float* ap = agg + (size_t)ed.y * 32;
    #pragma unroll
    for (int j = 0; j < 32; j++) atomicAdd(ap + j, o[j]);
}

__global__ void __launch_bounds__(256)
k_update(float* h, const float* __restrict__ agg,
         const float* __restrict__ w1g, const float* __restrict__ b1g,
         const float* __restrict__ w2g, const float* __restrict__ b2g,
         int n_nodes)
{
    __shared__ float sw1[64 * 32];
    __shared__ float sw2[32 * 32];
    __shared__ float sb1[32];
    __shared__ float sb2[32];
    for (int i = threadIdx.x; i < 64 * 32; i += 256) sw1[i] = w1g[i];
    for (int i = threadIdx.x; i < 32 * 32; i += 256) sw2[i] = w2g[i];
    if (threadIdx.x < 32) {
        sb1[threadIdx.x] = b1g[threadIdx.x];
        sb2[threadIdx.x] = b2g[threadIdx.x];
    }
    __syncthreads();
    int n = blockIdx.x * 256 + threadIdx.x;
    if (n >= n_nodes) return;

    const float4* hp = (const float4*)(h + (size_t)n * 32);
    const float4* ap = (const float4*)(agg + (size_t)n * 32);

    float hv[32];
    float acc[32];
    #pragma unroll
    for (int j = 0; j < 32; j++) acc[j] = sb1[j];
    #pragma unroll 2
    for (int cc = 0; cc < 8; cc++) {
        float4 xv = hp[cc];
        hv[4 * cc] = xv.x; hv[4 * cc + 1] = xv.y; hv[4 * cc + 2] = xv.z; hv[4 * cc + 3] = xv.w;
        float xsv[4] = {xv.x, xv.y, xv.z, xv.w};
        #pragma unroll
        for (int kk = 0; kk < 4; kk++) {
            float xk = xsv[kk];
            const float* wr = &sw1[(cc * 4 + kk) * 32];
            #pragma unroll
            for (int j = 0; j < 32; j++) acc[j] = fmaf(xk, wr[j], acc[j]);
        }
    }
    #pragma unroll 2
    for (int cc = 0; cc < 8; cc++) {
        float4 xv = ap[cc];
        float xsv[4] = {xv.x, xv.y, xv.z, xv.w};
        #pragma unroll
        for (int kk = 0; kk < 4; kk++) {
            float xk = xsv[kk];
            const float* wr = &sw1[(32 + cc * 4 + kk) * 32];
            #pragma unroll
            for (int j = 0; j < 32; j++) acc[j] = fmaf(xk, wr[j], acc[j]);
        }
    }
    #pragma unroll
    for (int j = 0; j < 32; j++) acc[j] = fmaxf(acc[j], 0.0f);

    float o[32];
    #pragma unroll
    for (int j = 0; j < 32; j++) o[j] = sb2[j];
    #pragma unroll 4
    for (int k = 0; k < 32; k++) {
        float hk = acc[k];
        const float* wr = &sw2[k * 32];
        #pragma unroll
        for (int j = 0; j < 32; j++) o[j] = fmaf(hk, wr[j], o[j]);
    }
    float4* op = (float4*)(h + (size_t)n * 32);
    #pragma unroll
    for (int cc = 0; cc < 8; cc++)
        op[cc] = make_float4(hv[4 * cc] + o[4 * cc], hv[4 * cc + 1] + o[4 * cc + 1],
                             hv[4 * cc + 2] + o[4 * cc + 2], hv[4 * cc + 3] + o[4 * cc + 3]);
}

// head: out = (relu(h @ w1 + b1) @ w2 + b2)[:, 0]   (fp32 out)
__global__ void AtomGNN_56169582297457_kernel(const float* h, const float* w1g, const float* b1g, const float* w2g, const float* b2g, float* out, int n_nodes) {
    __shared__ float sw1[32 * 32];
    __shared__ float sb1[32];
    __shared__ float sw2[32];
    __shared__ float sb2;
    for (int i = threadIdx.x; i < 32 * 32; i += 256) sw1[i] = w1g[i];
    if (threadIdx.x < 32) {
        sb1[threadIdx.x] = b1g[threadIdx.x];
        sw2[threadIdx.x] = w2g[threadIdx.x];
    }
    if (threadIdx.x == 0) sb2 = b2g[0];
    __syncthreads();
    int n = blockIdx.x * 256 + threadIdx.x;
    if (n >= n_nodes) return;

    const float4* hp = (const float4*)(h + (size_t)n * 32);
    float x[32];
    #pragma unroll
    for (int cc = 0; cc < 8; cc++) {
        float4 xv = hp[cc];
        x[4 * cc] = xv.x; x[4 * cc + 1] = xv.y; x[4 * cc + 2] = xv.z; x[4 * cc + 3] = xv.w;
    }
    float acc[32];
    #pragma unroll
    for (int j = 0; j < 32; j++) acc[j] = sb1[j];
    #pragma unroll 4
    for (int k = 0; k < 32; k++) {
        float xk = x[k];
        const float* wr = &sw1[k * 32];
        #pragma unroll
        for (int j = 0; j < 32; j++) acc[j] = fmaf(xk, wr[j], acc[j]);
    }
    float val = sb2;
    #pragma unroll
    for (int k = 0; k < 32; k++) val = fmaf(fmaxf(acc[k], 0.0f), sw2[k], val);
    out[n] = val;
}

extern "C" void kernel_launch(void* const* d_in, const int* in_sizes, int n_in,
                              void* d_out, int out_size, void* d_ws, size_t ws_size,
                              hipStream_t stream) {
    const float* nf      = (const float*)d_in[0];
    const int2*  edges   = (const int2*)d_in[1];
    const float4* ef     = (const float4*)d_in[2];
    const float* enc_w1  = (const float*)d_in[3];
    const float* enc_b1  = (const float*)d_in[4];
    const float* enc_w2  = (const float*)d_in[5];
    const float* enc_b2  = (const float*)d_in[6];
    const float* msg_w1  = (const float*)d_in[7];
    const float* msg_b1  = (const float*)d_in[8];
    const float* msg_w2  = (const float*)d_in[9];
    const float* msg_b2  = (const float*)d_in[10];
    const float* upd_w1  = (const float*)d_in[11];
    const float* upd_b1  = (const float*)d_in[12];
    const float* upd_w2  = (const float*)d_in[13];
    const float* upd_b2  = (const float*)d_in[14];
    const float* head_w1 = (const float*)d_in[15];
    const float* head_b1 = (const float*)d_in[16];
    const float* head_w2 = (const float*)d_in[17];
    const float* head_b2 = (const float*)d_in[18];

    int n_nodes = (out_size > 0) ? out_size : NN_REF;
    int n_edges = (in_sizes && n_in > 2 && in_sizes[2] > 0) ? in_sizes[2] / 4 : NE_REF;

    int nb_nodes = (n_nodes + 255) / 256;
    int nb_edges = (n_edges + 255) / 256;

    // Workspace layout (~71.2MB total, below proven-fitting 77.6MB):
    //   h0 | h1 | g16(half) | row_start[n+1] | cursor[n] | bsum[nb]
    //   | recs[3*E] int (packed: src, half2 ef01, half2 ef23)
    float* h0 = (float*)d_ws;
    float* h1 = h0 + (size_t)n_nodes * 32;
    __half* g16 = (__half*)(h1 + (size_t)n_nodes * 32);
    int* row_start = (int*)(g16 + (size_t)n_nodes * 32);
    int* cursor = row_start + (n_nodes + 1);
    int* bsum = cursor + n_nodes;
    int* recs = bsum + nb_nodes;
    size_t required = ((uintptr_t)(recs + (size_t)3 * n_edges) - (uintptr_t)d_ws);

    bool csr_ok = (nb_nodes <= 1024) &&
                  (ws_size == 0 || ws_size >= required);

    if (csr_ok) {
        k_encode<<<nb_nodes, 256, 0, stream>>>(nf, enc_w1, enc_b1, enc_w2, enc_b2, h0, n_nodes);

        // build dst-CSR once (edges identical across rounds)
        k_zero<<<256, 256, 0, stream>>>((float*)cursor, n_nodes);
        k_hist<<<nb_edges, 256, 0, stream>>>(edges, cursor, n_edges);
        k_scan_block<<<nb_nodes, 256, 0, stream>>>(cursor, row_start, bsum, n_nodes);
        k_scan_bsum<<<1, 1024, 0, stream>>>(bsum, nb_nodes, row_start, n_nodes, n_edges);
        k_scan_add<<<nb_nodes, 256, 0, stream>>>(row_start, cursor, bsum, n_nodes);
        k_fill3<<<nb_edges, 256, 0, stream>>>(edges, ef, cursor, recs, n_edges);

        // ping-pong rounds: h0 -> h1 -> h0
        for (int r = 0; r < 2; r++) {
            const float* hin = (r == 0) ? h0 : h1;
            float* hout      = (r == 0) ? h1 : h0;
            const float* mw1 = msg_w1 + (size_t)r * 68 * 32;
            k_gsrc16<<<1024, 256, 0, stream>>>(hin, mw1, g16, n_nodes);
            k_round_wave5<<<2048, 256, 0, stream>>>(
                hin, hout, g16, row_start, recs,
                mw1, msg_b1 + (size_t)r * 32,
                msg_w2 + (size_t)r * 32 * 32, msg_b2 + (size_t)r * 32,
                upd_w1 + (size_t)r * 64 * 32, upd_b1 + (size_t)r * 32,
                upd_w2 + (size_t)r * 32 * 32, upd_b2 + (size_t)r * 32,
                n_nodes);
        }

        AtomGNN_56169582297457_kernel<<<nb_nodes, 256, 0, stream>>>(
            h0, head_w1, head_b1, head_w2, head_b2, (float*)d_out, n_nodes);
    } else {
        // R14 fallback: atomic scatter path
        float* h   = (float*)d_ws;
        float* agg = h + (size_t)n_nodes * 32;

        k_encode<<<nb_nodes, 256, 0, stream>>>(nf, enc_w1, enc_b1, enc_w2, enc_b2, h, n_nodes);
        for (int r = 0; r < 2; r++) {
            k_zero<<<1024, 256, 0, stream>>>(agg, n_nodes * 32);
            k_message<<<nb_edges, 256, 0, stream>>>(
                h, edges, ef,
                msg_w1 + (size_t)r * 68 * 32, msg_b1 + (size_t)r * 32,
                msg_w2 + (size_t)r * 32 * 32, msg_b2 + (size_t)r * 32,
                agg, n_edges);
            k_update<<<nb_nodes, 256, 0, stream>>>(
                h, agg,
                upd_w1 + (size_t)r * 64 * 32, upd_b1 + (size_t)r * 32,
                upd_w2 + (size_t)r * 32 * 32, upd_b2 + (size_t)r * 32,
                n_nodes);
        }
        AtomGNN_56169582297457_kernel<<<nb_nodes, 256, 0, stream>>>(
            h, head_w1, head_b1, head_w2, head_b2, (float*)d_out, n_nodes);
    }
}

// Round 11
// 807.642 us; speedup vs baseline: 4.0073x; 1.4690x over previous
//
#include <hip/hip_runtime.h>
#include <hip/hip_fp16.h>
#include <cstdio>
#include <cstdint>

// R25: phase-split the round. R24's split-chains were NULL (336->335us):
// chains weren't the stall. Real issue: the fused kernel mixes a latency-bound
// gather (needs waves: R20-22 ran 8/SIMD at VGPR 64) with LDS-heavy node
// matmuls (needs registers: VGPR 128 -> only 4 waves/SIMD). Split:
// k_edge (wave-per-node: base chain + ILP-4 gather + rsum -> h_out buffer,
// lean LDS/regs -> occupancy back up) and k_post (thread-per-node register-
// tile matmuls, k_encode pattern, zero shfl; fuses next-round g16 emit and
// last-round head MLP -> kills k_gsrc16 x2 + head kernel). Workspace layout
// byte-identical to proven 71.2MB. R14 atomic path kept as fallback.

__attribute__((constructor)) static void atomgnn_r25_load_beacon() {
    fprintf(stderr, "ATOMGNN_R25_SOURCE_LOADED\n");
    fflush(stderr);
}

#define NN_REF 100000
#define NE_REF 3200000

// zero a float/int buffer (4B words), grid-stride
__global__ void __launch_bounds__(256)
k_zero(float* __restrict__ p, int n)
{
    int i = blockIdx.x * 256 + threadIdx.x;
    int stride = gridDim.x * 256;
    for (; i < n; i += stride) p[i] = 0.0f;
}

// encoder + g16 emit: h = relu(nf@w1+b1)@w2+b2; g16 = fp16(h @ W1a_round0)
__global__ void __launch_bounds__(256)
k_encode2(const float* __restrict__ nf,
          const float* __restrict__ w1g, const float* __restrict__ b1g,
          const float* __restrict__ w2g, const float* __restrict__ b2g,
          const float* __restrict__ mw1r0,   // msg_w1 round 0 (rows 0..31 used)
          float* __restrict__ h, __half* __restrict__ g16, int n_nodes)
{
    __shared__ float sw1[16 * 32];
    __shared__ float sw2[32 * 32];
    __shared__ float sWg[32 * 32];
    __shared__ float sb1[32];
    __shared__ float sb2[32];
    for (int i = threadIdx.x; i < 16 * 32; i += 256) sw1[i] = w1g[i];
    for (int i = threadIdx.x; i < 32 * 32; i += 256) sw2[i] = w2g[i];
    for (int i = threadIdx.x; i < 32 * 32; i += 256) sWg[i] = mw1r0[i];
    if (threadIdx.x < 32) {
        sb1[threadIdx.x] = b1g[threadIdx.x];
        sb2[threadIdx.x] = b2g[threadIdx.x];
    }
    __syncthreads();
    int n = blockIdx.x * 256 + threadIdx.x;
    if (n >= n_nodes) return;

    const float4* p = (const float4*)(nf + (size_t)n * 16);
    float x[16];
    #pragma unroll
    for (int c = 0; c < 4; c++) {
        float4 v = p[c];
        x[4 * c] = v.x; x[4 * c + 1] = v.y; x[4 * c + 2] = v.z; x[4 * c + 3] = v.w;
    }

    float acc[32];
    #pragma unroll
    for (int j = 0; j < 32; j++) acc[j] = sb1[j];
    #pragma unroll 4
    for (int k = 0; k < 16; k++) {
        float xk = x[k];
        const float* wr = &sw1[k * 32];
        #pragma unroll
        for (int j = 0; j < 32; j++) acc[j] = fmaf(xk, wr[j], acc[j]);
    }
    #pragma unroll
    for (int j = 0; j < 32; j++) acc[j] = fmaxf(acc[j], 0.0f);

    float o[32];
    #pragma unroll
    for (int j = 0; j < 32; j++) o[j] = sb2[j];
    #pragma unroll 4
    for (int k = 0; k < 32; k++) {
        float hk = acc[k];
        const float* wr = &sw2[k * 32];
        #pragma unroll
        for (int j = 0; j < 32; j++) o[j] = fmaf(hk, wr[j], o[j]);
    }
    float4* hp = (float4*)(h + (size_t)n * 32);
    #pragma unroll
    for (int c = 0; c < 8; c++)
        hp[c] = make_float4(o[4 * c], o[4 * c + 1], o[4 * c + 2], o[4 * c + 3]);

    // g16 = fp16(h @ W1a_r0)
    float g[32];
    #pragma unroll
    for (int j = 0; j < 32; j++) g[j] = 0.0f;
    #pragma unroll 4
    for (int k = 0; k < 32; k++) {
        float hk = o[k];
        const float* wr = &sWg[k * 32];
        #pragma unroll
        for (int j = 0; j < 32; j++) g[j] = fmaf(hk, wr[j], g[j]);
    }
    __half* gp = g16 + (size_t)n * 32;
    #pragma unroll
    for (int j = 0; j < 32; j++) gp[j] = __float2half(g[j]);
}

// -------- CSR build: histogram -> exclusive scan -> fill --------

__global__ void __launch_bounds__(256)
k_hist(const int2* __restrict__ edges, int* __restrict__ cnt, int n_edges)
{
    int e = blockIdx.x * 256 + threadIdx.x;
    if (e >= n_edges) return;
    atomicAdd(&cnt[edges[e].y], 1);
}

__global__ void __launch_bounds__(256)
k_scan_block(const int* __restrict__ cnt, int* __restrict__ rs,
             int* __restrict__ bsum, int n)
{
    __shared__ int sd[256];
    int t = threadIdx.x;
    int i = blockIdx.x * 256 + t;
    int v = (i < n) ? cnt[i] : 0;
    sd[t] = v;
    __syncthreads();
    int val = v;
    for (int off = 1; off < 256; off <<= 1) {
        int add = (t >= off) ? sd[t - off] : 0;
        __syncthreads();
        val += add;
        sd[t] = val;
        __syncthreads();
    }
    if (i < n) rs[i] = val - v;           // exclusive within block
    if (t == 255) bsum[blockIdx.x] = val; // block total
}

__global__ void __launch_bounds__(1024)
k_scan_bsum(int* __restrict__ bsum, int nb, int* __restrict__ rs,
            int n_nodes, int n_edges)
{
    __shared__ int sd[1024];
    int t = threadIdx.x;
    int v = (t < nb) ? bsum[t] : 0;
    sd[t] = v;
    __syncthreads();
    int val = v;
    for (int off = 1; off < 1024; off <<= 1) {
        int add = (t >= off) ? sd[t - off] : 0;
        __syncthreads();
        val += add;
        sd[t] = val;
        __syncthreads();
    }
    if (t < nb) bsum[t] = val - v;  // exclusive prefix of block totals
    if (t == 0) rs[n_nodes] = n_edges;
}

__global__ void __launch_bounds__(256)
k_scan_add(int* __restrict__ rs, int* __restrict__ cursor,
           const int* __restrict__ bsum, int n)
{
    int i = blockIdx.x * 256 + threadIdx.x;
    if (i < n) {
        int v = rs[i] + bsum[blockIdx.x];
        rs[i] = v;
        cursor[i] = v;
    }
}

// scatter edges into dst-sorted packed slot records:
//   recs[3*pos] = src, recs[3*pos+1] = half2(ef.x,ef.y),
//   recs[3*pos+2] = half2(ef.z,ef.w)
__global__ void __launch_bounds__(256)
k_fill3(const int2* __restrict__ edges, const float4* __restrict__ ef,
        int* __restrict__ cursor, int* __restrict__ recs, int n_edges)
{
    int e = blockIdx.x * 256 + threadIdx.x;
    if (e >= n_edges) return;
    int2 ed = edges[e];
    float4 v = ef[e];
    int pos = atomicAdd(&cursor[ed.y], 1);
    __half2 h01 = __floats2half2_rn(v.x, v.y);
    __half2 h23 = __floats2half2_rn(v.z, v.w);
    recs[3 * pos]     = ed.x;
    recs[3 * pos + 1] = *reinterpret_cast<int*>(&h01);
    recs[3 * pos + 2] = *reinterpret_cast<int*>(&h23);
}

// -------- k_edge: wave-per-node gather phase only --------
// per edge: m1[c] = relu(base[dst][c] + g[src][c] + sum_k ef[k]*W1c[k][c])
// base computed in-kernel (32-shfl chain, once per node); rsum written to
// rsum_out (= the round's h_out buffer). Lean LDS (4.2KB) + lean regs for
// max occupancy on the latency-bound gather.
__global__ void __launch_bounds__(256)
k_edge(const float* __restrict__ h_in, float* __restrict__ rsum_out,
       const __half* __restrict__ g16,
       const int* __restrict__ row_start, const int* __restrict__ recs,
       const float* __restrict__ mw1, const float* __restrict__ mb1,
       int n_nodes)
{
    __shared__ float sW1b[32 * 32];   // msg_w1 rows 32..63 (dst half)
    __shared__ float sB1[32];
    for (int i = threadIdx.x; i < 32 * 32; i += 256) sW1b[i] = mw1[32 * 32 + i];
    if (threadIdx.x < 32) sB1[threadIdx.x] = mb1[threadIdx.x];
    __syncthreads();

    const int lane = threadIdx.x & 63;
    const int c    = lane & 31;
    const int half = lane >> 5;

    float w1c[4];
    #pragma unroll
    for (int k = 0; k < 4; k++) w1c[k] = mw1[(64 + k) * 32 + c];

    int wave   = (int)((blockIdx.x * 256 + threadIdx.x) >> 6);
    int nwaves = gridDim.x * 4;

    for (int n = wave; n < n_nodes; n += nwaves) {
        float hn = h_in[(size_t)n * 32 + c];

        // base = mb1 + h[n] @ W1b (4-way split chains)
        float base;
        {
            float p0 = sB1[c], p1 = 0.0f, p2 = 0.0f, p3 = 0.0f;
            #pragma unroll
            for (int k = 0; k < 8; k++) {
                p0 = fmaf(__shfl(hn, k,      32), sW1b[(k)      * 32 + c], p0);
                p1 = fmaf(__shfl(hn, k + 8,  32), sW1b[(k + 8)  * 32 + c], p1);
                p2 = fmaf(__shfl(hn, k + 16, 32), sW1b[(k + 16) * 32 + c], p2);
                p3 = fmaf(__shfl(hn, k + 24, 32), sW1b[(k + 24) * 32 + c], p3);
            }
            base = (p0 + p1) + (p2 + p3);
        }

        int s0 = row_start[n];
        int s1 = row_start[n + 1];
        float rsum = 0.0f;

        int s = s0 + half;
        for (; s + 6 < s1; s += 8) {
            int b0 = 3 * s;
            int b1 = 3 * (s + 2);
            int b2 = 3 * (s + 4);
            int b3 = 3 * (s + 6);
            int i0 = recs[b0];
            int i1 = recs[b1];
            int i2 = recs[b2];
            int i3 = recs[b3];
            uint32_t u01_0 = (uint32_t)recs[b0 + 1], u23_0 = (uint32_t)recs[b0 + 2];
            uint32_t u01_1 = (uint32_t)recs[b1 + 1], u23_1 = (uint32_t)recs[b1 + 2];
            uint32_t u01_2 = (uint32_t)recs[b2 + 1], u23_2 = (uint32_t)recs[b2 + 2];
            uint32_t u01_3 = (uint32_t)recs[b3 + 1], u23_3 = (uint32_t)recs[b3 + 2];
            float x0 = __half2float(g16[(size_t)i0 * 32 + c]);
            float x1 = __half2float(g16[(size_t)i1 * 32 + c]);
            float x2 = __half2float(g16[(size_t)i2 * 32 + c]);
            float x3 = __half2float(g16[(size_t)i3 * 32 + c]);

            float2 eA0 = __half22float2(*reinterpret_cast<const __half2*>(&u01_0));
            float2 eB0 = __half22float2(*reinterpret_cast<const __half2*>(&u23_0));
            float2 eA1 = __half22float2(*reinterpret_cast<const __half2*>(&u01_1));
            float2 eB1 = __half22float2(*reinterpret_cast<const __half2*>(&u23_1));
            float2 eA2 = __half22float2(*reinterpret_cast<const __half2*>(&u01_2));
            float2 eB2 = __half22float2(*reinterpret_cast<const __half2*>(&u23_2));
            float2 eA3 = __half22float2(*reinterpret_cast<const __half2*>(&u01_3));
            float2 eB3 = __half22float2(*reinterpret_cast<const __half2*>(&u23_3));

            float a0 = base + x0;
            float a1 = base + x1;
            float a2 = base + x2;
            float a3 = base + x3;
            a0 = fmaf(eA0.x, w1c[0], a0); a0 = fmaf(eA0.y, w1c[1], a0);
            a0 = fmaf(eB0.x, w1c[2], a0); a0 = fmaf(eB0.y, w1c[3], a0);
            a1 = fmaf(eA1.x, w1c[0], a1); a1 = fmaf(eA1.y, w1c[1], a1);
            a1 = fmaf(eB1.x, w1c[2], a1); a1 = fmaf(eB1.y, w1c[3], a1);
            a2 = fmaf(eA2.x, w1c[0], a2); a2 = fmaf(eA2.y, w1c[1], a2);
            a2 = fmaf(eB2.x, w1c[2], a2); a2 = fmaf(eB2.y, w1c[3], a2);
            a3 = fmaf(eA3.x, w1c[0], a3); a3 = fmaf(eA3.y, w1c[1], a3);
            a3 = fmaf(eB3.x, w1c[2], a3); a3 = fmaf(eB3.y, w1c[3], a3);

            rsum += fmaxf(a0, 0.0f);
            rsum += fmaxf(a1, 0.0f);
            rsum += fmaxf(a2, 0.0f);
            rsum += fmaxf(a3, 0.0f);
        }
        for (; s < s1; s += 2) {
            int b = 3 * s;
            int i0 = recs[b];
            uint32_t u01 = (uint32_t)recs[b + 1], u23 = (uint32_t)recs[b + 2];
            float x = __half2float(g16[(size_t)i0 * 32 + c]);
            float2 eA = __half22float2(*reinterpret_cast<const __half2*>(&u01));
            float2 eB = __half22float2(*reinterpret_cast<const __half2*>(&u23));
            float a = base + x;
            a = fmaf(eA.x, w1c[0], a); a = fmaf(eA.y, w1c[1], a);
            a = fmaf(eB.x, w1c[2], a); a = fmaf(eB.y, w1c[3], a);
            rsum += fmaxf(a, 0.0f);
        }
        rsum += __shfl_xor(rsum, 32, 64);
        if (lane < 32) rsum_out[(size_t)n * 32 + c] = rsum;
    }
}

// -------- k_post: thread-per-node matmul phase (k_encode pattern) --------
// hr holds rsum on entry; on exit holds hnew. Optionally emits g16 for the
// next round (do_g) and the head output (do_head).
__global__ void __launch_bounds__(256)
k_post(const float* __restrict__ h_in, float* __restrict__ hr,
       const int* __restrict__ row_start,
       const float* __restrict__ mw2, const float* __restrict__ mb2,
       const float* __restrict__ uw1, const float* __restrict__ ub1,
       const float* __restrict__ uw2, const float* __restrict__ ub2,
       const float* __restrict__ nmw1, __half* __restrict__ g16, int do_g,
       const float* __restrict__ hw1, const float* __restrict__ hb1,
       const float* __restrict__ hw2, const float* __restrict__ hb2,
       float* __restrict__ out, int do_head,
       int n_nodes)
{
    __shared__ float sW2[32 * 32];
    __shared__ float sU1[64 * 32];
    __shared__ float sU2[32 * 32];
    __shared__ float sG[32 * 32];
    __shared__ float sH1[32 * 32];
    __shared__ float sB[3 * 32];   // mb2 | ub1 | ub2
    __shared__ float sHb1[32];
    __shared__ float sHw2[32];
    __shared__ float sHb2;
    for (int i = threadIdx.x; i < 32 * 32; i += 256) sW2[i] = mw2[i];
    for (int i = threadIdx.x; i < 64 * 32; i += 256) sU1[i] = uw1[i];
    for (int i = threadIdx.x; i < 32 * 32; i += 256) sU2[i] = uw2[i];
    if (do_g)
        for (int i = threadIdx.x; i < 32 * 32; i += 256) sG[i] = nmw1[i];
    if (do_head) {
        for (int i = threadIdx.x; i < 32 * 32; i += 256) sH1[i] = hw1[i];
        if (threadIdx.x < 32) {
            sHb1[threadIdx.x] = hb1[threadIdx.x];
            sHw2[threadIdx.x] = hw2[threadIdx.x];
        }
        if (threadIdx.x == 0) sHb2 = hb2[0];
    }
    if (threadIdx.x < 32) {
        sB[threadIdx.x]      = mb2[threadIdx.x];
        sB[32 + threadIdx.x] = ub1[threadIdx.x];
        sB[64 + threadIdx.x] = ub2[threadIdx.x];
    }
    __syncthreads();
    int n = blockIdx.x * 256 + threadIdx.x;
    if (n >= n_nodes) return;

    float hv[32], rs[32];
    {
        const float4* hp = (const float4*)(h_in + (size_t)n * 32);
        const float4* rp = (const float4*)(hr + (size_t)n * 32);
        #pragma unroll
        for (int q = 0; q < 8; q++) {
            float4 a = hp[q];
            hv[4 * q] = a.x; hv[4 * q + 1] = a.y; hv[4 * q + 2] = a.z; hv[4 * q + 3] = a.w;
            float4 b = rp[q];
            rs[4 * q] = b.x; rs[4 * q + 1] = b.y; rs[4 * q + 2] = b.z; rs[4 * q + 3] = b.w;
        }
    }
    float deg = (float)(row_start[n + 1] - row_start[n]);

    // agg = deg*mb2 + rsum @ W2
    float agg[32];
    #pragma unroll
    for (int j = 0; j < 32; j++) agg[j] = deg * sB[j];
    #pragma unroll 4
    for (int k = 0; k < 32; k++) {
        float rk = rs[k];
        const float* wr = &sW2[k * 32];
        #pragma unroll
        for (int j = 0; j < 32; j++) agg[j] = fmaf(rk, wr[j], agg[j]);
    }

    // acc = ub1 + h@U1[0:32] + agg@U1[32:64]
    float acc[32];
    #pragma unroll
    for (int j = 0; j < 32; j++) acc[j] = sB[32 + j];
    #pragma unroll 4
    for (int k = 0; k < 32; k++) {
        float xk = hv[k];
        const float* wr = &sU1[k * 32];
        #pragma unroll
        for (int j = 0; j < 32; j++) acc[j] = fmaf(xk, wr[j], acc[j]);
    }
    #pragma unroll 4
    for (int k = 0; k < 32; k++) {
        float xk = agg[k];
        const float* wr = &sU1[(32 + k) * 32];
        #pragma unroll
        for (int j = 0; j < 32; j++) acc[j] = fmaf(xk, wr[j], acc[j]);
    }
    #pragma unroll
    for (int j = 0; j < 32; j++) acc[j] = fmaxf(acc[j], 0.0f);

    // o = ub2 + t @ U2 ; hnew = h + o
    float o[32];
    #pragma unroll
    for (int j = 0; j < 32; j++) o[j] = sB[64 + j];
    #pragma unroll 4
    for (int k = 0; k < 32; k++) {
        float tk = acc[k];
        const float* wr = &sU2[k * 32];
        #pragma unroll
        for (int j = 0; j < 32; j++) o[j] = fmaf(tk, wr[j], o[j]);
    }
    #pragma unroll
    for (int j = 0; j < 32; j++) hv[j] += o[j];

    {
        float4* op = (float4*)(hr + (size_t)n * 32);
        #pragma unroll
        for (int q = 0; q < 8; q++)
            op[q] = make_float4(hv[4 * q], hv[4 * q + 1], hv[4 * q + 2], hv[4 * q + 3]);
    }

    if (do_g) {
        float g[32];
        #pragma unroll
        for (int j = 0; j < 32; j++) g[j] = 0.0f;
        #pragma unroll 4
        for (int k = 0; k < 32; k++) {
            float hk = hv[k];
            const float* wr = &sG[k * 32];
            #pragma unroll
            for (int j = 0; j < 32; j++) g[j] = fmaf(hk, wr[j], g[j]);
        }
        __half* gp = g16 + (size_t)n * 32;
        #pragma unroll
        for (int j = 0; j < 32; j++) gp[j] = __float2half(g[j]);
    }

    if (do_head) {
        float a[32];
        #pragma unroll
        for (int j = 0; j < 32; j++) a[j] = sHb1[j];
        #pragma unroll 4
        for (int k = 0; k < 32; k++) {
            float hk = hv[k];
            const float* wr = &sH1[k * 32];
            #pragma unroll
            for (int j = 0; j < 32; j++) a[j] = fmaf(hk, wr[j], a[j]);
        }
        float val = sHb2;
        #pragma unroll
        for (int k = 0; k < 32; k++) val = fmaf(fmaxf(a[k], 0.0f), sHw2[k], val);
        out[n] = val;
    }
}

// -------- R14 fallback kernels (atomic path), used only if ws too small -----

__global__ void __launch_bounds__(256)
k_encode(const float* __restrict__ nf,
         const float* __restrict__ w1g, const float* __restrict__ b1g,
         const float* __restrict__ w2g, const float* __restrict__ b2g,
         float* __restrict__ h, int n_nodes)
{
    __shared__ float sw1[16 * 32];
    __shared__ float sw2[32 * 32];
    __shared__ float sb1[32];
    __shared__ float sb2[32];
    for (int i = threadIdx.x; i < 16 * 32; i += 256) sw1[i] = w1g[i];
    for (int i = threadIdx.x; i < 32 * 32; i += 256) sw2[i] = w2g[i];
    if (threadIdx.x < 32) {
        sb1[threadIdx.x] = b1g[threadIdx.x];
        sb2[threadIdx.x] = b2g[threadIdx.x];
    }
    __syncthreads();
    int n = blockIdx.x * 256 + threadIdx.x;
    if (n >= n_nodes) return;

    const float4* p = (const float4*)(nf + (size_t)n * 16);
    float x[16];
    #pragma unroll
    for (int c = 0; c < 4; c++) {
        float4 v = p[c];
        x[4 * c] = v.x; x[4 * c + 1] = v.y; x[4 * c + 2] = v.z; x[4 * c + 3] = v.w;
    }
    float acc[32];
    #pragma unroll
    for (int j = 0; j < 32; j++) acc[j] = sb1[j];
    #pragma unroll 4
    for (int k = 0; k < 16; k++) {
        float xk = x[k];
        const float* wr = &sw1[k * 32];
        #pragma unroll
        for (int j = 0; j < 32; j++) acc[j] = fmaf(xk, wr[j], acc[j]);
    }
    #pragma unroll
    for (int j = 0; j < 32; j++) acc[j] = fmaxf(acc[j], 0.0f);
    float o[32];
    #pragma unroll
    for (int j = 0; j < 32; j++) o[j] = sb2[j];
    #pragma unroll 4
    for (int k = 0; k < 32; k++) {
        float hk = acc[k];
        const float* wr = &sw2[k * 32];
        #pragma unroll
        for (int j = 0; j < 32; j++) o[j] = fmaf(hk, wr[j], o[j]);
    }
    float4* hp = (float4*)(h + (size_t)n * 32);
    #pragma unroll
    for (int c = 0; c < 8; c++)
        hp[c] = make_float4(o[4 * c], o[4 * c + 1], o[4 * c + 2], o[4 * c + 3]);
}

__global__ void __launch_bounds__(256)
k_message(const float* __restrict__ h, const int2* __restrict__ edges,
          const float4* __restrict__ ef,
          const float* __restrict__ w1g, const float* __restrict__ b1g,
          const float* __restrict__ w2g, const float* __restrict__ b2g,
          float* __restrict__ agg, int n_edges)
{
    __shared__ float sw1[68 * 32];
    __shared__ float sw2[32 * 32];
    __shared__ float sb1[32];
    __shared__ float sb2[32];
    for (int i = threadIdx.x; i < 68 * 32; i += 256) sw1[i] = w1g[i];
    for (int i = threadIdx.x; i < 32 * 32; i += 256) sw2[i] = w2g[i];
    if (threadIdx.x < 32) {
        sb1[threadIdx.x] = b1g[threadIdx.x];
        sb2[threadIdx.x] = b2g[threadIdx.x];
    }
    __syncthreads();
    int e = blockIdx.x * 256 + threadIdx.x;
    if (e >= n_edges) return;

    int2 ed = edges[e];
    const float4* hs = (const float4*)(h + (size_t)ed.x * 32);
    const float4* hd = (const float4*)(h + (size_t)ed.y * 32);

    float acc[32];
    #pragma unroll
    for (int j = 0; j < 32; j++) acc[j] = sb1[j];
    #pragma unroll 2
    for (int cc = 0; cc < 8; cc++) {
        float4 xv = hs[cc];
        float xsv[4] = {xv.x, xv.y, xv.z, xv.w};
        #pragma unroll
        for (int kk = 0; kk < 4; kk++) {
            float xk = xsv[kk];
            const float* wr = &sw1[(cc * 4 + kk) * 32];
            #pragma unroll
            for (int j = 0; j < 32; j++) acc[j] = fmaf(xk, wr[j], acc[j]);
        }
    }
    #pragma unroll 2
    for (int cc = 0; cc < 8; cc++) {
        float4 xv = hd[cc];
        float xsv[4] = {xv.x, xv.y, xv.z, xv.w};
        #pragma unroll
        for (int kk = 0; kk < 4; kk++) {
            float xk = xsv[kk];
            const float* wr = &sw1[(32 + cc * 4 + kk) * 32];
            #pragma unroll
            for (int j = 0; j < 32; j++) acc[j] = fmaf(xk, wr[j], acc[j]);
        }
    }
    {
        float4 evv = ef[e];
        float ex[4] = {evv.x, evv.y, evv.z, evv.w};
        #pragma unroll
        for (int kk = 0; kk < 4; kk++) {
            float xk = ex[kk];
            const float* wr = &sw1[(64 + kk) * 32];
            #pragma unroll
            for (int j = 0; j < 32; j++) acc[j] = fmaf(xk, wr[j], acc[j]);
        }
    }
    #pragma unroll
    for (int j = 0; j < 32; j++) acc[j] = fmaxf(acc[j], 0.0f);

    float o[32];
    #pragma unroll
    for (int j = 0; j < 32; j++) o[j] = sb2[j];
    #pragma unroll 4
    for (int k = 0; k < 32; k++) {
        float hk = acc[k];
        const float* wr = &sw2[k * 32];
        #pragma unroll
        for (int j = 0; j < 32; j++) o[j] = fmaf(hk, wr[j], o[j]);
    }
    float* ap = agg + (size_t)ed.y * 32;
    #pragma unroll
    for (int j = 0; j < 32; j++) atomicAdd(ap + j, o[j]);
}

__global__ void __launch_bounds__(256)
k_update(float* h, const float* __restrict__ agg,
         const float* __restrict__ w1g, const float* __restrict__ b1g,
         const float* __restrict__ w2g, const float* __restrict__ b2g,
         int n_nodes)
{
    __shared__ float sw1[64 * 32];
    __shared__ float sw2[32 * 32];
    __shared__ float sb1[32];
    __shared__ float sb2[32];
    for (int i = threadIdx.x; i < 64 * 32; i += 256) sw1[i] = w1g[i];
    for (int i = threadIdx.x; i < 32 * 32; i += 256) sw2[i] = w2g[i];
    if (threadIdx.x < 32) {
        sb1[threadIdx.x] = b1g[threadIdx.x];
        sb2[threadIdx.x] = b2g[threadIdx.x];
    }
    __syncthreads();
    int n = blockIdx.x * 256 + threadIdx.x;
    if (n >= n_nodes) return;

    const float4* hp = (const float4*)(h + (size_t)n * 32);
    const float4* ap = (const float4*)(agg + (size_t)n * 32);

    float hv[32];
    float acc[32];
    #pragma unroll
    for (int j = 0; j < 32; j++) acc[j] = sb1[j];
    #pragma unroll 2
    for (int cc = 0; cc < 8; cc++) {
        float4 xv = hp[cc];
        hv[4 * cc] = xv.x; hv[4 * cc + 1] = xv.y; hv[4 * cc + 2] = xv.z; hv[4 * cc + 3] = xv.w;
        float xsv[4] = {xv.x, xv.y, xv.z, xv.w};
        #pragma unroll
        for (int kk = 0; kk < 4; kk++) {
            float xk = xsv[kk];
            const float* wr = &sw1[(cc * 4 + kk) * 32];
            #pragma unroll
            for (int j = 0; j < 32; j++) acc[j] = fmaf(xk, wr[j], acc[j]);
        }
    }
    #pragma unroll 2
    for (int cc = 0; cc < 8; cc++) {
        float4 xv = ap[cc];
        float xsv[4] = {xv.x, xv.y, xv.z, xv.w};
        #pragma unroll
        for (int kk = 0; kk < 4; kk++) {
            float xk = xsv[kk];
            const float* wr = &sw1[(32 + cc * 4 + kk) * 32];
            #pragma unroll
            for (int j = 0; j < 32; j++) acc[j] = fmaf(xk, wr[j], acc[j]);
        }
    }
    #pragma unroll
    for (int j = 0; j < 32; j++) acc[j] = fmaxf(acc[j], 0.0f);

    float o[32];
    #pragma unroll
    for (int j = 0; j < 32; j++) o[j] = sb2[j];
    #pragma unroll 4
    for (int k = 0; k < 32; k++) {
        float hk = acc[k];
        const float* wr = &sw2[k * 32];
        #pragma unroll
        for (int j = 0; j < 32; j++) o[j] = fmaf(hk, wr[j], o[j]);
    }
    float4* op = (float4*)(h + (size_t)n * 32);
    #pragma unroll
    for (int cc = 0; cc < 8; cc++)
        op[cc] = make_float4(hv[4 * cc] + o[4 * cc], hv[4 * cc + 1] + o[4 * cc + 1],
                             hv[4 * cc + 2] + o[4 * cc + 2], hv[4 * cc + 3] + o[4 * cc + 3]);
}

// head: out = (relu(h @ w1 + b1) @ w2 + b2)[:, 0]   (fp32 out)
__global__ void AtomGNN_56169582297457_kernel(const float* h, const float* w1g, const float* b1g, const float* w2g, const float* b2g, float* out, int n_nodes) {
    __shared__ float sw1[32 * 32];
    __shared__ float sb1[32];
    __shared__ float sw2[32];
    __shared__ float sb2;
    for (int i = threadIdx.x; i < 32 * 32; i += 256) sw1[i] = w1g[i];
    if (threadIdx.x < 32) {
        sb1[threadIdx.x] = b1g[threadIdx.x];
        sw2[threadIdx.x] = w2g[threadIdx.x];
    }
    if (threadIdx.x == 0) sb2 = b2g[0];
    __syncthreads();
    int n = blockIdx.x * 256 + threadIdx.x;
    if (n >= n_nodes) return;

    const float4* hp = (const float4*)(h + (size_t)n * 32);
    float x[32];
    #pragma unroll
    for (int cc = 0; cc < 8; cc++) {
        float4 xv = hp[cc];
        x[4 * cc] = xv.x; x[4 * cc + 1] = xv.y; x[4 * cc + 2] = xv.z; x[4 * cc + 3] = xv.w;
    }
    float acc[32];
    #pragma unroll
    for (int j = 0; j < 32; j++) acc[j] = sb1[j];
    #pragma unroll 4
    for (int k = 0; k < 32; k++) {
        float xk = x[k];
        const float* wr = &sw1[k * 32];
        #pragma unroll
        for (int j = 0; j < 32; j++) acc[j] = fmaf(xk, wr[j], acc[j]);
    }
    float val = sb2;
    #pragma unroll
    for (int k = 0; k < 32; k++) val = fmaf(fmaxf(acc[k], 0.0f), sw2[k], val);
    out[n] = val;
}

extern "C" void kernel_launch(void* const* d_in, const int* in_sizes, int n_in,
                              void* d_out, int out_size, void* d_ws, size_t ws_size,
                              hipStream_t stream) {
    const float* nf      = (const float*)d_in[0];
    const int2*  edges   = (const int2*)d_in[1];
    const float4* ef     = (const float4*)d_in[2];
    const float* enc_w1  = (const float*)d_in[3];
    const float* enc_b1  = (const float*)d_in[4];
    const float* enc_w2  = (const float*)d_in[5];
    const float* enc_b2  = (const float*)d_in[6];
    const float* msg_w1  = (const float*)d_in[7];
    const float* msg_b1  = (const float*)d_in[8];
    const float* msg_w2  = (const float*)d_in[9];
    const float* msg_b2  = (const float*)d_in[10];
    const float* upd_w1  = (const float*)d_in[11];
    const float* upd_b1  = (const float*)d_in[12];
    const float* upd_w2  = (const float*)d_in[13];
    const float* upd_b2  = (const float*)d_in[14];
    const float* head_w1 = (const float*)d_in[15];
    const float* head_b1 = (const float*)d_in[16];
    const float* head_w2 = (const float*)d_in[17];
    const float* head_b2 = (const float*)d_in[18];

    int n_nodes = (out_size > 0) ? out_size : NN_REF;
    int n_edges = (in_sizes && n_in > 2 && in_sizes[2] > 0) ? in_sizes[2] / 4 : NE_REF;

    int nb_nodes = (n_nodes + 255) / 256;
    int nb_edges = (n_edges + 255) / 256;

    // Workspace layout (~71.2MB total, proven to fit):
    //   h0 | h1 | g16(half) | row_start[n+1] | cursor[n] | bsum[nb]
    //   | recs[3*E] int (packed: src, half2 ef01, half2 ef23)
    float* h0 = (float*)d_ws;
    float* h1 = h0 + (size_t)n_nodes * 32;
    __half* g16 = (__half*)(h1 + (size_t)n_nodes * 32);
    int* row_start = (int*)(g16 + (size_t)n_nodes * 32);
    int* cursor = row_start + (n_nodes + 1);
    int* bsum = cursor + n_nodes;
    int* recs = bsum + nb_nodes;
    size_t required = ((uintptr_t)(recs + (size_t)3 * n_edges) - (uintptr_t)d_ws);

    bool csr_ok = (nb_nodes <= 1024) &&
                  (ws_size == 0 || ws_size >= required);

    if (csr_ok) {
        // encoder + round-0 g16 emit
        k_encode2<<<nb_nodes, 256, 0, stream>>>(
            nf, enc_w1, enc_b1, enc_w2, enc_b2, msg_w1, h0, g16, n_nodes);

        // build dst-CSR once (edges identical across rounds)
        k_zero<<<256, 256, 0, stream>>>((float*)cursor, n_nodes);
        k_hist<<<nb_edges, 256, 0, stream>>>(edges, cursor, n_edges);
        k_scan_block<<<nb_nodes, 256, 0, stream>>>(cursor, row_start, bsum, n_nodes);
        k_scan_bsum<<<1, 1024, 0, stream>>>(bsum, nb_nodes, row_start, n_nodes, n_edges);
        k_scan_add<<<nb_nodes, 256, 0, stream>>>(row_start, cursor, bsum, n_nodes);
        k_fill3<<<nb_edges, 256, 0, stream>>>(edges, ef, cursor, recs, n_edges);

        // ping-pong rounds: h0 -> h1 -> h0
        for (int r = 0; r < 2; r++) {
            const float* hin = (r == 0) ? h0 : h1;
            float* hr        = (r == 0) ? h1 : h0;   // rsum then hnew
            const float* mw1 = msg_w1 + (size_t)r * 68 * 32;
            int last = (r == 1);

            k_edge<<<2048, 256, 0, stream>>>(
                hin, hr, g16, row_start, recs,
                mw1, msg_b1 + (size_t)r * 32, n_nodes);

            k_post<<<nb_nodes, 256, 0, stream>>>(
                hin, hr, row_start,
                msg_w2 + (size_t)r * 32 * 32, msg_b2 + (size_t)r * 32,
                upd_w1 + (size_t)r * 64 * 32, upd_b1 + (size_t)r * 32,
                upd_w2 + (size_t)r * 32 * 32, upd_b2 + (size_t)r * 32,
                msg_w1 + (size_t)(r + 1) * 68 * 32, g16, last ? 0 : 1,
                head_w1, head_b1, head_w2, head_b2,
                (float*)d_out, last ? 1 : 0,
                n_nodes);
        }
    } else {
        // R14 fallback: atomic scatter path
        float* h   = (float*)d_ws;
        float* agg = h + (size_t)n_nodes * 32;

        k_encode<<<nb_nodes, 256, 0, stream>>>(nf, enc_w1, enc_b1, enc_w2, enc_b2, h, n_nodes);
        for (int r = 0; r < 2; r++) {
            k_zero<<<1024, 256, 0, stream>>>(agg, n_nodes * 32);
            k_message<<<nb_edges, 256, 0, stream>>>(
                h, edges, ef,
                msg_w1 + (size_t)r * 68 * 32, msg_b1 + (size_t)r * 32,
                msg_w2 + (size_t)r * 32 * 32, msg_b2 + (size_t)r * 32,
                agg, n_edges);
            k_update<<<nb_nodes, 256, 0, stream>>>(
                h, agg,
                upd_w1 + (size_t)r * 64 * 32, upd_b1 + (size_t)r * 32,
                upd_w2 + (size_t)r * 32 * 32, upd_b2 + (size_t)r * 32,
                n_nodes);
        }
        AtomGNN_56169582297457_kernel<<<nb_nodes, 256, 0, stream>>>(
            h, head_w1, head_b1, head_w2, head_b2, (float*)d_out, n_nodes);
    }
}